// Round 7
// baseline (5075.965 us; speedup 1.0000x reference)
//
#include <hip/hip_runtime.h>
#include <float.h>

// ---------------------------------------------------------------------------
// VQ-VAE quantizer forward — round 7: bit-level numpy/OpenBLAS f32 emulation
// for the ids path, with CORRECTED OpenBLAS kc panel splits:
//   level3.c: rem>=2Q -> take Q=384; Q<rem<2Q -> take rem/2 (rounded to 16).
//   K=1024 panels: 384,320,320  (joins at chunk 6, 11    -> mask 0x840)
//   K=2048 panels: 384x4,256,256 (joins at 6,12,18,24,28 -> mask 0x11041040)
// Pipeline: t = fl32(roi@W_in.T)+b_in; z = fl32(t@W_enc.T)+b_enc (sequential-k
// FMA chains, panel joins as above); z2/c2 = numpy pairwise sums (128-leaf,
// 8-acc, binary tree); d = fl(fl(z2-2dot)+c2); first-index argmin.
// z_q/recon/losses have 2%-of-max thresholds -> fast fp32 paths.
// ---------------------------------------------------------------------------

#define N_ROWS 8192
#define IN_DIM 2048
#define DIM 1024
#define CBK 8192

#define PANEL_MASK_K1024 0x00000840u
#define PANEL_MASK_K2048 0x11041040u

__device__ __forceinline__ float sqf(float v) { return __builtin_fmaf(v, v, 0.0f); }

__device__ __forceinline__ int swz128(int c) {
  return (c & 3) | (((c >> 3) & 7) << 2) | (((c >> 2) & 1) << 5) | ((c >> 6) << 6);
}

__device__ __forceinline__ float block_reduce_sum(float v) {
  __shared__ float sh[4];
  #pragma unroll
  for (int off = 32; off > 0; off >>= 1) v += __shfl_down(v, off, 64);
  const int lane = threadIdx.x & 63, w = threadIdx.x >> 6;
  if (lane == 0) sh[w] = v;
  __syncthreads();
  float r = 0.f;
  if (threadIdx.x == 0) r = sh[0] + sh[1] + sh[2] + sh[3];
  return r;  // valid on thread 0 only
}

// ---------------------------------------------------------------------------
// fp32 128x128x16 tiled GEMM (decoder path: W_dc fusion + recon). 2% thresh.
// ---------------------------------------------------------------------------
template <bool BT>
__global__ __launch_bounds__(256) void gemm128(
    const float* __restrict__ A, const float* __restrict__ B,
    const float* __restrict__ bias, float* __restrict__ C,
    int M, int N, int K) {
  __shared__ float As[16][132];
  __shared__ float Bs[16][132];
  const int tid = threadIdx.x;
  const int tx = tid & 15, ty = tid >> 4;
  const int bm = blockIdx.y, bn = blockIdx.x;

  const int mload = tid & 127, kh = tid >> 7;
  const size_t arow = (size_t)(bm * 128 + mload) * (size_t)K;
  const size_t brow = BT ? (size_t)(bn * 128 + mload) * (size_t)K : 0;
  const int swn = swz128(mload);
  const int c4 = (tid & 31) << 2;
  const int kr = tid >> 5;
  const int swc = swz128(c4);

  float acc[8][8];
  #pragma unroll
  for (int r = 0; r < 8; ++r)
    #pragma unroll
    for (int c = 0; c < 8; ++c) acc[r][c] = 0.f;

  const int boff = ((tx & 7) << 2) | ((tx >> 3) << 6);

  for (int k0 = 0; k0 < K; k0 += 16) {
    const float4 av0 = *(const float4*)&A[arow + k0 + kh * 8];
    const float4 av1 = *(const float4*)&A[arow + k0 + kh * 8 + 4];
    float4 bv0, bv1;
    if (BT) {
      bv0 = *(const float4*)&B[brow + k0 + kh * 8];
      bv1 = *(const float4*)&B[brow + k0 + kh * 8 + 4];
    } else {
      bv0 = *(const float4*)&B[(size_t)(k0 + kr) * N + bn * 128 + c4];
      bv1 = *(const float4*)&B[(size_t)(k0 + kr + 8) * N + bn * 128 + c4];
    }
    __syncthreads();
    As[kh * 8 + 0][mload] = av0.x; As[kh * 8 + 1][mload] = av0.y;
    As[kh * 8 + 2][mload] = av0.z; As[kh * 8 + 3][mload] = av0.w;
    As[kh * 8 + 4][mload] = av1.x; As[kh * 8 + 5][mload] = av1.y;
    As[kh * 8 + 6][mload] = av1.z; As[kh * 8 + 7][mload] = av1.w;
    if (BT) {
      Bs[kh * 8 + 0][swn] = bv0.x; Bs[kh * 8 + 1][swn] = bv0.y;
      Bs[kh * 8 + 2][swn] = bv0.z; Bs[kh * 8 + 3][swn] = bv0.w;
      Bs[kh * 8 + 4][swn] = bv1.x; Bs[kh * 8 + 5][swn] = bv1.y;
      Bs[kh * 8 + 6][swn] = bv1.z; Bs[kh * 8 + 7][swn] = bv1.w;
    } else {
      *(float4*)&Bs[kr][swc] = bv0;
      *(float4*)&Bs[kr + 8][swc] = bv1;
    }
    __syncthreads();
    #pragma unroll
    for (int kk = 0; kk < 16; ++kk) {
      const float4 a0 = *(const float4*)&As[kk][ty * 8];
      const float4 a1 = *(const float4*)&As[kk][ty * 8 + 4];
      const float4 b0 = *(const float4*)&Bs[kk][boff];
      const float4 b1 = *(const float4*)&Bs[kk][boff + 32];
      const float ar[8] = {a0.x, a0.y, a0.z, a0.w, a1.x, a1.y, a1.z, a1.w};
      const float br[8] = {b0.x, b0.y, b0.z, b0.w, b1.x, b1.y, b1.z, b1.w};
      #pragma unroll
      for (int r = 0; r < 8; ++r)
        #pragma unroll
        for (int c = 0; c < 8; ++c) acc[r][c] = fmaf(ar[r], br[c], acc[r][c]);
    }
  }

  const int gcol = bn * 128 + tx * 8;
  float bb[8] = {0, 0, 0, 0, 0, 0, 0, 0};
  if (bias) {
    const float4 v0 = *(const float4*)&bias[gcol];
    const float4 v1 = *(const float4*)&bias[gcol + 4];
    bb[0] = v0.x; bb[1] = v0.y; bb[2] = v0.z; bb[3] = v0.w;
    bb[4] = v1.x; bb[5] = v1.y; bb[6] = v1.z; bb[7] = v1.w;
  }
  #pragma unroll
  for (int r = 0; r < 8; ++r) {
    float* cp = &C[(size_t)(bm * 128 + ty * 8 + r) * N + gcol];
    float4 o0, o1;
    o0.x = acc[r][0] + bb[0]; o0.y = acc[r][1] + bb[1];
    o0.z = acc[r][2] + bb[2]; o0.w = acc[r][3] + bb[3];
    o1.x = acc[r][4] + bb[4]; o1.y = acc[r][5] + bb[5];
    o1.z = acc[r][6] + bb[6]; o1.w = acc[r][7] + bb[7];
    *(float4*)cp = o0;
    *(float4*)(cp + 4) = o1;
  }
}

// ---------------------------------------------------------------------------
// OpenBLAS-sgemm-emulating GEMM: C[M,N] = A[M,K] @ B[N,K]^T + bias.
// Per element: strict sequential-k fmaf chain within kc panels; panel starts
// given by bit i of panel_mask (chunk index, chunk = 64). Panels joined by
// single f32 adds in order. Block = 64 rows x 16 cols.
// ---------------------------------------------------------------------------
__global__ __launch_bounds__(256) void emul_gemm_kernel(
    const float* __restrict__ A, const float* __restrict__ B,
    const float* __restrict__ bias, float* __restrict__ C,
    int N, int K, int lda, int ldb, unsigned panel_mask) {
  __shared__ float As[64][68];  // [kk][row]
  __shared__ float Bs[64][20];  // [kk][col]
  const int tid = threadIdx.x;
  const int r_loc = tid >> 2;       // 0..63
  const int cg = tid & 3;           // 4 cols each
  const int row0 = blockIdx.y * 64;
  const int col0 = blockIdx.x * 16;

  const int sa_r = tid >> 2, sa_k = (tid & 3) * 16;  // 4 float4 per thread (A)
  const int sb_c = tid >> 4, sb_k = (tid & 15) * 4;  // 1 float4 per thread (B)

  float total[4] = {0.f, 0.f, 0.f, 0.f};
  float part[4] = {0.f, 0.f, 0.f, 0.f};

  const int nchunks = K >> 6;
  for (int ci = 0; ci < nchunks; ++ci) {
    const int k0 = ci << 6;
    if (ci && ((panel_mask >> ci) & 1u)) {  // OpenBLAS kc panel boundary
      #pragma unroll
      for (int i = 0; i < 4; ++i) { total[i] = total[i] + part[i]; part[i] = 0.f; }
    }
    float4 av[4];
    #pragma unroll
    for (int q = 0; q < 4; ++q)
      av[q] = *(const float4*)&A[(size_t)(row0 + sa_r) * lda + k0 + sa_k + q * 4];
    const float4 bv = *(const float4*)&B[(size_t)(col0 + sb_c) * ldb + k0 + sb_k];
    __syncthreads();
    #pragma unroll
    for (int q = 0; q < 4; ++q) {
      As[sa_k + q * 4 + 0][sa_r] = av[q].x;
      As[sa_k + q * 4 + 1][sa_r] = av[q].y;
      As[sa_k + q * 4 + 2][sa_r] = av[q].z;
      As[sa_k + q * 4 + 3][sa_r] = av[q].w;
    }
    Bs[sb_k + 0][sb_c] = bv.x; Bs[sb_k + 1][sb_c] = bv.y;
    Bs[sb_k + 2][sb_c] = bv.z; Bs[sb_k + 3][sb_c] = bv.w;
    __syncthreads();
    for (int kk = 0; kk < 64; ++kk) {  // strict sequential k within the panel
      const float a = As[kk][r_loc];
      const float4 b = *(const float4*)&Bs[kk][cg * 4];
      part[0] = __builtin_fmaf(a, b.x, part[0]);
      part[1] = __builtin_fmaf(a, b.y, part[1]);
      part[2] = __builtin_fmaf(a, b.z, part[2]);
      part[3] = __builtin_fmaf(a, b.w, part[3]);
    }
  }
  #pragma unroll
  for (int i = 0; i < 4; ++i) total[i] = total[i] + part[i];  // final panel join
  #pragma unroll
  for (int i = 0; i < 4; ++i) {
    const int c = col0 + cg * 4 + i;
    C[(size_t)(row0 + r_loc) * N + c] = total[i] + bias[c];  // np: matmul then +b
  }
}

// ---------------------------------------------------------------------------
// numpy pairwise_sum emulation of sum(x*x) over rows of 1024:
// 8 leaves of 128 (8-accumulator unroll), tree ((L0+L1)+(L2+L3))+((L4+L5)+(L6+L7)).
// ---------------------------------------------------------------------------
__global__ __launch_bounds__(256) void sumsq1024_kernel(
    const float* __restrict__ X, float* __restrict__ out) {
  __shared__ float rows[4][1024];
  __shared__ float leaves[4][8];
  const int tid = threadIdx.x;
  const int row0 = blockIdx.x * 4;
  for (int i = tid; i < 4096; i += 256)
    rows[i >> 10][i & 1023] = X[(size_t)row0 * 1024 + i];
  __syncthreads();
  if (tid < 32) {
    const int r = tid >> 3, lf = tid & 7;
    const float* a = &rows[r][lf * 128];
    float s0 = sqf(a[0]), s1 = sqf(a[1]), s2 = sqf(a[2]), s3 = sqf(a[3]);
    float s4 = sqf(a[4]), s5 = sqf(a[5]), s6 = sqf(a[6]), s7 = sqf(a[7]);
    for (int i = 8; i < 128; i += 8) {
      s0 = s0 + sqf(a[i + 0]); s1 = s1 + sqf(a[i + 1]);
      s2 = s2 + sqf(a[i + 2]); s3 = s3 + sqf(a[i + 3]);
      s4 = s4 + sqf(a[i + 4]); s5 = s5 + sqf(a[i + 5]);
      s6 = s6 + sqf(a[i + 6]); s7 = s7 + sqf(a[i + 7]);
    }
    leaves[r][lf] = ((s0 + s1) + (s2 + s3)) + ((s4 + s5) + (s6 + s7));
  }
  __syncthreads();
  if (tid < 4) {
    const float* L = leaves[tid];
    const float p01 = L[0] + L[1], p23 = L[2] + L[3];
    const float p45 = L[4] + L[5], p67 = L[6] + L[7];
    out[row0 + tid] = ((p01 + p23) + (p45 + p67));
  }
}

// ---------------------------------------------------------------------------
// Emulated distance GEMM + per-64-entry-chunk first-index argmin.
// K=1024: panels 384,320,320 (mask 0x840). d = fma(-2,dot,z2) + c2.
// Block = 32 rows x 64 entries.
// ---------------------------------------------------------------------------
__global__ __launch_bounds__(256) void emul_dot_argmin_kernel(
    const float* __restrict__ Z, const float* __restrict__ CB,
    const float* __restrict__ Z2, const float* __restrict__ C2,
    float2* __restrict__ parts) {
  __shared__ float Zs[64][33];  // [kk][row]
  __shared__ float Cs[64][64];  // [kk][entry]
  __shared__ float shd[32][8];
  __shared__ int shi[32][8];
  const int tid = threadIdx.x;
  const int r_loc = tid >> 3;   // 0..31
  const int eg = tid & 7;       // 8 entries each
  const int row0 = blockIdx.y * 32;
  const int e0 = blockIdx.x * 64;

  const int za_r = tid >> 3, za_k = (tid & 7) * 8;    // 2 float4 (Z)
  const int ca_e = tid >> 2, ca_k = (tid & 3) * 16;   // 4 float4 (CB)

  float total[8], part[8];
  #pragma unroll
  for (int j = 0; j < 8; ++j) { total[j] = 0.f; part[j] = 0.f; }

  for (int ci = 0; ci < 16; ++ci) {
    const int k0 = ci << 6;
    if (ci && ((PANEL_MASK_K1024 >> ci) & 1u)) {  // joins at k=384, 704
      #pragma unroll
      for (int j = 0; j < 8; ++j) { total[j] = total[j] + part[j]; part[j] = 0.f; }
    }
    float4 zv[2], cv[4];
    #pragma unroll
    for (int q = 0; q < 2; ++q)
      zv[q] = *(const float4*)&Z[(size_t)(row0 + za_r) * 1024 + k0 + za_k + q * 4];
    #pragma unroll
    for (int q = 0; q < 4; ++q)
      cv[q] = *(const float4*)&CB[(size_t)(e0 + ca_e) * 1024 + k0 + ca_k + q * 4];
    __syncthreads();
    #pragma unroll
    for (int q = 0; q < 2; ++q) {
      Zs[za_k + q * 4 + 0][za_r] = zv[q].x;
      Zs[za_k + q * 4 + 1][za_r] = zv[q].y;
      Zs[za_k + q * 4 + 2][za_r] = zv[q].z;
      Zs[za_k + q * 4 + 3][za_r] = zv[q].w;
    }
    #pragma unroll
    for (int q = 0; q < 4; ++q) {
      Cs[ca_k + q * 4 + 0][ca_e] = cv[q].x;
      Cs[ca_k + q * 4 + 1][ca_e] = cv[q].y;
      Cs[ca_k + q * 4 + 2][ca_e] = cv[q].z;
      Cs[ca_k + q * 4 + 3][ca_e] = cv[q].w;
    }
    __syncthreads();
    for (int kk = 0; kk < 64; ++kk) {
      const float zval = Zs[kk][r_loc];
      const float4 c0 = *(const float4*)&Cs[kk][eg * 8];
      const float4 c1 = *(const float4*)&Cs[kk][eg * 8 + 4];
      part[0] = __builtin_fmaf(zval, c0.x, part[0]);
      part[1] = __builtin_fmaf(zval, c0.y, part[1]);
      part[2] = __builtin_fmaf(zval, c0.z, part[2]);
      part[3] = __builtin_fmaf(zval, c0.w, part[3]);
      part[4] = __builtin_fmaf(zval, c1.x, part[4]);
      part[5] = __builtin_fmaf(zval, c1.y, part[5]);
      part[6] = __builtin_fmaf(zval, c1.z, part[6]);
      part[7] = __builtin_fmaf(zval, c1.w, part[7]);
    }
  }
  #pragma unroll
  for (int j = 0; j < 8; ++j) total[j] = total[j] + part[j];  // final join

  const float z2r = Z2[row0 + r_loc];
  float bd = FLT_MAX;
  int be = 0;
  #pragma unroll
  for (int j = 0; j < 8; ++j) {
    const int e = e0 + eg * 8 + j;
    const float d1 = __builtin_fmaf(-2.0f, total[j], z2r);  // == fl(z2-2dot): 2*dot exact
    const float d = d1 + C2[e];
    if (d < bd) { bd = d; be = e; }  // strict <: lowest index wins
  }
  shd[r_loc][eg] = bd;
  shi[r_loc][eg] = be;
  __syncthreads();
  if (tid < 32) {  // scan eg ascending -> ascending entry order
    float v = shd[tid][0];
    int ix = shi[tid][0];
    #pragma unroll
    for (int g = 1; g < 8; ++g) {
      const float ov = shd[tid][g];
      if (ov < v) { v = ov; ix = shi[tid][g]; }
    }
    parts[(size_t)(row0 + tid) * 128 + blockIdx.x] =
        make_float2(v, __int_as_float(ix));
  }
}

__global__ __launch_bounds__(256) void rowmin_kernel(
    const float2* __restrict__ parts, int* __restrict__ ids,
    float* __restrict__ o_ids) {
  const int row = blockIdx.x * 256 + threadIdx.x;
  float bd = FLT_MAX;
  int bi = 0;
  for (int c = 0; c < 128; ++c) {  // ascending chunks + strict < = first index
    const float2 p = parts[(size_t)row * 128 + c];
    if (p.x < bd) { bd = p.x; bi = __float_as_int(p.y); }
  }
  ids[row] = bi;
  o_ids[row] = (float)bi;
}

__global__ __launch_bounds__(256) void gather_zq_kernel(
    const float* __restrict__ cb, const int* __restrict__ ids,
    float* __restrict__ zq) {
  const int row = blockIdx.x;
  const int id = ids[row];
  const float4 v = *(const float4*)&cb[(size_t)id * DIM + threadIdx.x * 4];
  *(float4*)&zq[(size_t)row * DIM + threadIdx.x * 4] = v;
}

__global__ __launch_bounds__(256) void rowdot_bias_kernel(
    const float* __restrict__ W, const float* __restrict__ v,
    const float* __restrict__ b2, float* __restrict__ out) {
  const int row = blockIdx.x;
  const float4 w4 = *(const float4*)&W[(size_t)row * 1024 + threadIdx.x * 4];
  const float4 v4 = *(const float4*)&v[threadIdx.x * 4];
  const float s = w4.x * v4.x + w4.y * v4.y + w4.z * v4.z + w4.w * v4.w;
  const float r = block_reduce_sum(s);
  if (threadIdx.x == 0) out[row] = r + b2[row];
}

__global__ __launch_bounds__(256) void sqdiff_partial_kernel(
    const float* __restrict__ a, const float* __restrict__ b,
    float* __restrict__ part) {
  const size_t base = (size_t)blockIdx.x * 2048 + (size_t)threadIdx.x * 8;
  const float4 x0 = *(const float4*)&a[base];
  const float4 x1 = *(const float4*)&a[base + 4];
  const float4 y0 = *(const float4*)&b[base];
  const float4 y1 = *(const float4*)&b[base + 4];
  float s = 0.f;
  float d;
  d = x0.x - y0.x; s += d * d; d = x0.y - y0.y; s += d * d;
  d = x0.z - y0.z; s += d * d; d = x0.w - y0.w; s += d * d;
  d = x1.x - y1.x; s += d * d; d = x1.y - y1.y; s += d * d;
  d = x1.z - y1.z; s += d * d; d = x1.w - y1.w; s += d * d;
  const float r = block_reduce_sum(s);
  if (threadIdx.x == 0) part[blockIdx.x] = r;
}

__global__ __launch_bounds__(256) void final_losses_kernel(
    const float* __restrict__ rp, const float* __restrict__ ep,
    float* __restrict__ o) {
  __shared__ double sh[4];
  const int lane = threadIdx.x & 63, w = threadIdx.x >> 6;
  double s = 0.0;
  for (int i = threadIdx.x; i < 8192; i += 256) s += (double)rp[i];
  #pragma unroll
  for (int off = 32; off > 0; off >>= 1) s += __shfl_down(s, off, 64);
  if (lane == 0) sh[w] = s;
  __syncthreads();
  double rl = 0.0;
  if (threadIdx.x == 0) rl = (sh[0] + sh[1] + sh[2] + sh[3]) / ((double)N_ROWS * IN_DIM);
  __syncthreads();
  double s2 = 0.0;
  for (int i = threadIdx.x; i < 4096; i += 256) s2 += (double)ep[i];
  #pragma unroll
  for (int off = 32; off > 0; off >>= 1) s2 += __shfl_down(s2, off, 64);
  if (lane == 0) sh[w] = s2;
  __syncthreads();
  if (threadIdx.x == 0) {
    const double el = (sh[0] + sh[1] + sh[2] + sh[3]) / ((double)N_ROWS * DIM);
    o[0] = (float)(rl + el + 0.25 * el);
    o[1] = (float)rl;
    o[2] = (float)el;
    o[3] = (float)el;
  }
}

extern "C" void kernel_launch(void* const* d_in, const int* in_sizes, int n_in,
                              void* d_out, int out_size, void* d_ws, size_t ws_size,
                              hipStream_t stream) {
  const float* roi   = (const float*)d_in[0];
  const float* W_in  = (const float*)d_in[1];
  const float* b_in  = (const float*)d_in[2];
  const float* W_enc = (const float*)d_in[3];
  const float* b_enc = (const float*)d_in[4];
  const float* cb    = (const float*)d_in[5];
  const float* W_dec = (const float*)d_in[6];
  const float* b_dec = (const float*)d_in[7];
  const float* W_out = (const float*)d_in[8];
  const float* b_out = (const float*)d_in[9];

  float* out = (float*)d_out;
  float* o_ids   = out;
  float* o_zq    = out + 8192;
  float* o_recon = out + 8192 + (size_t)N_ROWS * DIM;
  float* o_scal  = out + 8192 + (size_t)N_ROWS * DIM + (size_t)N_ROWS * IN_DIM;

  // ws layout (float offsets), total ~16.9 MB
  float*  ws    = (float*)d_ws;
  float*  W_dc  = ws;                          // 2,097,152
  float2* parts = (float2*)(ws + 2097152);     // 8192*128 float2 = 2,097,152 f
  float*  z2    = ws + 4194304;                // 8192
  float*  c2    = ws + 4202496;                // 8192
  int*    ids   = (int*)(ws + 4210688);        // 8192
  float*  b_dc  = ws + 4218880;                // 2048
  float*  ep    = ws + 4220928;                // 4096
  float*  rp    = ws + 4225024;                // 8192

  // t and z (f32, each 8192x1024) live in the o_recon region (16.8M floats).
  float* t = o_recon;
  float* z = o_recon + (size_t)N_ROWS * DIM;

  // decoder fusion (2%-threshold outputs)
  rowdot_bias_kernel<<<IN_DIM, 256, 0, stream>>>(W_out, b_dec, b_out, b_dc);
  gemm128<false><<<dim3(DIM / 128, IN_DIM / 128), 256, 0, stream>>>(
      W_out, W_dec, nullptr, W_dc, IN_DIM, DIM, DIM);

  // ---- np-f32 emulated encoder (corrected OpenBLAS kc panels) ----
  emul_gemm_kernel<<<dim3(DIM / 16, N_ROWS / 64), 256, 0, stream>>>(
      roi, W_in, b_in, t, DIM, IN_DIM, IN_DIM, IN_DIM, PANEL_MASK_K2048);
  emul_gemm_kernel<<<dim3(DIM / 16, N_ROWS / 64), 256, 0, stream>>>(
      t, W_enc, b_enc, z, DIM, DIM, DIM, DIM, PANEL_MASK_K1024);

  // ---- np pairwise row sums of squares ----
  sumsq1024_kernel<<<N_ROWS / 4, 256, 0, stream>>>(z, z2);
  sumsq1024_kernel<<<CBK / 4, 256, 0, stream>>>(cb, c2);

  // ---- emulated f32 distances + first-index argmin ----
  emul_dot_argmin_kernel<<<dim3(CBK / 64, N_ROWS / 32), 256, 0, stream>>>(
      z, cb, z2, c2, parts);
  rowmin_kernel<<<N_ROWS / 256, 256, 0, stream>>>(parts, ids, o_ids);

  // ---- outputs ----
  gather_zq_kernel<<<N_ROWS, 256, 0, stream>>>(cb, ids, o_zq);
  sqdiff_partial_kernel<<<(N_ROWS * DIM) / 2048, 256, 0, stream>>>(o_zq, z, ep);

  // recon (overwrites t/z region AFTER ep consumed z)
  gemm128<true><<<dim3(IN_DIM / 128, N_ROWS / 128), 256, 0, stream>>>(
      o_zq, W_dc, b_dc, o_recon, N_ROWS, IN_DIM, DIM);

  sqdiff_partial_kernel<<<(N_ROWS * IN_DIM) / 2048, 256, 0, stream>>>(
      o_recon, roi, rp);
  final_losses_kernel<<<1, 256, 0, stream>>>(rp, ep, o_scal);
}

// Round 8
// 2922.600 us; speedup vs baseline: 1.7368x; 1.7368x over previous
//
#include <hip/hip_runtime.h>
#include <float.h>

// ---------------------------------------------------------------------------
// VQ-VAE quantizer forward — round 8: same bit-exact numpy/OpenBLAS emulation
// semantics as round 7 (PASSED), optimized:
//  * emul_dot: 128x128 block, 8x8 microtile (1.0 B LDS / FMA, was 4.5),
//    [kk][*] LDS layouts with 2-way-max bank patterns, two-plane C tile.
//  * emul_gemm: 128x64 block, 8x4 microtile (1.5 B/FMA, was 5).
//  Chain semantics preserved exactly: sequential-k fmaf per output element,
//  panel joins at k=384,704 (K=1024) and 384,768,1152,1536,1792 (K=2048).
// ---------------------------------------------------------------------------

#define N_ROWS 8192
#define IN_DIM 2048
#define DIM 1024
#define CBK 8192

// chunk=64 masks (emul_gemm)
#define PANEL_MASK_K1024_C64 0x00000840u
#define PANEL_MASK_K2048_C64 0x11041040u
// chunk=32 mask (emul_dot, K=1024): joins at chunk 12 (k=384), 22 (k=704)
#define PANEL_MASK_K1024_C32 0x00401000u

__device__ __forceinline__ float sqf(float v) { return __builtin_fmaf(v, v, 0.0f); }

__device__ __forceinline__ int swz128(int c) {
  return (c & 3) | (((c >> 3) & 7) << 2) | (((c >> 2) & 1) << 5) | ((c >> 6) << 6);
}

__device__ __forceinline__ float block_reduce_sum(float v) {
  __shared__ float sh[4];
  #pragma unroll
  for (int off = 32; off > 0; off >>= 1) v += __shfl_down(v, off, 64);
  const int lane = threadIdx.x & 63, w = threadIdx.x >> 6;
  if (lane == 0) sh[w] = v;
  __syncthreads();
  float r = 0.f;
  if (threadIdx.x == 0) r = sh[0] + sh[1] + sh[2] + sh[3];
  return r;  // valid on thread 0 only
}

// ---------------------------------------------------------------------------
// fp32 128x128x16 tiled GEMM (decoder path: W_dc fusion + recon). 2% thresh.
// ---------------------------------------------------------------------------
template <bool BT>
__global__ __launch_bounds__(256) void gemm128(
    const float* __restrict__ A, const float* __restrict__ B,
    const float* __restrict__ bias, float* __restrict__ C,
    int M, int N, int K) {
  __shared__ float As[16][132];
  __shared__ float Bs[16][132];
  const int tid = threadIdx.x;
  const int tx = tid & 15, ty = tid >> 4;
  const int bm = blockIdx.y, bn = blockIdx.x;

  const int mload = tid & 127, kh = tid >> 7;
  const size_t arow = (size_t)(bm * 128 + mload) * (size_t)K;
  const size_t brow = BT ? (size_t)(bn * 128 + mload) * (size_t)K : 0;
  const int swn = swz128(mload);
  const int c4 = (tid & 31) << 2;
  const int kr = tid >> 5;
  const int swc = swz128(c4);

  float acc[8][8];
  #pragma unroll
  for (int r = 0; r < 8; ++r)
    #pragma unroll
    for (int c = 0; c < 8; ++c) acc[r][c] = 0.f;

  const int boff = ((tx & 7) << 2) | ((tx >> 3) << 6);

  for (int k0 = 0; k0 < K; k0 += 16) {
    const float4 av0 = *(const float4*)&A[arow + k0 + kh * 8];
    const float4 av1 = *(const float4*)&A[arow + k0 + kh * 8 + 4];
    float4 bv0, bv1;
    if (BT) {
      bv0 = *(const float4*)&B[brow + k0 + kh * 8];
      bv1 = *(const float4*)&B[brow + k0 + kh * 8 + 4];
    } else {
      bv0 = *(const float4*)&B[(size_t)(k0 + kr) * N + bn * 128 + c4];
      bv1 = *(const float4*)&B[(size_t)(k0 + kr + 8) * N + bn * 128 + c4];
    }
    __syncthreads();
    As[kh * 8 + 0][mload] = av0.x; As[kh * 8 + 1][mload] = av0.y;
    As[kh * 8 + 2][mload] = av0.z; As[kh * 8 + 3][mload] = av0.w;
    As[kh * 8 + 4][mload] = av1.x; As[kh * 8 + 5][mload] = av1.y;
    As[kh * 8 + 6][mload] = av1.z; As[kh * 8 + 7][mload] = av1.w;
    if (BT) {
      Bs[kh * 8 + 0][swn] = bv0.x; Bs[kh * 8 + 1][swn] = bv0.y;
      Bs[kh * 8 + 2][swn] = bv0.z; Bs[kh * 8 + 3][swn] = bv0.w;
      Bs[kh * 8 + 4][swn] = bv1.x; Bs[kh * 8 + 5][swn] = bv1.y;
      Bs[kh * 8 + 6][swn] = bv1.z; Bs[kh * 8 + 7][swn] = bv1.w;
    } else {
      *(float4*)&Bs[kr][swc] = bv0;
      *(float4*)&Bs[kr + 8][swc] = bv1;
    }
    __syncthreads();
    #pragma unroll
    for (int kk = 0; kk < 16; ++kk) {
      const float4 a0 = *(const float4*)&As[kk][ty * 8];
      const float4 a1 = *(const float4*)&As[kk][ty * 8 + 4];
      const float4 b0 = *(const float4*)&Bs[kk][boff];
      const float4 b1 = *(const float4*)&Bs[kk][boff + 32];
      const float ar[8] = {a0.x, a0.y, a0.z, a0.w, a1.x, a1.y, a1.z, a1.w};
      const float br[8] = {b0.x, b0.y, b0.z, b0.w, b1.x, b1.y, b1.z, b1.w};
      #pragma unroll
      for (int r = 0; r < 8; ++r)
        #pragma unroll
        for (int c = 0; c < 8; ++c) acc[r][c] = fmaf(ar[r], br[c], acc[r][c]);
    }
  }

  const int gcol = bn * 128 + tx * 8;
  float bb[8] = {0, 0, 0, 0, 0, 0, 0, 0};
  if (bias) {
    const float4 v0 = *(const float4*)&bias[gcol];
    const float4 v1 = *(const float4*)&bias[gcol + 4];
    bb[0] = v0.x; bb[1] = v0.y; bb[2] = v0.z; bb[3] = v0.w;
    bb[4] = v1.x; bb[5] = v1.y; bb[6] = v1.z; bb[7] = v1.w;
  }
  #pragma unroll
  for (int r = 0; r < 8; ++r) {
    float* cp = &C[(size_t)(bm * 128 + ty * 8 + r) * N + gcol];
    float4 o0, o1;
    o0.x = acc[r][0] + bb[0]; o0.y = acc[r][1] + bb[1];
    o0.z = acc[r][2] + bb[2]; o0.w = acc[r][3] + bb[3];
    o1.x = acc[r][4] + bb[4]; o1.y = acc[r][5] + bb[5];
    o1.z = acc[r][6] + bb[6]; o1.w = acc[r][7] + bb[7];
    *(float4*)cp = o0;
    *(float4*)(cp + 4) = o1;
  }
}

// ---------------------------------------------------------------------------
// OpenBLAS-emulating GEMM: C[M,N] = A[M,K]@B[N,K]^T + bias (bit-exact chains).
// Block 128 rows x 64 cols, 8x4 microtile. LDS [kk][row]/[kk][col]:
// staging writes 2-way, A-frag reads conflict-free, B-frag reads 2-way.
// ---------------------------------------------------------------------------
__global__ __launch_bounds__(256) void emul_gemm_kernel(
    const float* __restrict__ A, const float* __restrict__ B,
    const float* __restrict__ bias, float* __restrict__ C,
    int N, int K, int lda, int ldb, unsigned panel_mask) {
  __shared__ float As[64][128];
  __shared__ float Bs[64][64];
  const int tid = threadIdx.x;
  const int tx = tid & 15, ty = tid >> 4;
  const int row0 = blockIdx.y * 128, col0 = blockIdx.x * 64;
  const int sar = tid & 127, sah = tid >> 7;  // A stage: row, k-half(32)
  const int sbc = tid & 63, sbq = tid >> 6;   // B stage: col, k-quarter(16)

  float total[8][4], part[8][4];
  #pragma unroll
  for (int r = 0; r < 8; ++r)
    #pragma unroll
    for (int j = 0; j < 4; ++j) { total[r][j] = 0.f; part[r][j] = 0.f; }

  const int nch = K >> 6;
  for (int ci = 0; ci < nch; ++ci) {
    const int k0 = ci << 6;
    if (ci && ((panel_mask >> ci) & 1u)) {  // OpenBLAS kc panel boundary
      #pragma unroll
      for (int r = 0; r < 8; ++r)
        #pragma unroll
        for (int j = 0; j < 4; ++j) { total[r][j] = total[r][j] + part[r][j]; part[r][j] = 0.f; }
    }
    float4 av[8], bv[4];
    #pragma unroll
    for (int q = 0; q < 8; ++q)
      av[q] = *(const float4*)&A[(size_t)(row0 + sar) * lda + k0 + sah * 32 + q * 4];
    #pragma unroll
    for (int q = 0; q < 4; ++q)
      bv[q] = *(const float4*)&B[(size_t)(col0 + sbc) * ldb + k0 + sbq * 16 + q * 4];
    __syncthreads();
    #pragma unroll
    for (int q = 0; q < 8; ++q) {
      As[sah * 32 + q * 4 + 0][sar] = av[q].x;
      As[sah * 32 + q * 4 + 1][sar] = av[q].y;
      As[sah * 32 + q * 4 + 2][sar] = av[q].z;
      As[sah * 32 + q * 4 + 3][sar] = av[q].w;
    }
    #pragma unroll
    for (int q = 0; q < 4; ++q) {
      Bs[sbq * 16 + q * 4 + 0][sbc] = bv[q].x;
      Bs[sbq * 16 + q * 4 + 1][sbc] = bv[q].y;
      Bs[sbq * 16 + q * 4 + 2][sbc] = bv[q].z;
      Bs[sbq * 16 + q * 4 + 3][sbc] = bv[q].w;
    }
    __syncthreads();
    #pragma unroll 4
    for (int kk = 0; kk < 64; ++kk) {
      const float4 a0 = *(const float4*)&As[kk][ty * 8];
      const float4 a1 = *(const float4*)&As[kk][ty * 8 + 4];
      const float4 b0 = *(const float4*)&Bs[kk][tx * 4];
      const float ar[8] = {a0.x, a0.y, a0.z, a0.w, a1.x, a1.y, a1.z, a1.w};
      const float br[4] = {b0.x, b0.y, b0.z, b0.w};
      #pragma unroll
      for (int r = 0; r < 8; ++r)
        #pragma unroll
        for (int j = 0; j < 4; ++j)
          part[r][j] = __builtin_fmaf(ar[r], br[j], part[r][j]);
    }
  }
  #pragma unroll
  for (int r = 0; r < 8; ++r)
    #pragma unroll
    for (int j = 0; j < 4; ++j) total[r][j] = total[r][j] + part[r][j];

  const float4 bb = *(const float4*)&bias[col0 + tx * 4];
  #pragma unroll
  for (int r = 0; r < 8; ++r) {
    float4 o;
    o.x = total[r][0] + bb.x; o.y = total[r][1] + bb.y;
    o.z = total[r][2] + bb.z; o.w = total[r][3] + bb.w;
    *(float4*)&C[(size_t)(row0 + ty * 8 + r) * N + col0 + tx * 4] = o;
  }
}

// ---------------------------------------------------------------------------
// numpy pairwise_sum emulation of sum(x*x) over rows of 1024 (unchanged).
// ---------------------------------------------------------------------------
__global__ __launch_bounds__(256) void sumsq1024_kernel(
    const float* __restrict__ X, float* __restrict__ out) {
  __shared__ float rows[4][1024];
  __shared__ float leaves[4][8];
  const int tid = threadIdx.x;
  const int row0 = blockIdx.x * 4;
  for (int i = tid; i < 4096; i += 256)
    rows[i >> 10][i & 1023] = X[(size_t)row0 * 1024 + i];
  __syncthreads();
  if (tid < 32) {
    const int r = tid >> 3, lf = tid & 7;
    const float* a = &rows[r][lf * 128];
    float s0 = sqf(a[0]), s1 = sqf(a[1]), s2 = sqf(a[2]), s3 = sqf(a[3]);
    float s4 = sqf(a[4]), s5 = sqf(a[5]), s6 = sqf(a[6]), s7 = sqf(a[7]);
    for (int i = 8; i < 128; i += 8) {
      s0 = s0 + sqf(a[i + 0]); s1 = s1 + sqf(a[i + 1]);
      s2 = s2 + sqf(a[i + 2]); s3 = s3 + sqf(a[i + 3]);
      s4 = s4 + sqf(a[i + 4]); s5 = s5 + sqf(a[i + 5]);
      s6 = s6 + sqf(a[i + 6]); s7 = s7 + sqf(a[i + 7]);
    }
    leaves[r][lf] = ((s0 + s1) + (s2 + s3)) + ((s4 + s5) + (s6 + s7));
  }
  __syncthreads();
  if (tid < 4) {
    const float* L = leaves[tid];
    const float p01 = L[0] + L[1], p23 = L[2] + L[3];
    const float p45 = L[4] + L[5], p67 = L[6] + L[7];
    out[row0 + tid] = ((p01 + p23) + (p45 + p67));
  }
}

// ---------------------------------------------------------------------------
// Emulated distance GEMM + per-128-entry-chunk first-index argmin.
// Block 128 rows x 128 entries, 8x8 microtile, chunk=32 kk.
// LDS: Zs[kk][row] (reads conflict-free), Cs[kk][two-plane col] (reads 2-way).
// d = fma(-2,dot,z2)+c2; lexicographic (val,idx) reduce == np first-index.
// ---------------------------------------------------------------------------
__global__ __launch_bounds__(256) void emul_dot_argmin_kernel(
    const float* __restrict__ Z, const float* __restrict__ CB,
    const float* __restrict__ Z2, const float* __restrict__ C2,
    float2* __restrict__ parts) {
  __shared__ float Zs[32][128];
  __shared__ float Cs[32][128];
  const int tid = threadIdx.x;
  const int tx = tid & 15, ty = tid >> 4;
  const int row0 = blockIdx.y * 128, e0 = blockIdx.x * 128;
  const int sr = tid & 127, sh = tid >> 7;  // stage: row/entry, k-half(16)
  // two-plane column for entry sr: plane ((e>>2)&1), slot (e>>3)*4 + (e&3)
  const int scol = (((sr >> 2) & 1) << 6) + ((sr >> 3) << 2) + (sr & 3);

  float part[8][8], total[8][8];  // [row][entry]
  #pragma unroll
  for (int r = 0; r < 8; ++r)
    #pragma unroll
    for (int e = 0; e < 8; ++e) { part[r][e] = 0.f; total[r][e] = 0.f; }

  for (int ci = 0; ci < 32; ++ci) {
    const int k0 = ci << 5;
    if (ci && ((PANEL_MASK_K1024_C32 >> ci) & 1u)) {  // joins at k=384, 704
      #pragma unroll
      for (int r = 0; r < 8; ++r)
        #pragma unroll
        for (int e = 0; e < 8; ++e) { total[r][e] = total[r][e] + part[r][e]; part[r][e] = 0.f; }
    }
    float4 zv[4], cv[4];
    #pragma unroll
    for (int q = 0; q < 4; ++q)
      zv[q] = *(const float4*)&Z[(size_t)(row0 + sr) * 1024 + k0 + sh * 16 + q * 4];
    #pragma unroll
    for (int q = 0; q < 4; ++q)
      cv[q] = *(const float4*)&CB[(size_t)(e0 + sr) * 1024 + k0 + sh * 16 + q * 4];
    __syncthreads();
    #pragma unroll
    for (int q = 0; q < 4; ++q) {
      Zs[sh * 16 + q * 4 + 0][sr] = zv[q].x;
      Zs[sh * 16 + q * 4 + 1][sr] = zv[q].y;
      Zs[sh * 16 + q * 4 + 2][sr] = zv[q].z;
      Zs[sh * 16 + q * 4 + 3][sr] = zv[q].w;
    }
    #pragma unroll
    for (int q = 0; q < 4; ++q) {
      Cs[sh * 16 + q * 4 + 0][scol] = cv[q].x;
      Cs[sh * 16 + q * 4 + 1][scol] = cv[q].y;
      Cs[sh * 16 + q * 4 + 2][scol] = cv[q].z;
      Cs[sh * 16 + q * 4 + 3][scol] = cv[q].w;
    }
    __syncthreads();
    #pragma unroll 4
    for (int kk = 0; kk < 32; ++kk) {
      const float4 za = *(const float4*)&Zs[kk][ty * 8];
      const float4 zb = *(const float4*)&Zs[kk][ty * 8 + 4];
      const float4 ca = *(const float4*)&Cs[kk][tx * 4];        // entries tx*8+0..3
      const float4 cb4 = *(const float4*)&Cs[kk][64 + tx * 4];  // entries tx*8+4..7
      const float zr[8] = {za.x, za.y, za.z, za.w, zb.x, zb.y, zb.z, zb.w};
      const float cr[8] = {ca.x, ca.y, ca.z, ca.w, cb4.x, cb4.y, cb4.z, cb4.w};
      #pragma unroll
      for (int r = 0; r < 8; ++r)
        #pragma unroll
        for (int e = 0; e < 8; ++e)
          part[r][e] = __builtin_fmaf(zr[r], cr[e], part[r][e]);
    }
  }
  #pragma unroll
  for (int r = 0; r < 8; ++r)
    #pragma unroll
    for (int e = 0; e < 8; ++e) total[r][e] = total[r][e] + part[r][e];

  const float4 c2a = *(const float4*)&C2[e0 + tx * 8];
  const float4 c2b = *(const float4*)&C2[e0 + tx * 8 + 4];
  const float c2r[8] = {c2a.x, c2a.y, c2a.z, c2a.w, c2b.x, c2b.y, c2b.z, c2b.w};
  #pragma unroll
  for (int rr = 0; rr < 8; ++rr) {
    const int row = row0 + ty * 8 + rr;
    const float z2r = Z2[row];
    float bd = FLT_MAX;
    int be = 0;
    #pragma unroll
    for (int j = 0; j < 8; ++j) {  // ascending entries; strict < = first index
      const float d = __builtin_fmaf(-2.0f, total[rr][j], z2r) + c2r[j];
      if (d < bd) { bd = d; be = e0 + tx * 8 + j; }
    }
    #pragma unroll
    for (int m = 1; m < 16; m <<= 1) {  // lexicographic min across 16 tx lanes
      const float od = __shfl_xor(bd, m, 64);
      const int oe = __shfl_xor(be, m, 64);
      if (od < bd || (od == bd && oe < be)) { bd = od; be = oe; }
    }
    if (tx == 0)
      parts[(size_t)row * 64 + blockIdx.x] = make_float2(bd, __int_as_float(be));
  }
}

__global__ __launch_bounds__(256) void rowmin_kernel(
    const float2* __restrict__ parts, int* __restrict__ ids,
    float* __restrict__ o_ids) {
  const int row = blockIdx.x * 256 + threadIdx.x;
  float bd = FLT_MAX;
  int bi = 0;
  for (int c = 0; c < 64; ++c) {  // ascending chunks + strict < = first index
    const float2 p = parts[(size_t)row * 64 + c];
    if (p.x < bd) { bd = p.x; bi = __float_as_int(p.y); }
  }
  ids[row] = bi;
  o_ids[row] = (float)bi;
}

__global__ __launch_bounds__(256) void gather_zq_kernel(
    const float* __restrict__ cb, const int* __restrict__ ids,
    float* __restrict__ zq) {
  const int row = blockIdx.x;
  const int id = ids[row];
  const float4 v = *(const float4*)&cb[(size_t)id * DIM + threadIdx.x * 4];
  *(float4*)&zq[(size_t)row * DIM + threadIdx.x * 4] = v;
}

__global__ __launch_bounds__(256) void rowdot_bias_kernel(
    const float* __restrict__ W, const float* __restrict__ v,
    const float* __restrict__ b2, float* __restrict__ out) {
  const int row = blockIdx.x;
  const float4 w4 = *(const float4*)&W[(size_t)row * 1024 + threadIdx.x * 4];
  const float4 v4 = *(const float4*)&v[threadIdx.x * 4];
  const float s = w4.x * v4.x + w4.y * v4.y + w4.z * v4.z + w4.w * v4.w;
  const float r = block_reduce_sum(s);
  if (threadIdx.x == 0) out[row] = r + b2[row];
}

__global__ __launch_bounds__(256) void sqdiff_partial_kernel(
    const float* __restrict__ a, const float* __restrict__ b,
    float* __restrict__ part) {
  const size_t base = (size_t)blockIdx.x * 2048 + (size_t)threadIdx.x * 8;
  const float4 x0 = *(const float4*)&a[base];
  const float4 x1 = *(const float4*)&a[base + 4];
  const float4 y0 = *(const float4*)&b[base];
  const float4 y1 = *(const float4*)&b[base + 4];
  float s = 0.f;
  float d;
  d = x0.x - y0.x; s += d * d; d = x0.y - y0.y; s += d * d;
  d = x0.z - y0.z; s += d * d; d = x0.w - y0.w; s += d * d;
  d = x1.x - y1.x; s += d * d; d = x1.y - y1.y; s += d * d;
  d = x1.z - y1.z; s += d * d; d = x1.w - y1.w; s += d * d;
  const float r = block_reduce_sum(s);
  if (threadIdx.x == 0) part[blockIdx.x] = r;
}

__global__ __launch_bounds__(256) void final_losses_kernel(
    const float* __restrict__ rp, const float* __restrict__ ep,
    float* __restrict__ o) {
  __shared__ double sh[4];
  const int lane = threadIdx.x & 63, w = threadIdx.x >> 6;
  double s = 0.0;
  for (int i = threadIdx.x; i < 8192; i += 256) s += (double)rp[i];
  #pragma unroll
  for (int off = 32; off > 0; off >>= 1) s += __shfl_down(s, off, 64);
  if (lane == 0) sh[w] = s;
  __syncthreads();
  double rl = 0.0;
  if (threadIdx.x == 0) rl = (sh[0] + sh[1] + sh[2] + sh[3]) / ((double)N_ROWS * IN_DIM);
  __syncthreads();
  double s2 = 0.0;
  for (int i = threadIdx.x; i < 4096; i += 256) s2 += (double)ep[i];
  #pragma unroll
  for (int off = 32; off > 0; off >>= 1) s2 += __shfl_down(s2, off, 64);
  if (lane == 0) sh[w] = s2;
  __syncthreads();
  if (threadIdx.x == 0) {
    const double el = (sh[0] + sh[1] + sh[2] + sh[3]) / ((double)N_ROWS * DIM);
    o[0] = (float)(rl + el + 0.25 * el);
    o[1] = (float)rl;
    o[2] = (float)el;
    o[3] = (float)el;
  }
}

extern "C" void kernel_launch(void* const* d_in, const int* in_sizes, int n_in,
                              void* d_out, int out_size, void* d_ws, size_t ws_size,
                              hipStream_t stream) {
  const float* roi   = (const float*)d_in[0];
  const float* W_in  = (const float*)d_in[1];
  const float* b_in  = (const float*)d_in[2];
  const float* W_enc = (const float*)d_in[3];
  const float* b_enc = (const float*)d_in[4];
  const float* cb    = (const float*)d_in[5];
  const float* W_dec = (const float*)d_in[6];
  const float* b_dec = (const float*)d_in[7];
  const float* W_out = (const float*)d_in[8];
  const float* b_out = (const float*)d_in[9];

  float* out = (float*)d_out;
  float* o_ids   = out;
  float* o_zq    = out + 8192;
  float* o_recon = out + 8192 + (size_t)N_ROWS * DIM;
  float* o_scal  = out + 8192 + (size_t)N_ROWS * DIM + (size_t)N_ROWS * IN_DIM;

  // ws layout (float offsets)
  float*  ws    = (float*)d_ws;
  float*  W_dc  = ws;                          // 2,097,152
  float2* parts = (float2*)(ws + 2097152);     // 8192*64 float2 = 1,048,576 f
  float*  z2    = ws + 4194304;                // 8192
  float*  c2    = ws + 4202496;                // 8192
  int*    ids   = (int*)(ws + 4210688);        // 8192
  float*  b_dc  = ws + 4218880;                // 2048
  float*  ep    = ws + 4220928;                // 4096
  float*  rp    = ws + 4225024;                // 8192

  // t and z (f32, each 8192x1024) live in the o_recon region (16.8M floats).
  float* t = o_recon;
  float* z = o_recon + (size_t)N_ROWS * DIM;

  // decoder fusion (2%-threshold outputs)
  rowdot_bias_kernel<<<IN_DIM, 256, 0, stream>>>(W_out, b_dec, b_out, b_dc);
  gemm128<false><<<dim3(DIM / 128, IN_DIM / 128), 256, 0, stream>>>(
      W_out, W_dec, nullptr, W_dc, IN_DIM, DIM, DIM);

  // ---- np-f32 emulated encoder (bit-exact chains, new tiling) ----
  emul_gemm_kernel<<<dim3(DIM / 64, N_ROWS / 128), 256, 0, stream>>>(
      roi, W_in, b_in, t, DIM, IN_DIM, IN_DIM, IN_DIM, PANEL_MASK_K2048_C64);
  emul_gemm_kernel<<<dim3(DIM / 64, N_ROWS / 128), 256, 0, stream>>>(
      t, W_enc, b_enc, z, DIM, DIM, DIM, DIM, PANEL_MASK_K1024_C64);

  // ---- np pairwise row sums of squares ----
  sumsq1024_kernel<<<N_ROWS / 4, 256, 0, stream>>>(z, z2);
  sumsq1024_kernel<<<CBK / 4, 256, 0, stream>>>(cb, c2);

  // ---- emulated f32 distances + first-index argmin ----
  emul_dot_argmin_kernel<<<dim3(CBK / 128, N_ROWS / 128), 256, 0, stream>>>(
      z, cb, z2, c2, parts);
  rowmin_kernel<<<N_ROWS / 256, 256, 0, stream>>>(parts, ids, o_ids);

  // ---- outputs ----
  gather_zq_kernel<<<N_ROWS, 256, 0, stream>>>(cb, ids, o_zq);
  sqdiff_partial_kernel<<<(N_ROWS * DIM) / 2048, 256, 0, stream>>>(o_zq, z, ep);

  // recon (overwrites t/z region AFTER ep consumed z)
  gemm128<true><<<dim3(IN_DIM / 128, N_ROWS / 128), 256, 0, stream>>>(
      o_zq, W_dc, b_dc, o_recon, N_ROWS, IN_DIM, DIM);

  sqdiff_partial_kernel<<<(N_ROWS * IN_DIM) / 2048, 256, 0, stream>>>(
      o_recon, roi, rp);
  final_losses_kernel<<<1, 256, 0, stream>>>(rp, ep, o_scal);
}

// Round 9
// 2903.528 us; speedup vs baseline: 1.7482x; 1.0066x over previous
//
#include <hip/hip_runtime.h>
#include <float.h>

// ---------------------------------------------------------------------------
// VQ-VAE quantizer forward — round 9: round-8 semantics (PASSED, bit-exact
// numpy/OpenBLAS emulation on the ids path) + register-prefetch software
// pipelining in all GEMM-shaped kernels: next tile's global loads issue
// BEFORE the current tile's compute, hiding L2/HBM latency under the FMAs.
// Chain semantics unchanged: sequential-k fmaf per element, panel joins at
// k=384,704 (K=1024) and 384,768,1152,1536,1792 (K=2048).
// ---------------------------------------------------------------------------

#define N_ROWS 8192
#define IN_DIM 2048
#define DIM 1024
#define CBK 8192

// chunk=64 masks (emul_gemm)
#define PANEL_MASK_K1024_C64 0x00000840u
#define PANEL_MASK_K2048_C64 0x11041040u
// chunk=32 mask (emul_dot, K=1024): joins at chunk 12 (k=384), 22 (k=704)
#define PANEL_MASK_K1024_C32 0x00401000u

__device__ __forceinline__ float sqf(float v) { return __builtin_fmaf(v, v, 0.0f); }

__device__ __forceinline__ int swz128(int c) {
  return (c & 3) | (((c >> 3) & 7) << 2) | (((c >> 2) & 1) << 5) | ((c >> 6) << 6);
}

__device__ __forceinline__ float block_reduce_sum(float v) {
  __shared__ float sh[4];
  #pragma unroll
  for (int off = 32; off > 0; off >>= 1) v += __shfl_down(v, off, 64);
  const int lane = threadIdx.x & 63, w = threadIdx.x >> 6;
  if (lane == 0) sh[w] = v;
  __syncthreads();
  float r = 0.f;
  if (threadIdx.x == 0) r = sh[0] + sh[1] + sh[2] + sh[3];
  return r;  // valid on thread 0 only
}

// ---------------------------------------------------------------------------
// fp32 128x128x16 tiled GEMM (decoder path: W_dc fusion + recon). 2% thresh.
// Register-prefetch pipelined.
// ---------------------------------------------------------------------------
template <bool BT>
__global__ __launch_bounds__(256) void gemm128(
    const float* __restrict__ A, const float* __restrict__ B,
    const float* __restrict__ bias, float* __restrict__ C,
    int M, int N, int K) {
  __shared__ float As[16][132];
  __shared__ float Bs[16][132];
  const int tid = threadIdx.x;
  const int tx = tid & 15, ty = tid >> 4;
  const int bm = blockIdx.y, bn = blockIdx.x;

  const int mload = tid & 127, kh = tid >> 7;
  const size_t arow = (size_t)(bm * 128 + mload) * (size_t)K;
  const size_t brow = BT ? (size_t)(bn * 128 + mload) * (size_t)K : 0;
  const int swn = swz128(mload);
  const int c4 = (tid & 31) << 2;
  const int kr = tid >> 5;
  const int swc = swz128(c4);

  float acc[8][8];
  #pragma unroll
  for (int r = 0; r < 8; ++r)
    #pragma unroll
    for (int c = 0; c < 8; ++c) acc[r][c] = 0.f;

  const int boff = ((tx & 7) << 2) | ((tx >> 3) << 6);

  float4 av0, av1, bv0, bv1;
  // initial load (k0 = 0)
  av0 = *(const float4*)&A[arow + kh * 8];
  av1 = *(const float4*)&A[arow + kh * 8 + 4];
  if (BT) {
    bv0 = *(const float4*)&B[brow + kh * 8];
    bv1 = *(const float4*)&B[brow + kh * 8 + 4];
  } else {
    bv0 = *(const float4*)&B[(size_t)kr * N + bn * 128 + c4];
    bv1 = *(const float4*)&B[(size_t)(kr + 8) * N + bn * 128 + c4];
  }

  for (int k0 = 0; k0 < K; k0 += 16) {
    __syncthreads();
    As[kh * 8 + 0][mload] = av0.x; As[kh * 8 + 1][mload] = av0.y;
    As[kh * 8 + 2][mload] = av0.z; As[kh * 8 + 3][mload] = av0.w;
    As[kh * 8 + 4][mload] = av1.x; As[kh * 8 + 5][mload] = av1.y;
    As[kh * 8 + 6][mload] = av1.z; As[kh * 8 + 7][mload] = av1.w;
    if (BT) {
      Bs[kh * 8 + 0][swn] = bv0.x; Bs[kh * 8 + 1][swn] = bv0.y;
      Bs[kh * 8 + 2][swn] = bv0.z; Bs[kh * 8 + 3][swn] = bv0.w;
      Bs[kh * 8 + 4][swn] = bv1.x; Bs[kh * 8 + 5][swn] = bv1.y;
      Bs[kh * 8 + 6][swn] = bv1.z; Bs[kh * 8 + 7][swn] = bv1.w;
    } else {
      *(float4*)&Bs[kr][swc] = bv0;
      *(float4*)&Bs[kr + 8][swc] = bv1;
    }
    __syncthreads();
    const int k1 = k0 + 16;
    if (k1 < K) {  // prefetch next tile: latency hides under compute below
      av0 = *(const float4*)&A[arow + k1 + kh * 8];
      av1 = *(const float4*)&A[arow + k1 + kh * 8 + 4];
      if (BT) {
        bv0 = *(const float4*)&B[brow + k1 + kh * 8];
        bv1 = *(const float4*)&B[brow + k1 + kh * 8 + 4];
      } else {
        bv0 = *(const float4*)&B[(size_t)(k1 + kr) * N + bn * 128 + c4];
        bv1 = *(const float4*)&B[(size_t)(k1 + kr + 8) * N + bn * 128 + c4];
      }
    }
    #pragma unroll
    for (int kk = 0; kk < 16; ++kk) {
      const float4 a0 = *(const float4*)&As[kk][ty * 8];
      const float4 a1 = *(const float4*)&As[kk][ty * 8 + 4];
      const float4 b0 = *(const float4*)&Bs[kk][boff];
      const float4 b1 = *(const float4*)&Bs[kk][boff + 32];
      const float ar[8] = {a0.x, a0.y, a0.z, a0.w, a1.x, a1.y, a1.z, a1.w};
      const float br[8] = {b0.x, b0.y, b0.z, b0.w, b1.x, b1.y, b1.z, b1.w};
      #pragma unroll
      for (int r = 0; r < 8; ++r)
        #pragma unroll
        for (int c = 0; c < 8; ++c) acc[r][c] = fmaf(ar[r], br[c], acc[r][c]);
    }
  }

  const int gcol = bn * 128 + tx * 8;
  float bb[8] = {0, 0, 0, 0, 0, 0, 0, 0};
  if (bias) {
    const float4 v0 = *(const float4*)&bias[gcol];
    const float4 v1 = *(const float4*)&bias[gcol + 4];
    bb[0] = v0.x; bb[1] = v0.y; bb[2] = v0.z; bb[3] = v0.w;
    bb[4] = v1.x; bb[5] = v1.y; bb[6] = v1.z; bb[7] = v1.w;
  }
  #pragma unroll
  for (int r = 0; r < 8; ++r) {
    float* cp = &C[(size_t)(bm * 128 + ty * 8 + r) * N + gcol];
    float4 o0, o1;
    o0.x = acc[r][0] + bb[0]; o0.y = acc[r][1] + bb[1];
    o0.z = acc[r][2] + bb[2]; o0.w = acc[r][3] + bb[3];
    o1.x = acc[r][4] + bb[4]; o1.y = acc[r][5] + bb[5];
    o1.z = acc[r][6] + bb[6]; o1.w = acc[r][7] + bb[7];
    *(float4*)cp = o0;
    *(float4*)(cp + 4) = o1;
  }
}

// ---------------------------------------------------------------------------
// OpenBLAS-emulating GEMM: C[M,N] = A[M,K]@B[N,K]^T + bias (bit-exact chains).
// Block 128 rows x 64 cols, 8x4 microtile, register-prefetch pipelined.
// ---------------------------------------------------------------------------
__global__ __launch_bounds__(256) void emul_gemm_kernel(
    const float* __restrict__ A, const float* __restrict__ B,
    const float* __restrict__ bias, float* __restrict__ C,
    int N, int K, int lda, int ldb, unsigned panel_mask) {
  __shared__ float As[64][128];
  __shared__ float Bs[64][64];
  const int tid = threadIdx.x;
  const int tx = tid & 15, ty = tid >> 4;
  const int row0 = blockIdx.y * 128, col0 = blockIdx.x * 64;
  const int sar = tid & 127, sah = tid >> 7;  // A stage: row, k-half(32)
  const int sbc = tid & 63, sbq = tid >> 6;   // B stage: col, k-quarter(16)

  float total[8][4], part[8][4];
  #pragma unroll
  for (int r = 0; r < 8; ++r)
    #pragma unroll
    for (int j = 0; j < 4; ++j) { total[r][j] = 0.f; part[r][j] = 0.f; }

  float4 av[8], bv[4];
  #pragma unroll
  for (int q = 0; q < 8; ++q)
    av[q] = *(const float4*)&A[(size_t)(row0 + sar) * lda + sah * 32 + q * 4];
  #pragma unroll
  for (int q = 0; q < 4; ++q)
    bv[q] = *(const float4*)&B[(size_t)(col0 + sbc) * ldb + sbq * 16 + q * 4];

  const int nch = K >> 6;
  for (int ci = 0; ci < nch; ++ci) {
    __syncthreads();
    #pragma unroll
    for (int q = 0; q < 8; ++q) {
      As[sah * 32 + q * 4 + 0][sar] = av[q].x;
      As[sah * 32 + q * 4 + 1][sar] = av[q].y;
      As[sah * 32 + q * 4 + 2][sar] = av[q].z;
      As[sah * 32 + q * 4 + 3][sar] = av[q].w;
    }
    #pragma unroll
    for (int q = 0; q < 4; ++q) {
      Bs[sbq * 16 + q * 4 + 0][sbc] = bv[q].x;
      Bs[sbq * 16 + q * 4 + 1][sbc] = bv[q].y;
      Bs[sbq * 16 + q * 4 + 2][sbc] = bv[q].z;
      Bs[sbq * 16 + q * 4 + 3][sbc] = bv[q].w;
    }
    __syncthreads();
    if (ci + 1 < nch) {  // prefetch next chunk
      const int k1 = (ci + 1) << 6;
      #pragma unroll
      for (int q = 0; q < 8; ++q)
        av[q] = *(const float4*)&A[(size_t)(row0 + sar) * lda + k1 + sah * 32 + q * 4];
      #pragma unroll
      for (int q = 0; q < 4; ++q)
        bv[q] = *(const float4*)&B[(size_t)(col0 + sbc) * ldb + k1 + sbq * 16 + q * 4];
    }
    if (ci && ((panel_mask >> ci) & 1u)) {  // OpenBLAS kc panel boundary
      #pragma unroll
      for (int r = 0; r < 8; ++r)
        #pragma unroll
        for (int j = 0; j < 4; ++j) { total[r][j] = total[r][j] + part[r][j]; part[r][j] = 0.f; }
    }
    #pragma unroll 4
    for (int kk = 0; kk < 64; ++kk) {
      const float4 a0 = *(const float4*)&As[kk][ty * 8];
      const float4 a1 = *(const float4*)&As[kk][ty * 8 + 4];
      const float4 b0 = *(const float4*)&Bs[kk][tx * 4];
      const float ar[8] = {a0.x, a0.y, a0.z, a0.w, a1.x, a1.y, a1.z, a1.w};
      const float br[4] = {b0.x, b0.y, b0.z, b0.w};
      #pragma unroll
      for (int r = 0; r < 8; ++r)
        #pragma unroll
        for (int j = 0; j < 4; ++j)
          part[r][j] = __builtin_fmaf(ar[r], br[j], part[r][j]);
    }
  }
  #pragma unroll
  for (int r = 0; r < 8; ++r)
    #pragma unroll
    for (int j = 0; j < 4; ++j) total[r][j] = total[r][j] + part[r][j];

  const float4 bb = *(const float4*)&bias[col0 + tx * 4];
  #pragma unroll
  for (int r = 0; r < 8; ++r) {
    float4 o;
    o.x = total[r][0] + bb.x; o.y = total[r][1] + bb.y;
    o.z = total[r][2] + bb.z; o.w = total[r][3] + bb.w;
    *(float4*)&C[(size_t)(row0 + ty * 8 + r) * N + col0 + tx * 4] = o;
  }
}

// ---------------------------------------------------------------------------
// numpy pairwise_sum emulation of sum(x*x) over rows of 1024 (unchanged).
// ---------------------------------------------------------------------------
__global__ __launch_bounds__(256) void sumsq1024_kernel(
    const float* __restrict__ X, float* __restrict__ out) {
  __shared__ float rows[4][1024];
  __shared__ float leaves[4][8];
  const int tid = threadIdx.x;
  const int row0 = blockIdx.x * 4;
  for (int i = tid; i < 4096; i += 256)
    rows[i >> 10][i & 1023] = X[(size_t)row0 * 1024 + i];
  __syncthreads();
  if (tid < 32) {
    const int r = tid >> 3, lf = tid & 7;
    const float* a = &rows[r][lf * 128];
    float s0 = sqf(a[0]), s1 = sqf(a[1]), s2 = sqf(a[2]), s3 = sqf(a[3]);
    float s4 = sqf(a[4]), s5 = sqf(a[5]), s6 = sqf(a[6]), s7 = sqf(a[7]);
    for (int i = 8; i < 128; i += 8) {
      s0 = s0 + sqf(a[i + 0]); s1 = s1 + sqf(a[i + 1]);
      s2 = s2 + sqf(a[i + 2]); s3 = s3 + sqf(a[i + 3]);
      s4 = s4 + sqf(a[i + 4]); s5 = s5 + sqf(a[i + 5]);
      s6 = s6 + sqf(a[i + 6]); s7 = s7 + sqf(a[i + 7]);
    }
    leaves[r][lf] = ((s0 + s1) + (s2 + s3)) + ((s4 + s5) + (s6 + s7));
  }
  __syncthreads();
  if (tid < 4) {
    const float* L = leaves[tid];
    const float p01 = L[0] + L[1], p23 = L[2] + L[3];
    const float p45 = L[4] + L[5], p67 = L[6] + L[7];
    out[row0 + tid] = ((p01 + p23) + (p45 + p67));
  }
}

// ---------------------------------------------------------------------------
// Emulated distance GEMM + per-128-entry-chunk first-index argmin.
// Block 128 rows x 128 entries, 8x8 microtile, chunk=32 kk, reg-prefetch.
// ---------------------------------------------------------------------------
__global__ __launch_bounds__(256) void emul_dot_argmin_kernel(
    const float* __restrict__ Z, const float* __restrict__ CB,
    const float* __restrict__ Z2, const float* __restrict__ C2,
    float2* __restrict__ parts) {
  __shared__ float Zs[32][128];
  __shared__ float Cs[32][128];
  const int tid = threadIdx.x;
  const int tx = tid & 15, ty = tid >> 4;
  const int row0 = blockIdx.y * 128, e0 = blockIdx.x * 128;
  const int sr = tid & 127, sh = tid >> 7;  // stage: row/entry, k-half(16)
  const int scol = (((sr >> 2) & 1) << 6) + ((sr >> 3) << 2) + (sr & 3);

  float part[8][8], total[8][8];  // [row][entry]
  #pragma unroll
  for (int r = 0; r < 8; ++r)
    #pragma unroll
    for (int e = 0; e < 8; ++e) { part[r][e] = 0.f; total[r][e] = 0.f; }

  float4 zv[4], cv[4];
  #pragma unroll
  for (int q = 0; q < 4; ++q) {
    zv[q] = *(const float4*)&Z[(size_t)(row0 + sr) * 1024 + sh * 16 + q * 4];
    cv[q] = *(const float4*)&CB[(size_t)(e0 + sr) * 1024 + sh * 16 + q * 4];
  }

  for (int ci = 0; ci < 32; ++ci) {
    __syncthreads();
    #pragma unroll
    for (int q = 0; q < 4; ++q) {
      Zs[sh * 16 + q * 4 + 0][sr] = zv[q].x;
      Zs[sh * 16 + q * 4 + 1][sr] = zv[q].y;
      Zs[sh * 16 + q * 4 + 2][sr] = zv[q].z;
      Zs[sh * 16 + q * 4 + 3][sr] = zv[q].w;
    }
    #pragma unroll
    for (int q = 0; q < 4; ++q) {
      Cs[sh * 16 + q * 4 + 0][scol] = cv[q].x;
      Cs[sh * 16 + q * 4 + 1][scol] = cv[q].y;
      Cs[sh * 16 + q * 4 + 2][scol] = cv[q].z;
      Cs[sh * 16 + q * 4 + 3][scol] = cv[q].w;
    }
    __syncthreads();
    if (ci + 1 < 32) {  // prefetch next chunk under the compute below
      const int k1 = (ci + 1) << 5;
      #pragma unroll
      for (int q = 0; q < 4; ++q) {
        zv[q] = *(const float4*)&Z[(size_t)(row0 + sr) * 1024 + k1 + sh * 16 + q * 4];
        cv[q] = *(const float4*)&CB[(size_t)(e0 + sr) * 1024 + k1 + sh * 16 + q * 4];
      }
    }
    if (ci && ((PANEL_MASK_K1024_C32 >> ci) & 1u)) {  // joins at k=384, 704
      #pragma unroll
      for (int r = 0; r < 8; ++r)
        #pragma unroll
        for (int e = 0; e < 8; ++e) { total[r][e] = total[r][e] + part[r][e]; part[r][e] = 0.f; }
    }
    #pragma unroll 4
    for (int kk = 0; kk < 32; ++kk) {
      const float4 za = *(const float4*)&Zs[kk][ty * 8];
      const float4 zb = *(const float4*)&Zs[kk][ty * 8 + 4];
      const float4 ca = *(const float4*)&Cs[kk][tx * 4];
      const float4 cb4 = *(const float4*)&Cs[kk][64 + tx * 4];
      const float zr[8] = {za.x, za.y, za.z, za.w, zb.x, zb.y, zb.z, zb.w};
      const float cr[8] = {ca.x, ca.y, ca.z, ca.w, cb4.x, cb4.y, cb4.z, cb4.w};
      #pragma unroll
      for (int r = 0; r < 8; ++r)
        #pragma unroll
        for (int e = 0; e < 8; ++e)
          part[r][e] = __builtin_fmaf(zr[r], cr[e], part[r][e]);
    }
  }
  #pragma unroll
  for (int r = 0; r < 8; ++r)
    #pragma unroll
    for (int e = 0; e < 8; ++e) total[r][e] = total[r][e] + part[r][e];

  const float4 c2a = *(const float4*)&C2[e0 + tx * 8];
  const float4 c2b = *(const float4*)&C2[e0 + tx * 8 + 4];
  const float c2r[8] = {c2a.x, c2a.y, c2a.z, c2a.w, c2b.x, c2b.y, c2b.z, c2b.w};
  #pragma unroll
  for (int rr = 0; rr < 8; ++rr) {
    const int row = row0 + ty * 8 + rr;
    const float z2r = Z2[row];
    float bd = FLT_MAX;
    int be = 0;
    #pragma unroll
    for (int j = 0; j < 8; ++j) {  // ascending entries; strict < = first index
      const float d = __builtin_fmaf(-2.0f, total[rr][j], z2r) + c2r[j];
      if (d < bd) { bd = d; be = e0 + tx * 8 + j; }
    }
    #pragma unroll
    for (int m = 1; m < 16; m <<= 1) {  // lexicographic min across 16 tx lanes
      const float od = __shfl_xor(bd, m, 64);
      const int oe = __shfl_xor(be, m, 64);
      if (od < bd || (od == bd && oe < be)) { bd = od; be = oe; }
    }
    if (tx == 0)
      parts[(size_t)row * 64 + blockIdx.x] = make_float2(bd, __int_as_float(be));
  }
}

__global__ __launch_bounds__(256) void rowmin_kernel(
    const float2* __restrict__ parts, int* __restrict__ ids,
    float* __restrict__ o_ids) {
  const int row = blockIdx.x * 256 + threadIdx.x;
  float bd = FLT_MAX;
  int bi = 0;
  for (int c = 0; c < 64; ++c) {  // ascending chunks + strict < = first index
    const float2 p = parts[(size_t)row * 64 + c];
    if (p.x < bd) { bd = p.x; bi = __float_as_int(p.y); }
  }
  ids[row] = bi;
  o_ids[row] = (float)bi;
}

__global__ __launch_bounds__(256) void gather_zq_kernel(
    const float* __restrict__ cb, const int* __restrict__ ids,
    float* __restrict__ zq) {
  const int row = blockIdx.x;
  const int id = ids[row];
  const float4 v = *(const float4*)&cb[(size_t)id * DIM + threadIdx.x * 4];
  *(float4*)&zq[(size_t)row * DIM + threadIdx.x * 4] = v;
}

__global__ __launch_bounds__(256) void rowdot_bias_kernel(
    const float* __restrict__ W, const float* __restrict__ v,
    const float* __restrict__ b2, float* __restrict__ out) {
  const int row = blockIdx.x;
  const float4 w4 = *(const float4*)&W[(size_t)row * 1024 + threadIdx.x * 4];
  const float4 v4 = *(const float4*)&v[threadIdx.x * 4];
  const float s = w4.x * v4.x + w4.y * v4.y + w4.z * v4.z + w4.w * v4.w;
  const float r = block_reduce_sum(s);
  if (threadIdx.x == 0) out[row] = r + b2[row];
}

__global__ __launch_bounds__(256) void sqdiff_partial_kernel(
    const float* __restrict__ a, const float* __restrict__ b,
    float* __restrict__ part) {
  const size_t base = (size_t)blockIdx.x * 2048 + (size_t)threadIdx.x * 8;
  const float4 x0 = *(const float4*)&a[base];
  const float4 x1 = *(const float4*)&a[base + 4];
  const float4 y0 = *(const float4*)&b[base];
  const float4 y1 = *(const float4*)&b[base + 4];
  float s = 0.f;
  float d;
  d = x0.x - y0.x; s += d * d; d = x0.y - y0.y; s += d * d;
  d = x0.z - y0.z; s += d * d; d = x0.w - y0.w; s += d * d;
  d = x1.x - y1.x; s += d * d; d = x1.y - y1.y; s += d * d;
  d = x1.z - y1.z; s += d * d; d = x1.w - y1.w; s += d * d;
  const float r = block_reduce_sum(s);
  if (threadIdx.x == 0) part[blockIdx.x] = r;
}

__global__ __launch_bounds__(256) void final_losses_kernel(
    const float* __restrict__ rp, const float* __restrict__ ep,
    float* __restrict__ o) {
  __shared__ double sh[4];
  const int lane = threadIdx.x & 63, w = threadIdx.x >> 6;
  double s = 0.0;
  for (int i = threadIdx.x; i < 8192; i += 256) s += (double)rp[i];
  #pragma unroll
  for (int off = 32; off > 0; off >>= 1) s += __shfl_down(s, off, 64);
  if (lane == 0) sh[w] = s;
  __syncthreads();
  double rl = 0.0;
  if (threadIdx.x == 0) rl = (sh[0] + sh[1] + sh[2] + sh[3]) / ((double)N_ROWS * IN_DIM);
  __syncthreads();
  double s2 = 0.0;
  for (int i = threadIdx.x; i < 4096; i += 256) s2 += (double)ep[i];
  #pragma unroll
  for (int off = 32; off > 0; off >>= 1) s2 += __shfl_down(s2, off, 64);
  if (lane == 0) sh[w] = s2;
  __syncthreads();
  if (threadIdx.x == 0) {
    const double el = (sh[0] + sh[1] + sh[2] + sh[3]) / ((double)N_ROWS * DIM);
    o[0] = (float)(rl + el + 0.25 * el);
    o[1] = (float)rl;
    o[2] = (float)el;
    o[3] = (float)el;
  }
}

extern "C" void kernel_launch(void* const* d_in, const int* in_sizes, int n_in,
                              void* d_out, int out_size, void* d_ws, size_t ws_size,
                              hipStream_t stream) {
  const float* roi   = (const float*)d_in[0];
  const float* W_in  = (const float*)d_in[1];
  const float* b_in  = (const float*)d_in[2];
  const float* W_enc = (const float*)d_in[3];
  const float* b_enc = (const float*)d_in[4];
  const float* cb    = (const float*)d_in[5];
  const float* W_dec = (const float*)d_in[6];
  const float* b_dec = (const float*)d_in[7];
  const float* W_out = (const float*)d_in[8];
  const float* b_out = (const float*)d_in[9];

  float* out = (float*)d_out;
  float* o_ids   = out;
  float* o_zq    = out + 8192;
  float* o_recon = out + 8192 + (size_t)N_ROWS * DIM;
  float* o_scal  = out + 8192 + (size_t)N_ROWS * DIM + (size_t)N_ROWS * IN_DIM;

  // ws layout (float offsets)
  float*  ws    = (float*)d_ws;
  float*  W_dc  = ws;                          // 2,097,152
  float2* parts = (float2*)(ws + 2097152);     // 8192*64 float2 = 1,048,576 f
  float*  z2    = ws + 4194304;                // 8192
  float*  c2    = ws + 4202496;                // 8192
  int*    ids   = (int*)(ws + 4210688);        // 8192
  float*  b_dc  = ws + 4218880;                // 2048
  float*  ep    = ws + 4220928;                // 4096
  float*  rp    = ws + 4225024;                // 8192

  // t and z (f32, each 8192x1024) live in the o_recon region (16.8M floats).
  float* t = o_recon;
  float* z = o_recon + (size_t)N_ROWS * DIM;

  // decoder fusion (2%-threshold outputs)
  rowdot_bias_kernel<<<IN_DIM, 256, 0, stream>>>(W_out, b_dec, b_out, b_dc);
  gemm128<false><<<dim3(DIM / 128, IN_DIM / 128), 256, 0, stream>>>(
      W_out, W_dec, nullptr, W_dc, IN_DIM, DIM, DIM);

  // ---- np-f32 emulated encoder (bit-exact chains, pipelined) ----
  emul_gemm_kernel<<<dim3(DIM / 64, N_ROWS / 128), 256, 0, stream>>>(
      roi, W_in, b_in, t, DIM, IN_DIM, IN_DIM, IN_DIM, PANEL_MASK_K2048_C64);
  emul_gemm_kernel<<<dim3(DIM / 64, N_ROWS / 128), 256, 0, stream>>>(
      t, W_enc, b_enc, z, DIM, DIM, DIM, DIM, PANEL_MASK_K1024_C64);

  // ---- np pairwise row sums of squares ----
  sumsq1024_kernel<<<N_ROWS / 4, 256, 0, stream>>>(z, z2);
  sumsq1024_kernel<<<CBK / 4, 256, 0, stream>>>(cb, c2);

  // ---- emulated f32 distances + first-index argmin ----
  emul_dot_argmin_kernel<<<dim3(CBK / 128, N_ROWS / 128), 256, 0, stream>>>(
      z, cb, z2, c2, parts);
  rowmin_kernel<<<N_ROWS / 256, 256, 0, stream>>>(parts, ids, o_ids);

  // ---- outputs ----
  gather_zq_kernel<<<N_ROWS, 256, 0, stream>>>(cb, ids, o_zq);
  sqdiff_partial_kernel<<<(N_ROWS * DIM) / 2048, 256, 0, stream>>>(o_zq, z, ep);

  // recon (overwrites t/z region AFTER ep consumed z)
  gemm128<true><<<dim3(IN_DIM / 128, N_ROWS / 128), 256, 0, stream>>>(
      o_zq, W_dc, b_dc, o_recon, N_ROWS, IN_DIM, DIM);

  sqdiff_partial_kernel<<<(N_ROWS * IN_DIM) / 2048, 256, 0, stream>>>(
      o_recon, roi, rp);
  final_losses_kernel<<<1, 256, 0, stream>>>(rp, ep, o_scal);
}

// Round 10
// 2820.614 us; speedup vs baseline: 1.7996x; 1.0294x over previous
//
#include <hip/hip_runtime.h>
#include <float.h>

// ---------------------------------------------------------------------------
// VQ-VAE quantizer forward — round 10: round-9 semantics (PASSED, bit-exact
// numpy/OpenBLAS emulation on the ids path) + single-barrier double-buffered
// LDS in all GEMM-shaped kernels (staging writes overlap compute across
// waves; one barrier per chunk instead of two). No arithmetic changes:
// sequential-k fmaf chains, panel joins at k=384,704 (K=1024) and
// 384,768,1152,1536,1792 (K=2048), lexicographic first-index argmin.
// ---------------------------------------------------------------------------

#define N_ROWS 8192
#define IN_DIM 2048
#define DIM 1024
#define CBK 8192

// chunk=32 panel-start masks (bit ci set -> join previous panel before chunk ci)
#define PANEL_MASK_K1024_C32 0x0000000000401000ULL  // k=384,704
#define PANEL_MASK_K2048_C32 0x0101001001001000ULL  // k=384,768,1152,1536,1792

__device__ __forceinline__ float sqf(float v) { return __builtin_fmaf(v, v, 0.0f); }

__device__ __forceinline__ int swz128(int c) {
  return (c & 3) | (((c >> 3) & 7) << 2) | (((c >> 2) & 1) << 5) | ((c >> 6) << 6);
}

__device__ __forceinline__ float block_reduce_sum(float v) {
  __shared__ float sh[4];
  #pragma unroll
  for (int off = 32; off > 0; off >>= 1) v += __shfl_down(v, off, 64);
  const int lane = threadIdx.x & 63, w = threadIdx.x >> 6;
  if (lane == 0) sh[w] = v;
  __syncthreads();
  float r = 0.f;
  if (threadIdx.x == 0) r = sh[0] + sh[1] + sh[2] + sh[3];
  return r;  // valid on thread 0 only
}

// ---------------------------------------------------------------------------
// fp32 128x128x16 tiled GEMM (decoder path: W_dc fusion + recon). 2% thresh.
// Double-buffered, one barrier per k-step.
// ---------------------------------------------------------------------------
template <bool BT>
__global__ __launch_bounds__(256) void gemm128(
    const float* __restrict__ A, const float* __restrict__ B,
    const float* __restrict__ bias, float* __restrict__ C,
    int M, int N, int K) {
  __shared__ float As[2][16][132];
  __shared__ float Bs[2][16][132];
  const int tid = threadIdx.x;
  const int tx = tid & 15, ty = tid >> 4;
  const int bm = blockIdx.y, bn = blockIdx.x;

  const int mload = tid & 127, kh = tid >> 7;
  const size_t arow = (size_t)(bm * 128 + mload) * (size_t)K;
  const size_t brow = BT ? (size_t)(bn * 128 + mload) * (size_t)K : 0;
  const int swn = swz128(mload);
  const int c4 = (tid & 31) << 2;
  const int kr = tid >> 5;
  const int swc = swz128(c4);

  float acc[8][8];
  #pragma unroll
  for (int r = 0; r < 8; ++r)
    #pragma unroll
    for (int c = 0; c < 8; ++c) acc[r][c] = 0.f;

  const int boff = ((tx & 7) << 2) | ((tx >> 3) << 6);

  float4 av0, av1, bv0, bv1;
  // load k-step 0
  av0 = *(const float4*)&A[arow + kh * 8];
  av1 = *(const float4*)&A[arow + kh * 8 + 4];
  if (BT) {
    bv0 = *(const float4*)&B[brow + kh * 8];
    bv1 = *(const float4*)&B[brow + kh * 8 + 4];
  } else {
    bv0 = *(const float4*)&B[(size_t)kr * N + bn * 128 + c4];
    bv1 = *(const float4*)&B[(size_t)(kr + 8) * N + bn * 128 + c4];
  }
  // write buf0
  As[0][kh * 8 + 0][mload] = av0.x; As[0][kh * 8 + 1][mload] = av0.y;
  As[0][kh * 8 + 2][mload] = av0.z; As[0][kh * 8 + 3][mload] = av0.w;
  As[0][kh * 8 + 4][mload] = av1.x; As[0][kh * 8 + 5][mload] = av1.y;
  As[0][kh * 8 + 6][mload] = av1.z; As[0][kh * 8 + 7][mload] = av1.w;
  if (BT) {
    Bs[0][kh * 8 + 0][swn] = bv0.x; Bs[0][kh * 8 + 1][swn] = bv0.y;
    Bs[0][kh * 8 + 2][swn] = bv0.z; Bs[0][kh * 8 + 3][swn] = bv0.w;
    Bs[0][kh * 8 + 4][swn] = bv1.x; Bs[0][kh * 8 + 5][swn] = bv1.y;
    Bs[0][kh * 8 + 6][swn] = bv1.z; Bs[0][kh * 8 + 7][swn] = bv1.w;
  } else {
    *(float4*)&Bs[0][kr][swc] = bv0;
    *(float4*)&Bs[0][kr + 8][swc] = bv1;
  }
  // load k-step 1
  const int nk = K >> 4;
  if (nk > 1) {
    av0 = *(const float4*)&A[arow + 16 + kh * 8];
    av1 = *(const float4*)&A[arow + 16 + kh * 8 + 4];
    if (BT) {
      bv0 = *(const float4*)&B[brow + 16 + kh * 8];
      bv1 = *(const float4*)&B[brow + 16 + kh * 8 + 4];
    } else {
      bv0 = *(const float4*)&B[(size_t)(16 + kr) * N + bn * 128 + c4];
      bv1 = *(const float4*)&B[(size_t)(16 + kr + 8) * N + bn * 128 + c4];
    }
  }
  __syncthreads();

  for (int ki = 0; ki < nk; ++ki) {
    const int p = ki & 1;
    if (ki + 1 < nk) {
      // write regs(ki+1) into the alternate buffer (other waves compute buf p)
      As[p ^ 1][kh * 8 + 0][mload] = av0.x; As[p ^ 1][kh * 8 + 1][mload] = av0.y;
      As[p ^ 1][kh * 8 + 2][mload] = av0.z; As[p ^ 1][kh * 8 + 3][mload] = av0.w;
      As[p ^ 1][kh * 8 + 4][mload] = av1.x; As[p ^ 1][kh * 8 + 5][mload] = av1.y;
      As[p ^ 1][kh * 8 + 6][mload] = av1.z; As[p ^ 1][kh * 8 + 7][mload] = av1.w;
      if (BT) {
        Bs[p ^ 1][kh * 8 + 0][swn] = bv0.x; Bs[p ^ 1][kh * 8 + 1][swn] = bv0.y;
        Bs[p ^ 1][kh * 8 + 2][swn] = bv0.z; Bs[p ^ 1][kh * 8 + 3][swn] = bv0.w;
        Bs[p ^ 1][kh * 8 + 4][swn] = bv1.x; Bs[p ^ 1][kh * 8 + 5][swn] = bv1.y;
        Bs[p ^ 1][kh * 8 + 6][swn] = bv1.z; Bs[p ^ 1][kh * 8 + 7][swn] = bv1.w;
      } else {
        *(float4*)&Bs[p ^ 1][kr][swc] = bv0;
        *(float4*)&Bs[p ^ 1][kr + 8][swc] = bv1;
      }
      if (ki + 2 < nk) {  // prefetch k-step ki+2
        const int k2 = (ki + 2) << 4;
        av0 = *(const float4*)&A[arow + k2 + kh * 8];
        av1 = *(const float4*)&A[arow + k2 + kh * 8 + 4];
        if (BT) {
          bv0 = *(const float4*)&B[brow + k2 + kh * 8];
          bv1 = *(const float4*)&B[brow + k2 + kh * 8 + 4];
        } else {
          bv0 = *(const float4*)&B[(size_t)(k2 + kr) * N + bn * 128 + c4];
          bv1 = *(const float4*)&B[(size_t)(k2 + kr + 8) * N + bn * 128 + c4];
        }
      }
    }
    #pragma unroll
    for (int kk = 0; kk < 16; ++kk) {
      const float4 a0 = *(const float4*)&As[p][kk][ty * 8];
      const float4 a1 = *(const float4*)&As[p][kk][ty * 8 + 4];
      const float4 b0 = *(const float4*)&Bs[p][kk][boff];
      const float4 b1 = *(const float4*)&Bs[p][kk][boff + 32];
      const float ar[8] = {a0.x, a0.y, a0.z, a0.w, a1.x, a1.y, a1.z, a1.w};
      const float br[8] = {b0.x, b0.y, b0.z, b0.w, b1.x, b1.y, b1.z, b1.w};
      #pragma unroll
      for (int r = 0; r < 8; ++r)
        #pragma unroll
        for (int c = 0; c < 8; ++c) acc[r][c] = fmaf(ar[r], br[c], acc[r][c]);
    }
    __syncthreads();
  }

  const int gcol = bn * 128 + tx * 8;
  float bb[8] = {0, 0, 0, 0, 0, 0, 0, 0};
  if (bias) {
    const float4 v0 = *(const float4*)&bias[gcol];
    const float4 v1 = *(const float4*)&bias[gcol + 4];
    bb[0] = v0.x; bb[1] = v0.y; bb[2] = v0.z; bb[3] = v0.w;
    bb[4] = v1.x; bb[5] = v1.y; bb[6] = v1.z; bb[7] = v1.w;
  }
  #pragma unroll
  for (int r = 0; r < 8; ++r) {
    float* cp = &C[(size_t)(bm * 128 + ty * 8 + r) * N + gcol];
    float4 o0, o1;
    o0.x = acc[r][0] + bb[0]; o0.y = acc[r][1] + bb[1];
    o0.z = acc[r][2] + bb[2]; o0.w = acc[r][3] + bb[3];
    o1.x = acc[r][4] + bb[4]; o1.y = acc[r][5] + bb[5];
    o1.z = acc[r][6] + bb[6]; o1.w = acc[r][7] + bb[7];
    *(float4*)cp = o0;
    *(float4*)(cp + 4) = o1;
  }
}

// ---------------------------------------------------------------------------
// OpenBLAS-emulating GEMM: C[M,N] = A[M,K]@B[N,K]^T + bias (bit-exact chains).
// Block 128 rows x 64 cols, 8x4 microtile, chunk=32, double-buffered.
// ---------------------------------------------------------------------------
__global__ __launch_bounds__(256) void emul_gemm_kernel(
    const float* __restrict__ A, const float* __restrict__ B,
    const float* __restrict__ bias, float* __restrict__ C,
    int N, int K, int lda, int ldb, unsigned long long panel_mask) {
  __shared__ float As[2][32][128];
  __shared__ float Bs[2][32][64];
  const int tid = threadIdx.x;
  const int tx = tid & 15, ty = tid >> 4;
  const int row0 = blockIdx.y * 128, col0 = blockIdx.x * 64;
  const int sar = tid & 127, sah = tid >> 7;  // A: row, k-half(16)
  const int sbc = tid & 63, sbq = tid >> 6;   // B: col, k-quarter(8)

  float total[8][4], part[8][4];
  #pragma unroll
  for (int r = 0; r < 8; ++r)
    #pragma unroll
    for (int j = 0; j < 4; ++j) { total[r][j] = 0.f; part[r][j] = 0.f; }

  float4 av[4], bv[2];
  #pragma unroll
  for (int q = 0; q < 4; ++q)
    av[q] = *(const float4*)&A[(size_t)(row0 + sar) * lda + sah * 16 + q * 4];
  #pragma unroll
  for (int q = 0; q < 2; ++q)
    bv[q] = *(const float4*)&B[(size_t)(col0 + sbc) * ldb + sbq * 8 + q * 4];
  // write buf0
  #pragma unroll
  for (int q = 0; q < 4; ++q) {
    As[0][sah * 16 + q * 4 + 0][sar] = av[q].x;
    As[0][sah * 16 + q * 4 + 1][sar] = av[q].y;
    As[0][sah * 16 + q * 4 + 2][sar] = av[q].z;
    As[0][sah * 16 + q * 4 + 3][sar] = av[q].w;
  }
  #pragma unroll
  for (int q = 0; q < 2; ++q) {
    Bs[0][sbq * 8 + q * 4 + 0][sbc] = bv[q].x;
    Bs[0][sbq * 8 + q * 4 + 1][sbc] = bv[q].y;
    Bs[0][sbq * 8 + q * 4 + 2][sbc] = bv[q].z;
    Bs[0][sbq * 8 + q * 4 + 3][sbc] = bv[q].w;
  }
  const int nch = K >> 5;
  if (nch > 1) {  // load chunk 1
    #pragma unroll
    for (int q = 0; q < 4; ++q)
      av[q] = *(const float4*)&A[(size_t)(row0 + sar) * lda + 32 + sah * 16 + q * 4];
    #pragma unroll
    for (int q = 0; q < 2; ++q)
      bv[q] = *(const float4*)&B[(size_t)(col0 + sbc) * ldb + 32 + sbq * 8 + q * 4];
  }
  __syncthreads();

  for (int ci = 0; ci < nch; ++ci) {
    const int p = ci & 1;
    if (ci + 1 < nch) {
      #pragma unroll
      for (int q = 0; q < 4; ++q) {
        As[p ^ 1][sah * 16 + q * 4 + 0][sar] = av[q].x;
        As[p ^ 1][sah * 16 + q * 4 + 1][sar] = av[q].y;
        As[p ^ 1][sah * 16 + q * 4 + 2][sar] = av[q].z;
        As[p ^ 1][sah * 16 + q * 4 + 3][sar] = av[q].w;
      }
      #pragma unroll
      for (int q = 0; q < 2; ++q) {
        Bs[p ^ 1][sbq * 8 + q * 4 + 0][sbc] = bv[q].x;
        Bs[p ^ 1][sbq * 8 + q * 4 + 1][sbc] = bv[q].y;
        Bs[p ^ 1][sbq * 8 + q * 4 + 2][sbc] = bv[q].z;
        Bs[p ^ 1][sbq * 8 + q * 4 + 3][sbc] = bv[q].w;
      }
      if (ci + 2 < nch) {
        const int k2 = (ci + 2) << 5;
        #pragma unroll
        for (int q = 0; q < 4; ++q)
          av[q] = *(const float4*)&A[(size_t)(row0 + sar) * lda + k2 + sah * 16 + q * 4];
        #pragma unroll
        for (int q = 0; q < 2; ++q)
          bv[q] = *(const float4*)&B[(size_t)(col0 + sbc) * ldb + k2 + sbq * 8 + q * 4];
      }
    }
    if (ci && ((panel_mask >> ci) & 1ULL)) {  // OpenBLAS kc panel boundary
      #pragma unroll
      for (int r = 0; r < 8; ++r)
        #pragma unroll
        for (int j = 0; j < 4; ++j) { total[r][j] = total[r][j] + part[r][j]; part[r][j] = 0.f; }
    }
    #pragma unroll 4
    for (int kk = 0; kk < 32; ++kk) {
      const float4 a0 = *(const float4*)&As[p][kk][ty * 8];
      const float4 a1 = *(const float4*)&As[p][kk][ty * 8 + 4];
      const float4 b0 = *(const float4*)&Bs[p][kk][tx * 4];
      const float ar[8] = {a0.x, a0.y, a0.z, a0.w, a1.x, a1.y, a1.z, a1.w};
      const float br[4] = {b0.x, b0.y, b0.z, b0.w};
      #pragma unroll
      for (int r = 0; r < 8; ++r)
        #pragma unroll
        for (int j = 0; j < 4; ++j)
          part[r][j] = __builtin_fmaf(ar[r], br[j], part[r][j]);
    }
    __syncthreads();
  }
  #pragma unroll
  for (int r = 0; r < 8; ++r)
    #pragma unroll
    for (int j = 0; j < 4; ++j) total[r][j] = total[r][j] + part[r][j];

  const float4 bb = *(const float4*)&bias[col0 + tx * 4];
  #pragma unroll
  for (int r = 0; r < 8; ++r) {
    float4 o;
    o.x = total[r][0] + bb.x; o.y = total[r][1] + bb.y;
    o.z = total[r][2] + bb.z; o.w = total[r][3] + bb.w;
    *(float4*)&C[(size_t)(row0 + ty * 8 + r) * N + col0 + tx * 4] = o;
  }
}

// ---------------------------------------------------------------------------
// numpy pairwise_sum emulation of sum(x*x) over rows of 1024 (unchanged).
// ---------------------------------------------------------------------------
__global__ __launch_bounds__(256) void sumsq1024_kernel(
    const float* __restrict__ X, float* __restrict__ out) {
  __shared__ float rows[4][1024];
  __shared__ float leaves[4][8];
  const int tid = threadIdx.x;
  const int row0 = blockIdx.x * 4;
  for (int i = tid; i < 4096; i += 256)
    rows[i >> 10][i & 1023] = X[(size_t)row0 * 1024 + i];
  __syncthreads();
  if (tid < 32) {
    const int r = tid >> 3, lf = tid & 7;
    const float* a = &rows[r][lf * 128];
    float s0 = sqf(a[0]), s1 = sqf(a[1]), s2 = sqf(a[2]), s3 = sqf(a[3]);
    float s4 = sqf(a[4]), s5 = sqf(a[5]), s6 = sqf(a[6]), s7 = sqf(a[7]);
    for (int i = 8; i < 128; i += 8) {
      s0 = s0 + sqf(a[i + 0]); s1 = s1 + sqf(a[i + 1]);
      s2 = s2 + sqf(a[i + 2]); s3 = s3 + sqf(a[i + 3]);
      s4 = s4 + sqf(a[i + 4]); s5 = s5 + sqf(a[i + 5]);
      s6 = s6 + sqf(a[i + 6]); s7 = s7 + sqf(a[i + 7]);
    }
    leaves[r][lf] = ((s0 + s1) + (s2 + s3)) + ((s4 + s5) + (s6 + s7));
  }
  __syncthreads();
  if (tid < 4) {
    const float* L = leaves[tid];
    const float p01 = L[0] + L[1], p23 = L[2] + L[3];
    const float p45 = L[4] + L[5], p67 = L[6] + L[7];
    out[row0 + tid] = ((p01 + p23) + (p45 + p67));
  }
}

// ---------------------------------------------------------------------------
// Emulated distance GEMM + per-128-entry-chunk first-index argmin.
// Block 128 rows x 128 entries, 8x8 microtile, chunk=32, double-buffered.
// ---------------------------------------------------------------------------
__global__ __launch_bounds__(256) void emul_dot_argmin_kernel(
    const float* __restrict__ Z, const float* __restrict__ CB,
    const float* __restrict__ Z2, const float* __restrict__ C2,
    float2* __restrict__ parts) {
  __shared__ float Zs[2][32][128];
  __shared__ float Cs[2][32][128];
  const int tid = threadIdx.x;
  const int tx = tid & 15, ty = tid >> 4;
  const int row0 = blockIdx.y * 128, e0 = blockIdx.x * 128;
  const int sr = tid & 127, sh = tid >> 7;  // stage: row/entry, k-half(16)
  const int scol = (((sr >> 2) & 1) << 6) + ((sr >> 3) << 2) + (sr & 3);

  float part[8][8], total[8][8];  // [row][entry]
  #pragma unroll
  for (int r = 0; r < 8; ++r)
    #pragma unroll
    for (int e = 0; e < 8; ++e) { part[r][e] = 0.f; total[r][e] = 0.f; }

  float4 zv[4], cv[4];
  #pragma unroll
  for (int q = 0; q < 4; ++q) {
    zv[q] = *(const float4*)&Z[(size_t)(row0 + sr) * 1024 + sh * 16 + q * 4];
    cv[q] = *(const float4*)&CB[(size_t)(e0 + sr) * 1024 + sh * 16 + q * 4];
  }
  #pragma unroll
  for (int q = 0; q < 4; ++q) {
    Zs[0][sh * 16 + q * 4 + 0][sr] = zv[q].x;
    Zs[0][sh * 16 + q * 4 + 1][sr] = zv[q].y;
    Zs[0][sh * 16 + q * 4 + 2][sr] = zv[q].z;
    Zs[0][sh * 16 + q * 4 + 3][sr] = zv[q].w;
    Cs[0][sh * 16 + q * 4 + 0][scol] = cv[q].x;
    Cs[0][sh * 16 + q * 4 + 1][scol] = cv[q].y;
    Cs[0][sh * 16 + q * 4 + 2][scol] = cv[q].z;
    Cs[0][sh * 16 + q * 4 + 3][scol] = cv[q].w;
  }
  #pragma unroll
  for (int q = 0; q < 4; ++q) {  // load chunk 1
    zv[q] = *(const float4*)&Z[(size_t)(row0 + sr) * 1024 + 32 + sh * 16 + q * 4];
    cv[q] = *(const float4*)&CB[(size_t)(e0 + sr) * 1024 + 32 + sh * 16 + q * 4];
  }
  __syncthreads();

  for (int ci = 0; ci < 32; ++ci) {
    const int p = ci & 1;
    if (ci + 1 < 32) {
      #pragma unroll
      for (int q = 0; q < 4; ++q) {
        Zs[p ^ 1][sh * 16 + q * 4 + 0][sr] = zv[q].x;
        Zs[p ^ 1][sh * 16 + q * 4 + 1][sr] = zv[q].y;
        Zs[p ^ 1][sh * 16 + q * 4 + 2][sr] = zv[q].z;
        Zs[p ^ 1][sh * 16 + q * 4 + 3][sr] = zv[q].w;
        Cs[p ^ 1][sh * 16 + q * 4 + 0][scol] = cv[q].x;
        Cs[p ^ 1][sh * 16 + q * 4 + 1][scol] = cv[q].y;
        Cs[p ^ 1][sh * 16 + q * 4 + 2][scol] = cv[q].z;
        Cs[p ^ 1][sh * 16 + q * 4 + 3][scol] = cv[q].w;
      }
      if (ci + 2 < 32) {
        const int k2 = (ci + 2) << 5;
        #pragma unroll
        for (int q = 0; q < 4; ++q) {
          zv[q] = *(const float4*)&Z[(size_t)(row0 + sr) * 1024 + k2 + sh * 16 + q * 4];
          cv[q] = *(const float4*)&CB[(size_t)(e0 + sr) * 1024 + k2 + sh * 16 + q * 4];
        }
      }
    }
    if (ci && ((PANEL_MASK_K1024_C32 >> ci) & 1ULL)) {  // joins at k=384, 704
      #pragma unroll
      for (int r = 0; r < 8; ++r)
        #pragma unroll
        for (int e = 0; e < 8; ++e) { total[r][e] = total[r][e] + part[r][e]; part[r][e] = 0.f; }
    }
    #pragma unroll 4
    for (int kk = 0; kk < 32; ++kk) {
      const float4 za = *(const float4*)&Zs[p][kk][ty * 8];
      const float4 zb = *(const float4*)&Zs[p][kk][ty * 8 + 4];
      const float4 ca = *(const float4*)&Cs[p][kk][tx * 4];
      const float4 cb4 = *(const float4*)&Cs[p][kk][64 + tx * 4];
      const float zr[8] = {za.x, za.y, za.z, za.w, zb.x, zb.y, zb.z, zb.w};
      const float cr[8] = {ca.x, ca.y, ca.z, ca.w, cb4.x, cb4.y, cb4.z, cb4.w};
      #pragma unroll
      for (int r = 0; r < 8; ++r)
        #pragma unroll
        for (int e = 0; e < 8; ++e)
          part[r][e] = __builtin_fmaf(zr[r], cr[e], part[r][e]);
    }
    __syncthreads();
  }
  #pragma unroll
  for (int r = 0; r < 8; ++r)
    #pragma unroll
    for (int e = 0; e < 8; ++e) total[r][e] = total[r][e] + part[r][e];

  const float4 c2a = *(const float4*)&C2[e0 + tx * 8];
  const float4 c2b = *(const float4*)&C2[e0 + tx * 8 + 4];
  const float c2r[8] = {c2a.x, c2a.y, c2a.z, c2a.w, c2b.x, c2b.y, c2b.z, c2b.w};
  #pragma unroll
  for (int rr = 0; rr < 8; ++rr) {
    const int row = row0 + ty * 8 + rr;
    const float z2r = Z2[row];
    float bd = FLT_MAX;
    int be = 0;
    #pragma unroll
    for (int j = 0; j < 8; ++j) {  // ascending entries; strict < = first index
      const float d = __builtin_fmaf(-2.0f, total[rr][j], z2r) + c2r[j];
      if (d < bd) { bd = d; be = e0 + tx * 8 + j; }
    }
    #pragma unroll
    for (int m = 1; m < 16; m <<= 1) {  // lexicographic min across 16 tx lanes
      const float od = __shfl_xor(bd, m, 64);
      const int oe = __shfl_xor(be, m, 64);
      if (od < bd || (od == bd && oe < be)) { bd = od; be = oe; }
    }
    if (tx == 0)
      parts[(size_t)row * 64 + blockIdx.x] = make_float2(bd, __int_as_float(be));
  }
}

__global__ __launch_bounds__(256) void rowmin_kernel(
    const float2* __restrict__ parts, int* __restrict__ ids,
    float* __restrict__ o_ids) {
  const int row = blockIdx.x * 256 + threadIdx.x;
  float bd = FLT_MAX;
  int bi = 0;
  for (int c = 0; c < 64; ++c) {  // ascending chunks + strict < = first index
    const float2 p = parts[(size_t)row * 64 + c];
    if (p.x < bd) { bd = p.x; bi = __float_as_int(p.y); }
  }
  ids[row] = bi;
  o_ids[row] = (float)bi;
}

__global__ __launch_bounds__(256) void gather_zq_kernel(
    const float* __restrict__ cb, const int* __restrict__ ids,
    float* __restrict__ zq) {
  const int row = blockIdx.x;
  const int id = ids[row];
  const float4 v = *(const float4*)&cb[(size_t)id * DIM + threadIdx.x * 4];
  *(float4*)&zq[(size_t)row * DIM + threadIdx.x * 4] = v;
}

__global__ __launch_bounds__(256) void rowdot_bias_kernel(
    const float* __restrict__ W, const float* __restrict__ v,
    const float* __restrict__ b2, float* __restrict__ out) {
  const int row = blockIdx.x;
  const float4 w4 = *(const float4*)&W[(size_t)row * 1024 + threadIdx.x * 4];
  const float4 v4 = *(const float4*)&v[threadIdx.x * 4];
  const float s = w4.x * v4.x + w4.y * v4.y + w4.z * v4.z + w4.w * v4.w;
  const float r = block_reduce_sum(s);
  if (threadIdx.x == 0) out[row] = r + b2[row];
}

__global__ __launch_bounds__(256) void sqdiff_partial_kernel(
    const float* __restrict__ a, const float* __restrict__ b,
    float* __restrict__ part) {
  const size_t base = (size_t)blockIdx.x * 2048 + (size_t)threadIdx.x * 8;
  const float4 x0 = *(const float4*)&a[base];
  const float4 x1 = *(const float4*)&a[base + 4];
  const float4 y0 = *(const float4*)&b[base];
  const float4 y1 = *(const float4*)&b[base + 4];
  float s = 0.f;
  float d;
  d = x0.x - y0.x; s += d * d; d = x0.y - y0.y; s += d * d;
  d = x0.z - y0.z; s += d * d; d = x0.w - y0.w; s += d * d;
  d = x1.x - y1.x; s += d * d; d = x1.y - y1.y; s += d * d;
  d = x1.z - y1.z; s += d * d; d = x1.w - y1.w; s += d * d;
  const float r = block_reduce_sum(s);
  if (threadIdx.x == 0) part[blockIdx.x] = r;
}

__global__ __launch_bounds__(256) void final_losses_kernel(
    const float* __restrict__ rp, const float* __restrict__ ep,
    float* __restrict__ o) {
  __shared__ double sh[4];
  const int lane = threadIdx.x & 63, w = threadIdx.x >> 6;
  double s = 0.0;
  for (int i = threadIdx.x; i < 8192; i += 256) s += (double)rp[i];
  #pragma unroll
  for (int off = 32; off > 0; off >>= 1) s += __shfl_down(s, off, 64);
  if (lane == 0) sh[w] = s;
  __syncthreads();
  double rl = 0.0;
  if (threadIdx.x == 0) rl = (sh[0] + sh[1] + sh[2] + sh[3]) / ((double)N_ROWS * IN_DIM);
  __syncthreads();
  double s2 = 0.0;
  for (int i = threadIdx.x; i < 4096; i += 256) s2 += (double)ep[i];
  #pragma unroll
  for (int off = 32; off > 0; off >>= 1) s2 += __shfl_down(s2, off, 64);
  if (lane == 0) sh[w] = s2;
  __syncthreads();
  if (threadIdx.x == 0) {
    const double el = (sh[0] + sh[1] + sh[2] + sh[3]) / ((double)N_ROWS * DIM);
    o[0] = (float)(rl + el + 0.25 * el);
    o[1] = (float)rl;
    o[2] = (float)el;
    o[3] = (float)el;
  }
}

extern "C" void kernel_launch(void* const* d_in, const int* in_sizes, int n_in,
                              void* d_out, int out_size, void* d_ws, size_t ws_size,
                              hipStream_t stream) {
  const float* roi   = (const float*)d_in[0];
  const float* W_in  = (const float*)d_in[1];
  const float* b_in  = (const float*)d_in[2];
  const float* W_enc = (const float*)d_in[3];
  const float* b_enc = (const float*)d_in[4];
  const float* cb    = (const float*)d_in[5];
  const float* W_dec = (const float*)d_in[6];
  const float* b_dec = (const float*)d_in[7];
  const float* W_out = (const float*)d_in[8];
  const float* b_out = (const float*)d_in[9];

  float* out = (float*)d_out;
  float* o_ids   = out;
  float* o_zq    = out + 8192;
  float* o_recon = out + 8192 + (size_t)N_ROWS * DIM;
  float* o_scal  = out + 8192 + (size_t)N_ROWS * DIM + (size_t)N_ROWS * IN_DIM;

  // ws layout (float offsets)
  float*  ws    = (float*)d_ws;
  float*  W_dc  = ws;                          // 2,097,152
  float2* parts = (float2*)(ws + 2097152);     // 8192*64 float2 = 1,048,576 f
  float*  z2    = ws + 4194304;                // 8192
  float*  c2    = ws + 4202496;                // 8192
  int*    ids   = (int*)(ws + 4210688);        // 8192
  float*  b_dc  = ws + 4218880;                // 2048
  float*  ep    = ws + 4220928;                // 4096
  float*  rp    = ws + 4225024;                // 8192

  // t and z (f32, each 8192x1024) live in the o_recon region (16.8M floats).
  float* t = o_recon;
  float* z = o_recon + (size_t)N_ROWS * DIM;

  // decoder fusion (2%-threshold outputs)
  rowdot_bias_kernel<<<IN_DIM, 256, 0, stream>>>(W_out, b_dec, b_out, b_dc);
  gemm128<false><<<dim3(DIM / 128, IN_DIM / 128), 256, 0, stream>>>(
      W_out, W_dec, nullptr, W_dc, IN_DIM, DIM, DIM);

  // ---- np-f32 emulated encoder (bit-exact chains, dbuf) ----
  emul_gemm_kernel<<<dim3(DIM / 64, N_ROWS / 128), 256, 0, stream>>>(
      roi, W_in, b_in, t, DIM, IN_DIM, IN_DIM, IN_DIM, PANEL_MASK_K2048_C32);
  emul_gemm_kernel<<<dim3(DIM / 64, N_ROWS / 128), 256, 0, stream>>>(
      t, W_enc, b_enc, z, DIM, DIM, DIM, DIM, PANEL_MASK_K1024_C32);

  // ---- np pairwise row sums of squares ----
  sumsq1024_kernel<<<N_ROWS / 4, 256, 0, stream>>>(z, z2);
  sumsq1024_kernel<<<CBK / 4, 256, 0, stream>>>(cb, c2);

  // ---- emulated f32 distances + first-index argmin ----
  emul_dot_argmin_kernel<<<dim3(CBK / 128, N_ROWS / 128), 256, 0, stream>>>(
      z, cb, z2, c2, parts);
  rowmin_kernel<<<N_ROWS / 256, 256, 0, stream>>>(parts, ids, o_ids);

  // ---- outputs ----
  gather_zq_kernel<<<N_ROWS, 256, 0, stream>>>(cb, ids, o_zq);
  sqdiff_partial_kernel<<<(N_ROWS * DIM) / 2048, 256, 0, stream>>>(o_zq, z, ep);

  // recon (overwrites t/z region AFTER ep consumed z)
  gemm128<true><<<dim3(IN_DIM / 128, N_ROWS / 128), 256, 0, stream>>>(
      o_zq, W_dc, b_dc, o_recon, N_ROWS, IN_DIM, DIM);

  sqdiff_partial_kernel<<<(N_ROWS * IN_DIM) / 2048, 256, 0, stream>>>(
      o_recon, roi, rp);
  final_losses_kernel<<<1, 256, 0, stream>>>(rp, ep, o_scal);
}

// Round 11
// 2451.242 us; speedup vs baseline: 2.0708x; 1.1507x over previous
//
#include <hip/hip_runtime.h>
#include <float.h>

// ---------------------------------------------------------------------------
// VQ-VAE quantizer forward — round 11: round-10 ids semantics (PASSED,
// bit-exact numpy/OpenBLAS emulation) with:
//  * recon path moved to bf16 MFMA (2%-threshold output; f32->bf16 RNE on the
//    fly; 16x16x32 bf16 mfma, verified operand/C layouts, XOR-swizzled LDS).
//  * emul_gemm widened to the dist kernel's proven 128x128 / 8x8 structure
//    (same sequential-k chains + panel joins -> t/z still bit-exact).
// ---------------------------------------------------------------------------

#define N_ROWS 8192
#define IN_DIM 2048
#define DIM 1024
#define CBK 8192

// chunk=32 panel-start masks (bit ci set -> join previous panel before chunk ci)
#define PANEL_MASK_K1024_C32 0x0000000000401000ULL  // k=384,704
#define PANEL_MASK_K2048_C32 0x0101001001001000ULL  // k=384,768,1152,1536,1792

typedef __attribute__((ext_vector_type(8))) short short8;
typedef __attribute__((ext_vector_type(8))) unsigned short ushort8;
typedef __attribute__((ext_vector_type(4))) float f32x4;

__device__ __forceinline__ float sqf(float v) { return __builtin_fmaf(v, v, 0.0f); }

__device__ __forceinline__ unsigned short f2bf(float f) {  // RNE f32->bf16
  unsigned int u = __float_as_uint(f);
  u += 0x7fffu + ((u >> 16) & 1u);
  return (unsigned short)(u >> 16);
}

__device__ __forceinline__ int swz128(int c) {
  return (c & 3) | (((c >> 3) & 7) << 2) | (((c >> 2) & 1) << 5) | ((c >> 6) << 6);
}

__device__ __forceinline__ float block_reduce_sum(float v) {
  __shared__ float sh[4];
  #pragma unroll
  for (int off = 32; off > 0; off >>= 1) v += __shfl_down(v, off, 64);
  const int lane = threadIdx.x & 63, w = threadIdx.x >> 6;
  if (lane == 0) sh[w] = v;
  __syncthreads();
  float r = 0.f;
  if (threadIdx.x == 0) r = sh[0] + sh[1] + sh[2] + sh[3];
  return r;  // valid on thread 0 only
}

// ---------------------------------------------------------------------------
// fp32 128x128x16 tiled GEMM (W_dc fusion only). 2% thresh. Double-buffered.
// ---------------------------------------------------------------------------
template <bool BT>
__global__ __launch_bounds__(256) void gemm128(
    const float* __restrict__ A, const float* __restrict__ B,
    const float* __restrict__ bias, float* __restrict__ C,
    int M, int N, int K) {
  __shared__ float As[2][16][132];
  __shared__ float Bs[2][16][132];
  const int tid = threadIdx.x;
  const int tx = tid & 15, ty = tid >> 4;
  const int bm = blockIdx.y, bn = blockIdx.x;

  const int mload = tid & 127, kh = tid >> 7;
  const size_t arow = (size_t)(bm * 128 + mload) * (size_t)K;
  const size_t brow = BT ? (size_t)(bn * 128 + mload) * (size_t)K : 0;
  const int swn = swz128(mload);
  const int c4 = (tid & 31) << 2;
  const int kr = tid >> 5;
  const int swc = swz128(c4);

  float acc[8][8];
  #pragma unroll
  for (int r = 0; r < 8; ++r)
    #pragma unroll
    for (int c = 0; c < 8; ++c) acc[r][c] = 0.f;

  const int boff = ((tx & 7) << 2) | ((tx >> 3) << 6);

  float4 av0, av1, bv0, bv1;
  av0 = *(const float4*)&A[arow + kh * 8];
  av1 = *(const float4*)&A[arow + kh * 8 + 4];
  if (BT) {
    bv0 = *(const float4*)&B[brow + kh * 8];
    bv1 = *(const float4*)&B[brow + kh * 8 + 4];
  } else {
    bv0 = *(const float4*)&B[(size_t)kr * N + bn * 128 + c4];
    bv1 = *(const float4*)&B[(size_t)(kr + 8) * N + bn * 128 + c4];
  }
  As[0][kh * 8 + 0][mload] = av0.x; As[0][kh * 8 + 1][mload] = av0.y;
  As[0][kh * 8 + 2][mload] = av0.z; As[0][kh * 8 + 3][mload] = av0.w;
  As[0][kh * 8 + 4][mload] = av1.x; As[0][kh * 8 + 5][mload] = av1.y;
  As[0][kh * 8 + 6][mload] = av1.z; As[0][kh * 8 + 7][mload] = av1.w;
  if (BT) {
    Bs[0][kh * 8 + 0][swn] = bv0.x; Bs[0][kh * 8 + 1][swn] = bv0.y;
    Bs[0][kh * 8 + 2][swn] = bv0.z; Bs[0][kh * 8 + 3][swn] = bv0.w;
    Bs[0][kh * 8 + 4][swn] = bv1.x; Bs[0][kh * 8 + 5][swn] = bv1.y;
    Bs[0][kh * 8 + 6][swn] = bv1.z; Bs[0][kh * 8 + 7][swn] = bv1.w;
  } else {
    *(float4*)&Bs[0][kr][swc] = bv0;
    *(float4*)&Bs[0][kr + 8][swc] = bv1;
  }
  const int nk = K >> 4;
  if (nk > 1) {
    av0 = *(const float4*)&A[arow + 16 + kh * 8];
    av1 = *(const float4*)&A[arow + 16 + kh * 8 + 4];
    if (BT) {
      bv0 = *(const float4*)&B[brow + 16 + kh * 8];
      bv1 = *(const float4*)&B[brow + 16 + kh * 8 + 4];
    } else {
      bv0 = *(const float4*)&B[(size_t)(16 + kr) * N + bn * 128 + c4];
      bv1 = *(const float4*)&B[(size_t)(16 + kr + 8) * N + bn * 128 + c4];
    }
  }
  __syncthreads();

  for (int ki = 0; ki < nk; ++ki) {
    const int p = ki & 1;
    if (ki + 1 < nk) {
      As[p ^ 1][kh * 8 + 0][mload] = av0.x; As[p ^ 1][kh * 8 + 1][mload] = av0.y;
      As[p ^ 1][kh * 8 + 2][mload] = av0.z; As[p ^ 1][kh * 8 + 3][mload] = av0.w;
      As[p ^ 1][kh * 8 + 4][mload] = av1.x; As[p ^ 1][kh * 8 + 5][mload] = av1.y;
      As[p ^ 1][kh * 8 + 6][mload] = av1.z; As[p ^ 1][kh * 8 + 7][mload] = av1.w;
      if (BT) {
        Bs[p ^ 1][kh * 8 + 0][swn] = bv0.x; Bs[p ^ 1][kh * 8 + 1][swn] = bv0.y;
        Bs[p ^ 1][kh * 8 + 2][swn] = bv0.z; Bs[p ^ 1][kh * 8 + 3][swn] = bv0.w;
        Bs[p ^ 1][kh * 8 + 4][swn] = bv1.x; Bs[p ^ 1][kh * 8 + 5][swn] = bv1.y;
        Bs[p ^ 1][kh * 8 + 6][swn] = bv1.z; Bs[p ^ 1][kh * 8 + 7][swn] = bv1.w;
      } else {
        *(float4*)&Bs[p ^ 1][kr][swc] = bv0;
        *(float4*)&Bs[p ^ 1][kr + 8][swc] = bv1;
      }
      if (ki + 2 < nk) {
        const int k2 = (ki + 2) << 4;
        av0 = *(const float4*)&A[arow + k2 + kh * 8];
        av1 = *(const float4*)&A[arow + k2 + kh * 8 + 4];
        if (BT) {
          bv0 = *(const float4*)&B[brow + k2 + kh * 8];
          bv1 = *(const float4*)&B[brow + k2 + kh * 8 + 4];
        } else {
          bv0 = *(const float4*)&B[(size_t)(k2 + kr) * N + bn * 128 + c4];
          bv1 = *(const float4*)&B[(size_t)(k2 + kr + 8) * N + bn * 128 + c4];
        }
      }
    }
    #pragma unroll
    for (int kk = 0; kk < 16; ++kk) {
      const float4 a0 = *(const float4*)&As[p][kk][ty * 8];
      const float4 a1 = *(const float4*)&As[p][kk][ty * 8 + 4];
      const float4 b0 = *(const float4*)&Bs[p][kk][boff];
      const float4 b1 = *(const float4*)&Bs[p][kk][boff + 32];
      const float ar[8] = {a0.x, a0.y, a0.z, a0.w, a1.x, a1.y, a1.z, a1.w};
      const float br[8] = {b0.x, b0.y, b0.z, b0.w, b1.x, b1.y, b1.z, b1.w};
      #pragma unroll
      for (int r = 0; r < 8; ++r)
        #pragma unroll
        for (int c = 0; c < 8; ++c) acc[r][c] = fmaf(ar[r], br[c], acc[r][c]);
    }
    __syncthreads();
  }

  const int gcol = bn * 128 + tx * 8;
  float bb[8] = {0, 0, 0, 0, 0, 0, 0, 0};
  if (bias) {
    const float4 v0 = *(const float4*)&bias[gcol];
    const float4 v1 = *(const float4*)&bias[gcol + 4];
    bb[0] = v0.x; bb[1] = v0.y; bb[2] = v0.z; bb[3] = v0.w;
    bb[4] = v1.x; bb[5] = v1.y; bb[6] = v1.z; bb[7] = v1.w;
  }
  #pragma unroll
  for (int r = 0; r < 8; ++r) {
    float* cp = &C[(size_t)(bm * 128 + ty * 8 + r) * N + gcol];
    float4 o0, o1;
    o0.x = acc[r][0] + bb[0]; o0.y = acc[r][1] + bb[1];
    o0.z = acc[r][2] + bb[2]; o0.w = acc[r][3] + bb[3];
    o1.x = acc[r][4] + bb[4]; o1.y = acc[r][5] + bb[5];
    o1.z = acc[r][6] + bb[6]; o1.w = acc[r][7] + bb[7];
    *(float4*)cp = o0;
    *(float4*)(cp + 4) = o1;
  }
}

// ---------------------------------------------------------------------------
// OpenBLAS-emulating GEMM: C[M,N] = A[M,K]@B[N,K]^T + bias (bit-exact chains).
// dist-kernel structure: 128x128 tile, 8x8 microtile, chunk=32, dbuf,
// two-plane B staging. Sequential-k chains, panel joins per mask.
// ---------------------------------------------------------------------------
__global__ __launch_bounds__(256) void emul_gemm_kernel(
    const float* __restrict__ A, const float* __restrict__ B,
    const float* __restrict__ bias, float* __restrict__ C,
    int N, int K, int lda, int ldb, unsigned long long panel_mask) {
  __shared__ float As_[2][32][128];
  __shared__ float Bs_[2][32][128];
  const int tid = threadIdx.x;
  const int tx = tid & 15, ty = tid >> 4;
  const int row0 = blockIdx.y * 128, col0 = blockIdx.x * 128;
  const int sr = tid & 127, sh = tid >> 7;  // stage: row/col idx, k-half(16)
  const int scol = (((sr >> 2) & 1) << 6) + ((sr >> 3) << 2) + (sr & 3);

  float part[8][8], total[8][8];  // [row][col]
  #pragma unroll
  for (int r = 0; r < 8; ++r)
    #pragma unroll
    for (int e = 0; e < 8; ++e) { part[r][e] = 0.f; total[r][e] = 0.f; }

  float4 av[4], bv[4];
  #pragma unroll
  for (int q = 0; q < 4; ++q) {
    av[q] = *(const float4*)&A[(size_t)(row0 + sr) * lda + sh * 16 + q * 4];
    bv[q] = *(const float4*)&B[(size_t)(col0 + sr) * ldb + sh * 16 + q * 4];
  }
  #pragma unroll
  for (int q = 0; q < 4; ++q) {
    As_[0][sh * 16 + q * 4 + 0][sr] = av[q].x;
    As_[0][sh * 16 + q * 4 + 1][sr] = av[q].y;
    As_[0][sh * 16 + q * 4 + 2][sr] = av[q].z;
    As_[0][sh * 16 + q * 4 + 3][sr] = av[q].w;
    Bs_[0][sh * 16 + q * 4 + 0][scol] = bv[q].x;
    Bs_[0][sh * 16 + q * 4 + 1][scol] = bv[q].y;
    Bs_[0][sh * 16 + q * 4 + 2][scol] = bv[q].z;
    Bs_[0][sh * 16 + q * 4 + 3][scol] = bv[q].w;
  }
  const int nch = K >> 5;
  if (nch > 1) {
    #pragma unroll
    for (int q = 0; q < 4; ++q) {
      av[q] = *(const float4*)&A[(size_t)(row0 + sr) * lda + 32 + sh * 16 + q * 4];
      bv[q] = *(const float4*)&B[(size_t)(col0 + sr) * ldb + 32 + sh * 16 + q * 4];
    }
  }
  __syncthreads();

  for (int ci = 0; ci < nch; ++ci) {
    const int p = ci & 1;
    if (ci + 1 < nch) {
      #pragma unroll
      for (int q = 0; q < 4; ++q) {
        As_[p ^ 1][sh * 16 + q * 4 + 0][sr] = av[q].x;
        As_[p ^ 1][sh * 16 + q * 4 + 1][sr] = av[q].y;
        As_[p ^ 1][sh * 16 + q * 4 + 2][sr] = av[q].z;
        As_[p ^ 1][sh * 16 + q * 4 + 3][sr] = av[q].w;
        Bs_[p ^ 1][sh * 16 + q * 4 + 0][scol] = bv[q].x;
        Bs_[p ^ 1][sh * 16 + q * 4 + 1][scol] = bv[q].y;
        Bs_[p ^ 1][sh * 16 + q * 4 + 2][scol] = bv[q].z;
        Bs_[p ^ 1][sh * 16 + q * 4 + 3][scol] = bv[q].w;
      }
      if (ci + 2 < nch) {
        const int k2 = (ci + 2) << 5;
        #pragma unroll
        for (int q = 0; q < 4; ++q) {
          av[q] = *(const float4*)&A[(size_t)(row0 + sr) * lda + k2 + sh * 16 + q * 4];
          bv[q] = *(const float4*)&B[(size_t)(col0 + sr) * ldb + k2 + sh * 16 + q * 4];
        }
      }
    }
    if (ci && ((panel_mask >> ci) & 1ULL)) {  // OpenBLAS kc panel boundary
      #pragma unroll
      for (int r = 0; r < 8; ++r)
        #pragma unroll
        for (int e = 0; e < 8; ++e) { total[r][e] = total[r][e] + part[r][e]; part[r][e] = 0.f; }
    }
    #pragma unroll 4
    for (int kk = 0; kk < 32; ++kk) {
      const float4 za = *(const float4*)&As_[p][kk][ty * 8];
      const float4 zb = *(const float4*)&As_[p][kk][ty * 8 + 4];
      const float4 ca = *(const float4*)&Bs_[p][kk][tx * 4];
      const float4 cb4 = *(const float4*)&Bs_[p][kk][64 + tx * 4];
      const float zr[8] = {za.x, za.y, za.z, za.w, zb.x, zb.y, zb.z, zb.w};
      const float cr[8] = {ca.x, ca.y, ca.z, ca.w, cb4.x, cb4.y, cb4.z, cb4.w};
      #pragma unroll
      for (int r = 0; r < 8; ++r)
        #pragma unroll
        for (int e = 0; e < 8; ++e)
          part[r][e] = __builtin_fmaf(zr[r], cr[e], part[r][e]);
    }
    __syncthreads();
  }
  #pragma unroll
  for (int r = 0; r < 8; ++r)
    #pragma unroll
    for (int e = 0; e < 8; ++e) total[r][e] = total[r][e] + part[r][e];

  const float4 ba = *(const float4*)&bias[col0 + tx * 8];
  const float4 bb = *(const float4*)&bias[col0 + tx * 8 + 4];
  const float br8[8] = {ba.x, ba.y, ba.z, ba.w, bb.x, bb.y, bb.z, bb.w};
  #pragma unroll
  for (int r = 0; r < 8; ++r) {
    float* cp = &C[(size_t)(row0 + ty * 8 + r) * N + col0 + tx * 8];
    float4 o0, o1;
    o0.x = total[r][0] + br8[0]; o0.y = total[r][1] + br8[1];
    o0.z = total[r][2] + br8[2]; o0.w = total[r][3] + br8[3];
    o1.x = total[r][4] + br8[4]; o1.y = total[r][5] + br8[5];
    o1.z = total[r][6] + br8[6]; o1.w = total[r][7] + br8[7];
    *(float4*)cp = o0;
    *(float4*)(cp + 4) = o1;
  }
}

// ---------------------------------------------------------------------------
// bf16 MFMA recon: C[8192,2048] = zq[8192,1024] @ W_dc[2048,1024]^T + b_dc.
// 2%-threshold output. 128x128 tile, 4 waves (64x64 each), BK=64.
// f32->bf16 RNE on the fly; XOR-swizzled LDS ((row&7)<<4) for b128 frag reads.
// Layouts (m89-verified): A/B operand idx=lane&15, k=8*(lane>>4)+b;
// C/D col=lane&15, row=4*(lane>>4)+reg.
// ---------------------------------------------------------------------------
__global__ __launch_bounds__(256) void mfma_recon_kernel(
    const float* __restrict__ A, const float* __restrict__ B,
    const float* __restrict__ bias, float* __restrict__ C) {
  __shared__ unsigned short Abf[128 * 64];
  __shared__ unsigned short Bbf[128 * 64];
  const int tid = threadIdx.x;
  const int wid = tid >> 6, lane = tid & 63;
  const int row0 = blockIdx.y * 128, col0 = blockIdx.x * 128;
  const int wr = (wid >> 1) * 64, wc = (wid & 1) * 64;

  f32x4 acc[4][4];
  #pragma unroll
  for (int m = 0; m < 4; ++m)
    #pragma unroll
    for (int n = 0; n < 4; ++n)
      #pragma unroll
      for (int j = 0; j < 4; ++j) acc[m][n][j] = 0.f;

  for (int k0 = 0; k0 < 1024; k0 += 64) {
    __syncthreads();
    #pragma unroll
    for (int q = 0; q < 4; ++q) {
      const int g = tid + q * 256;     // 0..1023
      const int r = g >> 3;            // row/col index 0..127
      const int kg = (g & 7) * 8;      // k-group base
      const float4 a0 = *(const float4*)&A[(size_t)(row0 + r) * 1024 + k0 + kg];
      const float4 a1 = *(const float4*)&A[(size_t)(row0 + r) * 1024 + k0 + kg + 4];
      const float4 b0 = *(const float4*)&B[(size_t)(col0 + r) * 1024 + k0 + kg];
      const float4 b1 = *(const float4*)&B[(size_t)(col0 + r) * 1024 + k0 + kg + 4];
      ushort8 pa, pb;
      pa[0] = f2bf(a0.x); pa[1] = f2bf(a0.y); pa[2] = f2bf(a0.z); pa[3] = f2bf(a0.w);
      pa[4] = f2bf(a1.x); pa[5] = f2bf(a1.y); pa[6] = f2bf(a1.z); pa[7] = f2bf(a1.w);
      pb[0] = f2bf(b0.x); pb[1] = f2bf(b0.y); pb[2] = f2bf(b0.z); pb[3] = f2bf(b0.w);
      pb[4] = f2bf(b1.x); pb[5] = f2bf(b1.y); pb[6] = f2bf(b1.z); pb[7] = f2bf(b1.w);
      const int byte = (r * 128 + kg * 2) ^ ((r & 7) << 4);
      *(ushort8*)((char*)Abf + byte) = pa;
      *(ushort8*)((char*)Bbf + byte) = pb;
    }
    __syncthreads();
    #pragma unroll
    for (int kh = 0; kh < 2; ++kh) {  // two K=32 mfma steps per BK=64
      const int kb = kh * 32 + 8 * (lane >> 4);
      short8 afr[4], bfr[4];
      #pragma unroll
      for (int m = 0; m < 4; ++m) {
        const int r = wr + m * 16 + (lane & 15);
        const int byte = (r * 128 + kb * 2) ^ ((r & 7) << 4);
        afr[m] = *(const short8*)((const char*)Abf + byte);
      }
      #pragma unroll
      for (int n = 0; n < 4; ++n) {
        const int r = wc + n * 16 + (lane & 15);
        const int byte = (r * 128 + kb * 2) ^ ((r & 7) << 4);
        bfr[n] = *(const short8*)((const char*)Bbf + byte);
      }
      #pragma unroll
      for (int m = 0; m < 4; ++m)
        #pragma unroll
        for (int n = 0; n < 4; ++n)
          acc[m][n] = __builtin_amdgcn_mfma_f32_16x16x32_bf16(
              afr[m], bfr[n], acc[m][n], 0, 0, 0);
    }
  }

  #pragma unroll
  for (int m = 0; m < 4; ++m)
    #pragma unroll
    for (int n = 0; n < 4; ++n) {
      const int col = col0 + wc + n * 16 + (lane & 15);
      const float bc = bias[col];
      #pragma unroll
      for (int j = 0; j < 4; ++j) {
        const int row = row0 + wr + m * 16 + (lane >> 4) * 4 + j;
        C[(size_t)row * 2048 + col] = acc[m][n][j] + bc;
      }
    }
}

// ---------------------------------------------------------------------------
// numpy pairwise_sum emulation of sum(x*x) over rows of 1024 (unchanged).
// ---------------------------------------------------------------------------
__global__ __launch_bounds__(256) void sumsq1024_kernel(
    const float* __restrict__ X, float* __restrict__ out) {
  __shared__ float rows[4][1024];
  __shared__ float leaves[4][8];
  const int tid = threadIdx.x;
  const int row0 = blockIdx.x * 4;
  for (int i = tid; i < 4096; i += 256)
    rows[i >> 10][i & 1023] = X[(size_t)row0 * 1024 + i];
  __syncthreads();
  if (tid < 32) {
    const int r = tid >> 3, lf = tid & 7;
    const float* a = &rows[r][lf * 128];
    float s0 = sqf(a[0]), s1 = sqf(a[1]), s2 = sqf(a[2]), s3 = sqf(a[3]);
    float s4 = sqf(a[4]), s5 = sqf(a[5]), s6 = sqf(a[6]), s7 = sqf(a[7]);
    for (int i = 8; i < 128; i += 8) {
      s0 = s0 + sqf(a[i + 0]); s1 = s1 + sqf(a[i + 1]);
      s2 = s2 + sqf(a[i + 2]); s3 = s3 + sqf(a[i + 3]);
      s4 = s4 + sqf(a[i + 4]); s5 = s5 + sqf(a[i + 5]);
      s6 = s6 + sqf(a[i + 6]); s7 = s7 + sqf(a[i + 7]);
    }
    leaves[r][lf] = ((s0 + s1) + (s2 + s3)) + ((s4 + s5) + (s6 + s7));
  }
  __syncthreads();
  if (tid < 4) {
    const float* L = leaves[tid];
    const float p01 = L[0] + L[1], p23 = L[2] + L[3];
    const float p45 = L[4] + L[5], p67 = L[6] + L[7];
    out[row0 + tid] = ((p01 + p23) + (p45 + p67));
  }
}

// ---------------------------------------------------------------------------
// Emulated distance GEMM + per-128-entry-chunk first-index argmin (unchanged
// from round 10, PASSED).
// ---------------------------------------------------------------------------
__global__ __launch_bounds__(256) void emul_dot_argmin_kernel(
    const float* __restrict__ Z, const float* __restrict__ CB,
    const float* __restrict__ Z2, const float* __restrict__ C2,
    float2* __restrict__ parts) {
  __shared__ float Zs[2][32][128];
  __shared__ float Cs[2][32][128];
  const int tid = threadIdx.x;
  const int tx = tid & 15, ty = tid >> 4;
  const int row0 = blockIdx.y * 128, e0 = blockIdx.x * 128;
  const int sr = tid & 127, sh = tid >> 7;
  const int scol = (((sr >> 2) & 1) << 6) + ((sr >> 3) << 2) + (sr & 3);

  float part[8][8], total[8][8];
  #pragma unroll
  for (int r = 0; r < 8; ++r)
    #pragma unroll
    for (int e = 0; e < 8; ++e) { part[r][e] = 0.f; total[r][e] = 0.f; }

  float4 zv[4], cv[4];
  #pragma unroll
  for (int q = 0; q < 4; ++q) {
    zv[q] = *(const float4*)&Z[(size_t)(row0 + sr) * 1024 + sh * 16 + q * 4];
    cv[q] = *(const float4*)&CB[(size_t)(e0 + sr) * 1024 + sh * 16 + q * 4];
  }
  #pragma unroll
  for (int q = 0; q < 4; ++q) {
    Zs[0][sh * 16 + q * 4 + 0][sr] = zv[q].x;
    Zs[0][sh * 16 + q * 4 + 1][sr] = zv[q].y;
    Zs[0][sh * 16 + q * 4 + 2][sr] = zv[q].z;
    Zs[0][sh * 16 + q * 4 + 3][sr] = zv[q].w;
    Cs[0][sh * 16 + q * 4 + 0][scol] = cv[q].x;
    Cs[0][sh * 16 + q * 4 + 1][scol] = cv[q].y;
    Cs[0][sh * 16 + q * 4 + 2][scol] = cv[q].z;
    Cs[0][sh * 16 + q * 4 + 3][scol] = cv[q].w;
  }
  #pragma unroll
  for (int q = 0; q < 4; ++q) {
    zv[q] = *(const float4*)&Z[(size_t)(row0 + sr) * 1024 + 32 + sh * 16 + q * 4];
    cv[q] = *(const float4*)&CB[(size_t)(e0 + sr) * 1024 + 32 + sh * 16 + q * 4];
  }
  __syncthreads();

  for (int ci = 0; ci < 32; ++ci) {
    const int p = ci & 1;
    if (ci + 1 < 32) {
      #pragma unroll
      for (int q = 0; q < 4; ++q) {
        Zs[p ^ 1][sh * 16 + q * 4 + 0][sr] = zv[q].x;
        Zs[p ^ 1][sh * 16 + q * 4 + 1][sr] = zv[q].y;
        Zs[p ^ 1][sh * 16 + q * 4 + 2][sr] = zv[q].z;
        Zs[p ^ 1][sh * 16 + q * 4 + 3][sr] = zv[q].w;
        Cs[p ^ 1][sh * 16 + q * 4 + 0][scol] = cv[q].x;
        Cs[p ^ 1][sh * 16 + q * 4 + 1][scol] = cv[q].y;
        Cs[p ^ 1][sh * 16 + q * 4 + 2][scol] = cv[q].z;
        Cs[p ^ 1][sh * 16 + q * 4 + 3][scol] = cv[q].w;
      }
      if (ci + 2 < 32) {
        const int k2 = (ci + 2) << 5;
        #pragma unroll
        for (int q = 0; q < 4; ++q) {
          zv[q] = *(const float4*)&Z[(size_t)(row0 + sr) * 1024 + k2 + sh * 16 + q * 4];
          cv[q] = *(const float4*)&CB[(size_t)(e0 + sr) * 1024 + k2 + sh * 16 + q * 4];
        }
      }
    }
    if (ci && ((PANEL_MASK_K1024_C32 >> ci) & 1ULL)) {
      #pragma unroll
      for (int r = 0; r < 8; ++r)
        #pragma unroll
        for (int e = 0; e < 8; ++e) { total[r][e] = total[r][e] + part[r][e]; part[r][e] = 0.f; }
    }
    #pragma unroll 4
    for (int kk = 0; kk < 32; ++kk) {
      const float4 za = *(const float4*)&Zs[p][kk][ty * 8];
      const float4 zb = *(const float4*)&Zs[p][kk][ty * 8 + 4];
      const float4 ca = *(const float4*)&Cs[p][kk][tx * 4];
      const float4 cb4 = *(const float4*)&Cs[p][kk][64 + tx * 4];
      const float zr[8] = {za.x, za.y, za.z, za.w, zb.x, zb.y, zb.z, zb.w};
      const float cr[8] = {ca.x, ca.y, ca.z, ca.w, cb4.x, cb4.y, cb4.z, cb4.w};
      #pragma unroll
      for (int r = 0; r < 8; ++r)
        #pragma unroll
        for (int e = 0; e < 8; ++e)
          part[r][e] = __builtin_fmaf(zr[r], cr[e], part[r][e]);
    }
    __syncthreads();
  }
  #pragma unroll
  for (int r = 0; r < 8; ++r)
    #pragma unroll
    for (int e = 0; e < 8; ++e) total[r][e] = total[r][e] + part[r][e];

  const float4 c2a = *(const float4*)&C2[e0 + tx * 8];
  const float4 c2b = *(const float4*)&C2[e0 + tx * 8 + 4];
  const float c2r[8] = {c2a.x, c2a.y, c2a.z, c2a.w, c2b.x, c2b.y, c2b.z, c2b.w};
  #pragma unroll
  for (int rr = 0; rr < 8; ++rr) {
    const int row = row0 + ty * 8 + rr;
    const float z2r = Z2[row];
    float bd = FLT_MAX;
    int be = 0;
    #pragma unroll
    for (int j = 0; j < 8; ++j) {
      const float d = __builtin_fmaf(-2.0f, total[rr][j], z2r) + c2r[j];
      if (d < bd) { bd = d; be = e0 + tx * 8 + j; }
    }
    #pragma unroll
    for (int m = 1; m < 16; m <<= 1) {
      const float od = __shfl_xor(bd, m, 64);
      const int oe = __shfl_xor(be, m, 64);
      if (od < bd || (od == bd && oe < be)) { bd = od; be = oe; }
    }
    if (tx == 0)
      parts[(size_t)row * 64 + blockIdx.x] = make_float2(bd, __int_as_float(be));
  }
}

__global__ __launch_bounds__(256) void rowmin_kernel(
    const float2* __restrict__ parts, int* __restrict__ ids,
    float* __restrict__ o_ids) {
  const int row = blockIdx.x * 256 + threadIdx.x;
  float bd = FLT_MAX;
  int bi = 0;
  for (int c = 0; c < 64; ++c) {
    const float2 p = parts[(size_t)row * 64 + c];
    if (p.x < bd) { bd = p.x; bi = __float_as_int(p.y); }
  }
  ids[row] = bi;
  o_ids[row] = (float)bi;
}

__global__ __launch_bounds__(256) void gather_zq_kernel(
    const float* __restrict__ cb, const int* __restrict__ ids,
    float* __restrict__ zq) {
  const int row = blockIdx.x;
  const int id = ids[row];
  const float4 v = *(const float4*)&cb[(size_t)id * DIM + threadIdx.x * 4];
  *(float4*)&zq[(size_t)row * DIM + threadIdx.x * 4] = v;
}

__global__ __launch_bounds__(256) void rowdot_bias_kernel(
    const float* __restrict__ W, const float* __restrict__ v,
    const float* __restrict__ b2, float* __restrict__ out) {
  const int row = blockIdx.x;
  const float4 w4 = *(const float4*)&W[(size_t)row * 1024 + threadIdx.x * 4];
  const float4 v4 = *(const float4*)&v[threadIdx.x * 4];
  const float s = w4.x * v4.x + w4.y * v4.y + w4.z * v4.z + w4.w * v4.w;
  const float r = block_reduce_sum(s);
  if (threadIdx.x == 0) out[row] = r + b2[row];
}

__global__ __launch_bounds__(256) void sqdiff_partial_kernel(
    const float* __restrict__ a, const float* __restrict__ b,
    float* __restrict__ part) {
  const size_t base = (size_t)blockIdx.x * 2048 + (size_t)threadIdx.x * 8;
  const float4 x0 = *(const float4*)&a[base];
  const float4 x1 = *(const float4*)&a[base + 4];
  const float4 y0 = *(const float4*)&b[base];
  const float4 y1 = *(const float4*)&b[base + 4];
  float s = 0.f;
  float d;
  d = x0.x - y0.x; s += d * d; d = x0.y - y0.y; s += d * d;
  d = x0.z - y0.z; s += d * d; d = x0.w - y0.w; s += d * d;
  d = x1.x - y1.x; s += d * d; d = x1.y - y1.y; s += d * d;
  d = x1.z - y1.z; s += d * d; d = x1.w - y1.w; s += d * d;
  const float r = block_reduce_sum(s);
  if (threadIdx.x == 0) part[blockIdx.x] = r;
}

__global__ __launch_bounds__(256) void final_losses_kernel(
    const float* __restrict__ rp, const float* __restrict__ ep,
    float* __restrict__ o) {
  __shared__ double sh[4];
  const int lane = threadIdx.x & 63, w = threadIdx.x >> 6;
  double s = 0.0;
  for (int i = threadIdx.x; i < 8192; i += 256) s += (double)rp[i];
  #pragma unroll
  for (int off = 32; off > 0; off >>= 1) s += __shfl_down(s, off, 64);
  if (lane == 0) sh[w] = s;
  __syncthreads();
  double rl = 0.0;
  if (threadIdx.x == 0) rl = (sh[0] + sh[1] + sh[2] + sh[3]) / ((double)N_ROWS * IN_DIM);
  __syncthreads();
  double s2 = 0.0;
  for (int i = threadIdx.x; i < 4096; i += 256) s2 += (double)ep[i];
  #pragma unroll
  for (int off = 32; off > 0; off >>= 1) s2 += __shfl_down(s2, off, 64);
  if (lane == 0) sh[w] = s2;
  __syncthreads();
  if (threadIdx.x == 0) {
    const double el = (sh[0] + sh[1] + sh[2] + sh[3]) / ((double)N_ROWS * DIM);
    o[0] = (float)(rl + el + 0.25 * el);
    o[1] = (float)rl;
    o[2] = (float)el;
    o[3] = (float)el;
  }
}

extern "C" void kernel_launch(void* const* d_in, const int* in_sizes, int n_in,
                              void* d_out, int out_size, void* d_ws, size_t ws_size,
                              hipStream_t stream) {
  const float* roi   = (const float*)d_in[0];
  const float* W_in  = (const float*)d_in[1];
  const float* b_in  = (const float*)d_in[2];
  const float* W_enc = (const float*)d_in[3];
  const float* b_enc = (const float*)d_in[4];
  const float* cb    = (const float*)d_in[5];
  const float* W_dec = (const float*)d_in[6];
  const float* b_dec = (const float*)d_in[7];
  const float* W_out = (const float*)d_in[8];
  const float* b_out = (const float*)d_in[9];

  float* out = (float*)d_out;
  float* o_ids   = out;
  float* o_zq    = out + 8192;
  float* o_recon = out + 8192 + (size_t)N_ROWS * DIM;
  float* o_scal  = out + 8192 + (size_t)N_ROWS * DIM + (size_t)N_ROWS * IN_DIM;

  // ws layout (float offsets)
  float*  ws    = (float*)d_ws;
  float*  W_dc  = ws;                          // 2,097,152
  float2* parts = (float2*)(ws + 2097152);     // 8192*64 float2 = 1,048,576 f
  float*  z2    = ws + 4194304;                // 8192
  float*  c2    = ws + 4202496;                // 8192
  int*    ids   = (int*)(ws + 4210688);        // 8192
  float*  b_dc  = ws + 4218880;                // 2048
  float*  ep    = ws + 4220928;                // 4096
  float*  rp    = ws + 4225024;                // 8192

  // t and z (f32, each 8192x1024) live in the o_recon region (16.8M floats).
  float* t = o_recon;
  float* z = o_recon + (size_t)N_ROWS * DIM;

  // decoder fusion (2%-threshold outputs)
  rowdot_bias_kernel<<<IN_DIM, 256, 0, stream>>>(W_out, b_dec, b_out, b_dc);
  gemm128<false><<<dim3(DIM / 128, IN_DIM / 128), 256, 0, stream>>>(
      W_out, W_dec, nullptr, W_dc, IN_DIM, DIM, DIM);

  // ---- np-f32 emulated encoder (bit-exact chains, 128x128 structure) ----
  emul_gemm_kernel<<<dim3(DIM / 128, N_ROWS / 128), 256, 0, stream>>>(
      roi, W_in, b_in, t, DIM, IN_DIM, IN_DIM, IN_DIM, PANEL_MASK_K2048_C32);
  emul_gemm_kernel<<<dim3(DIM / 128, N_ROWS / 128), 256, 0, stream>>>(
      t, W_enc, b_enc, z, DIM, DIM, DIM, DIM, PANEL_MASK_K1024_C32);

  // ---- np pairwise row sums of squares ----
  sumsq1024_kernel<<<N_ROWS / 4, 256, 0, stream>>>(z, z2);
  sumsq1024_kernel<<<CBK / 4, 256, 0, stream>>>(cb, c2);

  // ---- emulated f32 distances + first-index argmin ----
  emul_dot_argmin_kernel<<<dim3(CBK / 128, N_ROWS / 128), 256, 0, stream>>>(
      z, cb, z2, c2, parts);
  rowmin_kernel<<<N_ROWS / 256, 256, 0, stream>>>(parts, ids, o_ids);

  // ---- outputs ----
  gather_zq_kernel<<<N_ROWS, 256, 0, stream>>>(cb, ids, o_zq);
  sqdiff_partial_kernel<<<(N_ROWS * DIM) / 2048, 256, 0, stream>>>(o_zq, z, ep);

  // recon via bf16 MFMA (overwrites t/z region AFTER ep consumed z)
  mfma_recon_kernel<<<dim3(IN_DIM / 128, N_ROWS / 128), 256, 0, stream>>>(
      o_zq, W_dc, b_dc, o_recon);

  sqdiff_partial_kernel<<<(N_ROWS * IN_DIM) / 2048, 256, 0, stream>>>(
      o_recon, roi, rp);
  final_losses_kernel<<<1, 256, 0, stream>>>(rp, ep, o_scal);
}

// Round 13
// 1536.901 us; speedup vs baseline: 3.3027x; 1.5949x over previous
//
#include <hip/hip_runtime.h>
#include <float.h>

// ---------------------------------------------------------------------------
// VQ-VAE quantizer forward — round 13 (= round 12 with the vector-element
// reference compile fix): ids path = certified bf16x2 MFMA screen + exact
// emulated-chain rescore of the certified candidate set.
//   screen: d~ = fma(-2, mfma(z_hi,c_hi)+mfma(z_hi,c_lo)+mfma(z_lo,c_hi), z2)+c2
//           |d~ - d_exact| <= ~4.4e-4 worst-case << DELTA=1.2e-3.
//   per (row, 128-chunk): {min d~, cnt, <=12 idx within min+DELTA}.
//   collect: qualifying chunks (min <= gmin+DELTA) -> exact sequential-k f32
//   chain (panel joins k=384,704) on candidates; lexicographic (d,idx) min ==
//   np.argmin first-index. Overflow -> exact full-row scan.
// Encoder t/z GEMMs remain bit-exact OpenBLAS emulation (rounds 7-11 PASSED).
// Decoder recon on bf16 MFMA (2% threshold, r11 PASSED).
// ---------------------------------------------------------------------------

#define N_ROWS 8192
#define IN_DIM 2048
#define DIM 1024
#define CBK 8192

#define PANEL_MASK_K1024_C32 0x0000000000401000ULL  // joins k=384,704
#define PANEL_MASK_K2048_C32 0x0101001001001000ULL  // k=384,768,1152,1536,1792

#define SCREEN_DELTA 1.2e-3f

typedef __attribute__((ext_vector_type(8))) short short8;
typedef __attribute__((ext_vector_type(8))) unsigned short ushort8;
typedef __attribute__((ext_vector_type(4))) float f32x4;

__device__ __forceinline__ float sqf(float v) { return __builtin_fmaf(v, v, 0.0f); }

__device__ __forceinline__ unsigned short f2bf(float f) {  // RNE f32->bf16
  unsigned int u = __float_as_uint(f);
  u += 0x7fffu + ((u >> 16) & 1u);
  return (unsigned short)(u >> 16);
}

// split x = hi + lo (both bf16); returns packed hi | lo<<16
__device__ __forceinline__ unsigned int split_bf(float x) {
  const unsigned short hi = f2bf(x);
  const float hf = __uint_as_float((unsigned)hi << 16);
  const unsigned short lo = f2bf(x - hf);
  return (unsigned)hi | ((unsigned)lo << 16);
}

__device__ __forceinline__ int swz128(int c) {
  return (c & 3) | (((c >> 3) & 7) << 2) | (((c >> 2) & 1) << 5) | ((c >> 6) << 6);
}

__device__ __forceinline__ float block_reduce_sum(float v) {
  __shared__ float sh[4];
  #pragma unroll
  for (int off = 32; off > 0; off >>= 1) v += __shfl_down(v, off, 64);
  const int lane = threadIdx.x & 63, w = threadIdx.x >> 6;
  if (lane == 0) sh[w] = v;
  __syncthreads();
  float r = 0.f;
  if (threadIdx.x == 0) r = sh[0] + sh[1] + sh[2] + sh[3];
  return r;  // valid on thread 0 only
}

// exact emulated-f32 distance: sequential-k chain, panel joins at 384/704.
__device__ __forceinline__ float chain_d(const float* __restrict__ zsh,
                                         const float* __restrict__ cbr,
                                         float z2r, float c2e) {
  float part = 0.f;
  for (int k = 0; k < 384; ++k) part = __builtin_fmaf(zsh[k], cbr[k], part);
  float total = part;
  part = 0.f;
  for (int k = 384; k < 704; ++k) part = __builtin_fmaf(zsh[k], cbr[k], part);
  total = total + part;
  part = 0.f;
  for (int k = 704; k < 1024; ++k) part = __builtin_fmaf(zsh[k], cbr[k], part);
  total = total + part;
  return __builtin_fmaf(-2.0f, total, z2r) + c2e;
}

// ---------------------------------------------------------------------------
// fp32 128x128x16 tiled GEMM (W_dc fusion only). Double-buffered. (r10 PASSED)
// ---------------------------------------------------------------------------
template <bool BT>
__global__ __launch_bounds__(256) void gemm128(
    const float* __restrict__ A, const float* __restrict__ B,
    const float* __restrict__ bias, float* __restrict__ C,
    int M, int N, int K) {
  __shared__ float As[2][16][132];
  __shared__ float Bs[2][16][132];
  const int tid = threadIdx.x;
  const int tx = tid & 15, ty = tid >> 4;
  const int bm = blockIdx.y, bn = blockIdx.x;

  const int mload = tid & 127, kh = tid >> 7;
  const size_t arow = (size_t)(bm * 128 + mload) * (size_t)K;
  const size_t brow = BT ? (size_t)(bn * 128 + mload) * (size_t)K : 0;
  const int swn = swz128(mload);
  const int c4 = (tid & 31) << 2;
  const int kr = tid >> 5;
  const int swc = swz128(c4);

  float acc[8][8];
  #pragma unroll
  for (int r = 0; r < 8; ++r)
    #pragma unroll
    for (int c = 0; c < 8; ++c) acc[r][c] = 0.f;

  const int boff = ((tx & 7) << 2) | ((tx >> 3) << 6);

  float4 av0, av1, bv0, bv1;
  av0 = *(const float4*)&A[arow + kh * 8];
  av1 = *(const float4*)&A[arow + kh * 8 + 4];
  if (BT) {
    bv0 = *(const float4*)&B[brow + kh * 8];
    bv1 = *(const float4*)&B[brow + kh * 8 + 4];
  } else {
    bv0 = *(const float4*)&B[(size_t)kr * N + bn * 128 + c4];
    bv1 = *(const float4*)&B[(size_t)(kr + 8) * N + bn * 128 + c4];
  }
  As[0][kh * 8 + 0][mload] = av0.x; As[0][kh * 8 + 1][mload] = av0.y;
  As[0][kh * 8 + 2][mload] = av0.z; As[0][kh * 8 + 3][mload] = av0.w;
  As[0][kh * 8 + 4][mload] = av1.x; As[0][kh * 8 + 5][mload] = av1.y;
  As[0][kh * 8 + 6][mload] = av1.z; As[0][kh * 8 + 7][mload] = av1.w;
  if (BT) {
    Bs[0][kh * 8 + 0][swn] = bv0.x; Bs[0][kh * 8 + 1][swn] = bv0.y;
    Bs[0][kh * 8 + 2][swn] = bv0.z; Bs[0][kh * 8 + 3][swn] = bv0.w;
    Bs[0][kh * 8 + 4][swn] = bv1.x; Bs[0][kh * 8 + 5][swn] = bv1.y;
    Bs[0][kh * 8 + 6][swn] = bv1.z; Bs[0][kh * 8 + 7][swn] = bv1.w;
  } else {
    *(float4*)&Bs[0][kr][swc] = bv0;
    *(float4*)&Bs[0][kr + 8][swc] = bv1;
  }
  const int nk = K >> 4;
  if (nk > 1) {
    av0 = *(const float4*)&A[arow + 16 + kh * 8];
    av1 = *(const float4*)&A[arow + 16 + kh * 8 + 4];
    if (BT) {
      bv0 = *(const float4*)&B[brow + 16 + kh * 8];
      bv1 = *(const float4*)&B[brow + 16 + kh * 8 + 4];
    } else {
      bv0 = *(const float4*)&B[(size_t)(16 + kr) * N + bn * 128 + c4];
      bv1 = *(const float4*)&B[(size_t)(16 + kr + 8) * N + bn * 128 + c4];
    }
  }
  __syncthreads();

  for (int ki = 0; ki < nk; ++ki) {
    const int p = ki & 1;
    if (ki + 1 < nk) {
      As[p ^ 1][kh * 8 + 0][mload] = av0.x; As[p ^ 1][kh * 8 + 1][mload] = av0.y;
      As[p ^ 1][kh * 8 + 2][mload] = av0.z; As[p ^ 1][kh * 8 + 3][mload] = av0.w;
      As[p ^ 1][kh * 8 + 4][mload] = av1.x; As[p ^ 1][kh * 8 + 5][mload] = av1.y;
      As[p ^ 1][kh * 8 + 6][mload] = av1.z; As[p ^ 1][kh * 8 + 7][mload] = av1.w;
      if (BT) {
        Bs[p ^ 1][kh * 8 + 0][swn] = bv0.x; Bs[p ^ 1][kh * 8 + 1][swn] = bv0.y;
        Bs[p ^ 1][kh * 8 + 2][swn] = bv0.z; Bs[p ^ 1][kh * 8 + 3][swn] = bv0.w;
        Bs[p ^ 1][kh * 8 + 4][swn] = bv1.x; Bs[p ^ 1][kh * 8 + 5][swn] = bv1.y;
        Bs[p ^ 1][kh * 8 + 6][swn] = bv1.z; Bs[p ^ 1][kh * 8 + 7][swn] = bv1.w;
      } else {
        *(float4*)&Bs[p ^ 1][kr][swc] = bv0;
        *(float4*)&Bs[p ^ 1][kr + 8][swc] = bv1;
      }
      if (ki + 2 < nk) {
        const int k2 = (ki + 2) << 4;
        av0 = *(const float4*)&A[arow + k2 + kh * 8];
        av1 = *(const float4*)&A[arow + k2 + kh * 8 + 4];
        if (BT) {
          bv0 = *(const float4*)&B[brow + k2 + kh * 8];
          bv1 = *(const float4*)&B[brow + k2 + kh * 8 + 4];
        } else {
          bv0 = *(const float4*)&B[(size_t)(k2 + kr) * N + bn * 128 + c4];
          bv1 = *(const float4*)&B[(size_t)(k2 + kr + 8) * N + bn * 128 + c4];
        }
      }
    }
    #pragma unroll
    for (int kk = 0; kk < 16; ++kk) {
      const float4 a0 = *(const float4*)&As[p][kk][ty * 8];
      const float4 a1 = *(const float4*)&As[p][kk][ty * 8 + 4];
      const float4 b0 = *(const float4*)&Bs[p][kk][boff];
      const float4 b1 = *(const float4*)&Bs[p][kk][boff + 32];
      const float ar[8] = {a0.x, a0.y, a0.z, a0.w, a1.x, a1.y, a1.z, a1.w};
      const float br[8] = {b0.x, b0.y, b0.z, b0.w, b1.x, b1.y, b1.z, b1.w};
      #pragma unroll
      for (int r = 0; r < 8; ++r)
        #pragma unroll
        for (int c = 0; c < 8; ++c) acc[r][c] = fmaf(ar[r], br[c], acc[r][c]);
    }
    __syncthreads();
  }

  const int gcol = bn * 128 + tx * 8;
  float bb[8] = {0, 0, 0, 0, 0, 0, 0, 0};
  if (bias) {
    const float4 v0 = *(const float4*)&bias[gcol];
    const float4 v1 = *(const float4*)&bias[gcol + 4];
    bb[0] = v0.x; bb[1] = v0.y; bb[2] = v0.z; bb[3] = v0.w;
    bb[4] = v1.x; bb[5] = v1.y; bb[6] = v1.z; bb[7] = v1.w;
  }
  #pragma unroll
  for (int r = 0; r < 8; ++r) {
    float* cp = &C[(size_t)(bm * 128 + ty * 8 + r) * N + gcol];
    float4 o0, o1;
    o0.x = acc[r][0] + bb[0]; o0.y = acc[r][1] + bb[1];
    o0.z = acc[r][2] + bb[2]; o0.w = acc[r][3] + bb[3];
    o1.x = acc[r][4] + bb[4]; o1.y = acc[r][5] + bb[5];
    o1.z = acc[r][6] + bb[6]; o1.w = acc[r][7] + bb[7];
    *(float4*)cp = o0;
    *(float4*)(cp + 4) = o1;
  }
}

// ---------------------------------------------------------------------------
// OpenBLAS-emulating GEMM (bit-exact chains), 128x128 / 8x8, dbuf (r11 PASSED)
// ---------------------------------------------------------------------------
__global__ __launch_bounds__(256) void emul_gemm_kernel(
    const float* __restrict__ A, const float* __restrict__ B,
    const float* __restrict__ bias, float* __restrict__ C,
    int N, int K, int lda, int ldb, unsigned long long panel_mask) {
  __shared__ float As_[2][32][128];
  __shared__ float Bs_[2][32][128];
  const int tid = threadIdx.x;
  const int tx = tid & 15, ty = tid >> 4;
  const int row0 = blockIdx.y * 128, col0 = blockIdx.x * 128;
  const int sr = tid & 127, sh = tid >> 7;
  const int scol = (((sr >> 2) & 1) << 6) + ((sr >> 3) << 2) + (sr & 3);

  float part[8][8], total[8][8];
  #pragma unroll
  for (int r = 0; r < 8; ++r)
    #pragma unroll
    for (int e = 0; e < 8; ++e) { part[r][e] = 0.f; total[r][e] = 0.f; }

  float4 av[4], bv[4];
  #pragma unroll
  for (int q = 0; q < 4; ++q) {
    av[q] = *(const float4*)&A[(size_t)(row0 + sr) * lda + sh * 16 + q * 4];
    bv[q] = *(const float4*)&B[(size_t)(col0 + sr) * ldb + sh * 16 + q * 4];
  }
  #pragma unroll
  for (int q = 0; q < 4; ++q) {
    As_[0][sh * 16 + q * 4 + 0][sr] = av[q].x;
    As_[0][sh * 16 + q * 4 + 1][sr] = av[q].y;
    As_[0][sh * 16 + q * 4 + 2][sr] = av[q].z;
    As_[0][sh * 16 + q * 4 + 3][sr] = av[q].w;
    Bs_[0][sh * 16 + q * 4 + 0][scol] = bv[q].x;
    Bs_[0][sh * 16 + q * 4 + 1][scol] = bv[q].y;
    Bs_[0][sh * 16 + q * 4 + 2][scol] = bv[q].z;
    Bs_[0][sh * 16 + q * 4 + 3][scol] = bv[q].w;
  }
  const int nch = K >> 5;
  if (nch > 1) {
    #pragma unroll
    for (int q = 0; q < 4; ++q) {
      av[q] = *(const float4*)&A[(size_t)(row0 + sr) * lda + 32 + sh * 16 + q * 4];
      bv[q] = *(const float4*)&B[(size_t)(col0 + sr) * ldb + 32 + sh * 16 + q * 4];
    }
  }
  __syncthreads();

  for (int ci = 0; ci < nch; ++ci) {
    const int p = ci & 1;
    if (ci + 1 < nch) {
      #pragma unroll
      for (int q = 0; q < 4; ++q) {
        As_[p ^ 1][sh * 16 + q * 4 + 0][sr] = av[q].x;
        As_[p ^ 1][sh * 16 + q * 4 + 1][sr] = av[q].y;
        As_[p ^ 1][sh * 16 + q * 4 + 2][sr] = av[q].z;
        As_[p ^ 1][sh * 16 + q * 4 + 3][sr] = av[q].w;
        Bs_[p ^ 1][sh * 16 + q * 4 + 0][scol] = bv[q].x;
        Bs_[p ^ 1][sh * 16 + q * 4 + 1][scol] = bv[q].y;
        Bs_[p ^ 1][sh * 16 + q * 4 + 2][scol] = bv[q].z;
        Bs_[p ^ 1][sh * 16 + q * 4 + 3][scol] = bv[q].w;
      }
      if (ci + 2 < nch) {
        const int k2 = (ci + 2) << 5;
        #pragma unroll
        for (int q = 0; q < 4; ++q) {
          av[q] = *(const float4*)&A[(size_t)(row0 + sr) * lda + k2 + sh * 16 + q * 4];
          bv[q] = *(const float4*)&B[(size_t)(col0 + sr) * ldb + k2 + sh * 16 + q * 4];
        }
      }
    }
    if (ci && ((panel_mask >> ci) & 1ULL)) {
      #pragma unroll
      for (int r = 0; r < 8; ++r)
        #pragma unroll
        for (int e = 0; e < 8; ++e) { total[r][e] = total[r][e] + part[r][e]; part[r][e] = 0.f; }
    }
    #pragma unroll 4
    for (int kk = 0; kk < 32; ++kk) {
      const float4 za = *(const float4*)&As_[p][kk][ty * 8];
      const float4 zb = *(const float4*)&As_[p][kk][ty * 8 + 4];
      const float4 ca = *(const float4*)&Bs_[p][kk][tx * 4];
      const float4 cb4 = *(const float4*)&Bs_[p][kk][64 + tx * 4];
      const float zr[8] = {za.x, za.y, za.z, za.w, zb.x, zb.y, zb.z, zb.w};
      const float cr[8] = {ca.x, ca.y, ca.z, ca.w, cb4.x, cb4.y, cb4.z, cb4.w};
      #pragma unroll
      for (int r = 0; r < 8; ++r)
        #pragma unroll
        for (int e = 0; e < 8; ++e)
          part[r][e] = __builtin_fmaf(zr[r], cr[e], part[r][e]);
    }
    __syncthreads();
  }
  #pragma unroll
  for (int r = 0; r < 8; ++r)
    #pragma unroll
    for (int e = 0; e < 8; ++e) total[r][e] = total[r][e] + part[r][e];

  const float4 ba = *(const float4*)&bias[col0 + tx * 8];
  const float4 bb = *(const float4*)&bias[col0 + tx * 8 + 4];
  const float br8[8] = {ba.x, ba.y, ba.z, ba.w, bb.x, bb.y, bb.z, bb.w};
  #pragma unroll
  for (int r = 0; r < 8; ++r) {
    float* cp = &C[(size_t)(row0 + ty * 8 + r) * N + col0 + tx * 8];
    float4 o0, o1;
    o0.x = total[r][0] + br8[0]; o0.y = total[r][1] + br8[1];
    o0.z = total[r][2] + br8[2]; o0.w = total[r][3] + br8[3];
    o1.x = total[r][4] + br8[4]; o1.y = total[r][5] + br8[5];
    o1.z = total[r][6] + br8[6]; o1.w = total[r][7] + br8[7];
    *(float4*)cp = o0;
    *(float4*)(cp + 4) = o1;
  }
}

// ---------------------------------------------------------------------------
// bf16x2 MFMA distance screen. Block = 128 rows x 128 entries, 4 waves,
// K-stage 32. Emits per-(row,chunk) record: {min d~ bits, cnt, 12 idx (u16)}.
// ---------------------------------------------------------------------------
__global__ __launch_bounds__(256) void mfma_screen_kernel(
    const float* __restrict__ Z, const float* __restrict__ CB,
    const float* __restrict__ Z2, const float* __restrict__ C2,
    uint4* __restrict__ recs) {
  __shared__ unsigned short Zhi[128 * 32], Zlo[128 * 32];
  __shared__ unsigned short Chi[128 * 32], Clo[128 * 32];
  __shared__ int rowminI[128];
  __shared__ int cnt[128];
  __shared__ unsigned short cand[128][12];
  const int tid = threadIdx.x;
  const int wid = tid >> 6, lane = tid & 63;
  const int e0 = blockIdx.x * 128, row0 = blockIdx.y * 128;
  const int wr = (wid >> 1) * 64, wc = (wid & 1) * 64;

  if (tid < 128) { rowminI[tid] = 0x7F800000; cnt[tid] = 0; }

  f32x4 acc[4][4];
  #pragma unroll
  for (int m = 0; m < 4; ++m)
    #pragma unroll
    for (int n = 0; n < 4; ++n)
      #pragma unroll
      for (int j = 0; j < 4; ++j) acc[m][n][j] = 0.f;

  const int kb2 = (lane >> 4) * 16;  // byte offset of this lane's k-slice

  for (int k0 = 0; k0 < 1024; k0 += 32) {
    __syncthreads();
    #pragma unroll
    for (int s = 0; s < 2; ++s) {
      const int g = tid + s * 256;
      const int r = g >> 2, kg = (g & 3) * 8;
      const float4 z0 = *(const float4*)&Z[(size_t)(row0 + r) * 1024 + k0 + kg];
      const float4 z1 = *(const float4*)&Z[(size_t)(row0 + r) * 1024 + k0 + kg + 4];
      const float4 c0 = *(const float4*)&CB[(size_t)(e0 + r) * 1024 + k0 + kg];
      const float4 c1 = *(const float4*)&CB[(size_t)(e0 + r) * 1024 + k0 + kg + 4];
      const float zf[8] = {z0.x, z0.y, z0.z, z0.w, z1.x, z1.y, z1.z, z1.w};
      const float cf[8] = {c0.x, c0.y, c0.z, c0.w, c1.x, c1.y, c1.z, c1.w};
      ushort8 zh, zl, ch, cl;
      #pragma unroll
      for (int i = 0; i < 8; ++i) {
        const unsigned int zp = split_bf(zf[i]);
        const unsigned int cp = split_bf(cf[i]);
        zh[i] = (unsigned short)(zp & 0xFFFF);
        zl[i] = (unsigned short)(zp >> 16);
        ch[i] = (unsigned short)(cp & 0xFFFF);
        cl[i] = (unsigned short)(cp >> 16);
      }
      const int byte = (r * 64 + kg * 2) ^ ((r & 3) << 4);
      *(ushort8*)((char*)Zhi + byte) = zh;
      *(ushort8*)((char*)Zlo + byte) = zl;
      *(ushort8*)((char*)Chi + byte) = ch;
      *(ushort8*)((char*)Clo + byte) = cl;
    }
    __syncthreads();
    short8 ah[4], al[4], bh[4], bl[4];
    #pragma unroll
    for (int m = 0; m < 4; ++m) {
      const int r = wr + m * 16 + (lane & 15);
      const int byte = (r * 64 + kb2) ^ ((r & 3) << 4);
      ah[m] = *(const short8*)((const char*)Zhi + byte);
      al[m] = *(const short8*)((const char*)Zlo + byte);
    }
    #pragma unroll
    for (int n = 0; n < 4; ++n) {
      const int r = wc + n * 16 + (lane & 15);
      const int byte = (r * 64 + kb2) ^ ((r & 3) << 4);
      bh[n] = *(const short8*)((const char*)Chi + byte);
      bl[n] = *(const short8*)((const char*)Clo + byte);
    }
    #pragma unroll
    for (int m = 0; m < 4; ++m)
      #pragma unroll
      for (int n = 0; n < 4; ++n) {
        acc[m][n] = __builtin_amdgcn_mfma_f32_16x16x32_bf16(ah[m], bh[n], acc[m][n], 0, 0, 0);
        acc[m][n] = __builtin_amdgcn_mfma_f32_16x16x32_bf16(ah[m], bl[n], acc[m][n], 0, 0, 0);
        acc[m][n] = __builtin_amdgcn_mfma_f32_16x16x32_bf16(al[m], bh[n], acc[m][n], 0, 0, 0);
      }
  }

  // epilogue: d~ values + per-row min + candidate extraction
  float dv[4][4][4];
  #pragma unroll
  for (int m = 0; m < 4; ++m)
    #pragma unroll
    for (int j = 0; j < 4; ++j) {
      const int rg = row0 + wr + m * 16 + (lane >> 4) * 4 + j;
      const float z2r = Z2[rg];
      float lm = FLT_MAX;
      #pragma unroll
      for (int n = 0; n < 4; ++n) {
        const float d = __builtin_fmaf(-2.0f, acc[m][n][j], z2r) +
                        C2[e0 + wc + n * 16 + (lane & 15)];
        dv[m][n][j] = d;
        lm = fminf(lm, d);
      }
      atomicMin(&rowminI[wr + m * 16 + (lane >> 4) * 4 + j], __float_as_int(lm));
    }
  __syncthreads();
  #pragma unroll
  for (int m = 0; m < 4; ++m)
    #pragma unroll
    for (int j = 0; j < 4; ++j) {
      const int rl = wr + m * 16 + (lane >> 4) * 4 + j;
      const float thr = __int_as_float(rowminI[rl]) + SCREEN_DELTA;
      #pragma unroll
      for (int n = 0; n < 4; ++n) {
        if (dv[m][n][j] <= thr) {
          const int pos = atomicAdd(&cnt[rl], 1);
          if (pos < 12)
            cand[rl][pos] = (unsigned short)(e0 + wc + n * 16 + (lane & 15));
        }
      }
    }
  __syncthreads();
  if (tid < 128) {
    uint4 a, b;
    a.x = (unsigned)rowminI[tid];
    a.y = (unsigned)cnt[tid];
    a.z = (unsigned)cand[tid][0] | ((unsigned)cand[tid][1] << 16);
    a.w = (unsigned)cand[tid][2] | ((unsigned)cand[tid][3] << 16);
    b.x = (unsigned)cand[tid][4] | ((unsigned)cand[tid][5] << 16);
    b.y = (unsigned)cand[tid][6] | ((unsigned)cand[tid][7] << 16);
    b.z = (unsigned)cand[tid][8] | ((unsigned)cand[tid][9] << 16);
    b.w = (unsigned)cand[tid][10] | ((unsigned)cand[tid][11] << 16);
    const size_t base = ((size_t)(row0 + tid) * 64 + blockIdx.x) * 2;
    recs[base] = a;
    recs[base + 1] = b;
  }
}

// ---------------------------------------------------------------------------
// Collect + exact rescore: block per row. Qualifying chunks' candidates get
// the exact sequential-k chain; lexicographic (d, idx) min = np first-index.
// ---------------------------------------------------------------------------
__global__ __launch_bounds__(256) void collect_rescore_kernel(
    const uint4* __restrict__ recs, const float* __restrict__ Z,
    const float* __restrict__ CB, const float* __restrict__ Z2,
    const float* __restrict__ C2, int* __restrict__ ids,
    float* __restrict__ o_ids) {
  __shared__ float zsh[1024];
  __shared__ float gmin_sh;
  __shared__ int lcnt, ovf;
  __shared__ unsigned short list[64];
  __shared__ unsigned long long kred[4];
  const int row = blockIdx.x, tid = threadIdx.x;
  if (tid == 0) { lcnt = 0; ovf = 0; }
  uint4 r0 = make_uint4(0, 0, 0, 0), r1 = make_uint4(0, 0, 0, 0);
  float mymin = FLT_MAX;
  if (tid < 64) {
    const size_t base = ((size_t)row * 64 + tid) * 2;
    r0 = recs[base];
    r1 = recs[base + 1];
    mymin = __uint_as_float(r0.x);
  }
  for (int i = tid; i < 1024; i += 256) zsh[i] = Z[(size_t)row * 1024 + i];
  if (tid < 64) {
    float m = mymin;
    #pragma unroll
    for (int off = 32; off > 0; off >>= 1) m = fminf(m, __shfl_down(m, off, 64));
    if (tid == 0) gmin_sh = m;
  }
  __syncthreads();
  const float thr = gmin_sh + SCREEN_DELTA;
  if (tid < 64 && mymin <= thr) {
    const int c = (int)r0.y;
    if (c > 12) {
      atomicOr(&ovf, 1);
    } else {
      unsigned short idxs[12];
      idxs[0] = r0.z & 0xFFFF; idxs[1] = r0.z >> 16;
      idxs[2] = r0.w & 0xFFFF; idxs[3] = r0.w >> 16;
      idxs[4] = r1.x & 0xFFFF; idxs[5] = r1.x >> 16;
      idxs[6] = r1.y & 0xFFFF; idxs[7] = r1.y >> 16;
      idxs[8] = r1.z & 0xFFFF; idxs[9] = r1.z >> 16;
      idxs[10] = r1.w & 0xFFFF; idxs[11] = r1.w >> 16;
      for (int i = 0; i < c; ++i) {
        const int pos = atomicAdd(&lcnt, 1);
        if (pos < 64) list[pos] = idxs[i];
        else atomicOr(&ovf, 1);
      }
    }
  }
  __syncthreads();
  const float z2r = Z2[row];
  unsigned long long key = ~0ULL;
  if (ovf) {  // rare: exact full-row scan
    for (int e = tid; e < CBK; e += 256) {
      const float d = chain_d(zsh, &CB[(size_t)e * 1024], z2r, C2[e]);
      const unsigned long long k =
          ((unsigned long long)__float_as_uint(d) << 32) | (unsigned)e;
      key = (k < key) ? k : key;
    }
  } else {
    const int n = lcnt < 64 ? lcnt : 64;
    if (tid < n) {
      const int e = list[tid];
      const float d = chain_d(zsh, &CB[(size_t)e * 1024], z2r, C2[e]);
      key = ((unsigned long long)__float_as_uint(d) << 32) | (unsigned)e;
    }
  }
  #pragma unroll
  for (int off = 32; off > 0; off >>= 1) {
    const unsigned long long o = __shfl_down(key, off, 64);
    key = (o < key) ? o : key;
  }
  if ((tid & 63) == 0) kred[tid >> 6] = key;
  __syncthreads();
  if (tid == 0) {
    unsigned long long k = kred[0];
    k = (kred[1] < k) ? kred[1] : k;
    k = (kred[2] < k) ? kred[2] : k;
    k = (kred[3] < k) ? kred[3] : k;
    const int e = (int)(k & 0xFFFFFFFFu);
    ids[row] = e;
    o_ids[row] = (float)e;
  }
}

// ---------------------------------------------------------------------------
// bf16 MFMA recon (r11 PASSED, unchanged).
// ---------------------------------------------------------------------------
__global__ __launch_bounds__(256) void mfma_recon_kernel(
    const float* __restrict__ A, const float* __restrict__ B,
    const float* __restrict__ bias, float* __restrict__ C) {
  __shared__ unsigned short Abf[128 * 64];
  __shared__ unsigned short Bbf[128 * 64];
  const int tid = threadIdx.x;
  const int wid = tid >> 6, lane = tid & 63;
  const int row0 = blockIdx.y * 128, col0 = blockIdx.x * 128;
  const int wr = (wid >> 1) * 64, wc = (wid & 1) * 64;

  f32x4 acc[4][4];
  #pragma unroll
  for (int m = 0; m < 4; ++m)
    #pragma unroll
    for (int n = 0; n < 4; ++n)
      #pragma unroll
      for (int j = 0; j < 4; ++j) acc[m][n][j] = 0.f;

  for (int k0 = 0; k0 < 1024; k0 += 64) {
    __syncthreads();
    #pragma unroll
    for (int q = 0; q < 4; ++q) {
      const int g = tid + q * 256;
      const int r = g >> 3;
      const int kg = (g & 7) * 8;
      const float4 a0 = *(const float4*)&A[(size_t)(row0 + r) * 1024 + k0 + kg];
      const float4 a1 = *(const float4*)&A[(size_t)(row0 + r) * 1024 + k0 + kg + 4];
      const float4 b0 = *(const float4*)&B[(size_t)(col0 + r) * 1024 + k0 + kg];
      const float4 b1 = *(const float4*)&B[(size_t)(col0 + r) * 1024 + k0 + kg + 4];
      ushort8 pa, pb;
      pa[0] = f2bf(a0.x); pa[1] = f2bf(a0.y); pa[2] = f2bf(a0.z); pa[3] = f2bf(a0.w);
      pa[4] = f2bf(a1.x); pa[5] = f2bf(a1.y); pa[6] = f2bf(a1.z); pa[7] = f2bf(a1.w);
      pb[0] = f2bf(b0.x); pb[1] = f2bf(b0.y); pb[2] = f2bf(b0.z); pb[3] = f2bf(b0.w);
      pb[4] = f2bf(b1.x); pb[5] = f2bf(b1.y); pb[6] = f2bf(b1.z); pb[7] = f2bf(b1.w);
      const int byte = (r * 128 + kg * 2) ^ ((r & 7) << 4);
      *(ushort8*)((char*)Abf + byte) = pa;
      *(ushort8*)((char*)Bbf + byte) = pb;
    }
    __syncthreads();
    #pragma unroll
    for (int kh = 0; kh < 2; ++kh) {
      const int kb = kh * 32 + 8 * (lane >> 4);
      short8 afr[4], bfr[4];
      #pragma unroll
      for (int m = 0; m < 4; ++m) {
        const int r = wr + m * 16 + (lane & 15);
        const int byte = (r * 128 + kb * 2) ^ ((r & 7) << 4);
        afr[m] = *(const short8*)((const char*)Abf + byte);
      }
      #pragma unroll
      for (int n = 0; n < 4; ++n) {
        const int r = wc + n * 16 + (lane & 15);
        const int byte = (r * 128 + kb * 2) ^ ((r & 7) << 4);
        bfr[n] = *(const short8*)((const char*)Bbf + byte);
      }
      #pragma unroll
      for (int m = 0; m < 4; ++m)
        #pragma unroll
        for (int n = 0; n < 4; ++n)
          acc[m][n] = __builtin_amdgcn_mfma_f32_16x16x32_bf16(
              afr[m], bfr[n], acc[m][n], 0, 0, 0);
    }
  }

  #pragma unroll
  for (int m = 0; m < 4; ++m)
    #pragma unroll
    for (int n = 0; n < 4; ++n) {
      const int col = col0 + wc + n * 16 + (lane & 15);
      const float bc = bias[col];
      #pragma unroll
      for (int j = 0; j < 4; ++j) {
        const int row = row0 + wr + m * 16 + (lane >> 4) * 4 + j;
        C[(size_t)row * 2048 + col] = acc[m][n][j] + bc;
      }
    }
}

// ---------------------------------------------------------------------------
// numpy pairwise_sum emulation of sum(x*x) over rows of 1024 (unchanged).
// ---------------------------------------------------------------------------
__global__ __launch_bounds__(256) void sumsq1024_kernel(
    const float* __restrict__ X, float* __restrict__ out) {
  __shared__ float rows[4][1024];
  __shared__ float leaves[4][8];
  const int tid = threadIdx.x;
  const int row0 = blockIdx.x * 4;
  for (int i = tid; i < 4096; i += 256)
    rows[i >> 10][i & 1023] = X[(size_t)row0 * 1024 + i];
  __syncthreads();
  if (tid < 32) {
    const int r = tid >> 3, lf = tid & 7;
    const float* a = &rows[r][lf * 128];
    float s0 = sqf(a[0]), s1 = sqf(a[1]), s2 = sqf(a[2]), s3 = sqf(a[3]);
    float s4 = sqf(a[4]), s5 = sqf(a[5]), s6 = sqf(a[6]), s7 = sqf(a[7]);
    for (int i = 8; i < 128; i += 8) {
      s0 = s0 + sqf(a[i + 0]); s1 = s1 + sqf(a[i + 1]);
      s2 = s2 + sqf(a[i + 2]); s3 = s3 + sqf(a[i + 3]);
      s4 = s4 + sqf(a[i + 4]); s5 = s5 + sqf(a[i + 5]);
      s6 = s6 + sqf(a[i + 6]); s7 = s7 + sqf(a[i + 7]);
    }
    leaves[r][lf] = ((s0 + s1) + (s2 + s3)) + ((s4 + s5) + (s6 + s7));
  }
  __syncthreads();
  if (tid < 4) {
    const float* L = leaves[tid];
    const float p01 = L[0] + L[1], p23 = L[2] + L[3];
    const float p45 = L[4] + L[5], p67 = L[6] + L[7];
    out[row0 + tid] = ((p01 + p23) + (p45 + p67));
  }
}

__global__ __launch_bounds__(256) void gather_zq_kernel(
    const float* __restrict__ cb, const int* __restrict__ ids,
    float* __restrict__ zq) {
  const int row = blockIdx.x;
  const int id = ids[row];
  const float4 v = *(const float4*)&cb[(size_t)id * DIM + threadIdx.x * 4];
  *(float4*)&zq[(size_t)row * DIM + threadIdx.x * 4] = v;
}

__global__ __launch_bounds__(256) void rowdot_bias_kernel(
    const float* __restrict__ W, const float* __restrict__ v,
    const float* __restrict__ b2, float* __restrict__ out) {
  const int row = blockIdx.x;
  const float4 w4 = *(const float4*)&W[(size_t)row * 1024 + threadIdx.x * 4];
  const float4 v4 = *(const float4*)&v[threadIdx.x * 4];
  const float s = w4.x * v4.x + w4.y * v4.y + w4.z * v4.z + w4.w * v4.w;
  const float r = block_reduce_sum(s);
  if (threadIdx.x == 0) out[row] = r + b2[row];
}

__global__ __launch_bounds__(256) void sqdiff_partial_kernel(
    const float* __restrict__ a, const float* __restrict__ b,
    float* __restrict__ part) {
  const size_t base = (size_t)blockIdx.x * 2048 + (size_t)threadIdx.x * 8;
  const float4 x0 = *(const float4*)&a[base];
  const float4 x1 = *(const float4*)&a[base + 4];
  const float4 y0 = *(const float4*)&b[base];
  const float4 y1 = *(const float4*)&b[base + 4];
  float s = 0.f;
  float d;
  d = x0.x - y0.x; s += d * d; d = x0.y - y0.y; s += d * d;
  d = x0.z - y0.z; s += d * d; d = x0.w - y0.w; s += d * d;
  d = x1.x - y1.x; s += d * d; d = x1.y - y1.y; s += d * d;
  d = x1.z - y1.z; s += d * d; d = x1.w - y1.w; s += d * d;
  const float r = block_reduce_sum(s);
  if (threadIdx.x == 0) part[blockIdx.x] = r;
}

__global__ __launch_bounds__(256) void final_losses_kernel(
    const float* __restrict__ rp, const float* __restrict__ ep,
    float* __restrict__ o) {
  __shared__ double sh[4];
  const int lane = threadIdx.x & 63, w = threadIdx.x >> 6;
  double s = 0.0;
  for (int i = threadIdx.x; i < 8192; i += 256) s += (double)rp[i];
  #pragma unroll
  for (int off = 32; off > 0; off >>= 1) s += __shfl_down(s, off, 64);
  if (lane == 0) sh[w] = s;
  __syncthreads();
  double rl = 0.0;
  if (threadIdx.x == 0) rl = (sh[0] + sh[1] + sh[2] + sh[3]) / ((double)N_ROWS * IN_DIM);
  __syncthreads();
  double s2 = 0.0;
  for (int i = threadIdx.x; i < 4096; i += 256) s2 += (double)ep[i];
  #pragma unroll
  for (int off = 32; off > 0; off >>= 1) s2 += __shfl_down(s2, off, 64);
  if (lane == 0) sh[w] = s2;
  __syncthreads();
  if (threadIdx.x == 0) {
    const double el = (sh[0] + sh[1] + sh[2] + sh[3]) / ((double)N_ROWS * DIM);
    o[0] = (float)(rl + el + 0.25 * el);
    o[1] = (float)rl;
    o[2] = (float)el;
    o[3] = (float)el;
  }
}

extern "C" void kernel_launch(void* const* d_in, const int* in_sizes, int n_in,
                              void* d_out, int out_size, void* d_ws, size_t ws_size,
                              hipStream_t stream) {
  const float* roi   = (const float*)d_in[0];
  const float* W_in  = (const float*)d_in[1];
  const float* b_in  = (const float*)d_in[2];
  const float* W_enc = (const float*)d_in[3];
  const float* b_enc = (const float*)d_in[4];
  const float* cb    = (const float*)d_in[5];
  const float* W_dec = (const float*)d_in[6];
  const float* b_dec = (const float*)d_in[7];
  const float* W_out = (const float*)d_in[8];
  const float* b_out = (const float*)d_in[9];

  float* out = (float*)d_out;
  float* o_ids   = out;
  float* o_zq    = out + 8192;
  float* o_recon = out + 8192 + (size_t)N_ROWS * DIM;
  float* o_scal  = out + 8192 + (size_t)N_ROWS * DIM + (size_t)N_ROWS * IN_DIM;

  // ws layout (float offsets)
  float*  ws    = (float*)d_ws;
  float*  W_dc  = ws;                          // 2,097,152
  float*  z2    = ws + 2097152;                // 8192
  float*  c2    = ws + 2105344;                // 8192
  int*    ids   = (int*)(ws + 2113536);        // 8192
  float*  b_dc  = ws + 2121728;                // 2048
  float*  ep    = ws + 2123776;                // 4096
  float*  rp    = ws + 2127872;                // 8192

  // o_recon region (8192x2048 f32 = 64 MB) doubles as scratch:
  //   t (f32 8192x1024) first half -> dead after z; screen records (16 MB)
  //   reuse t's region. z in second half, live until ep. recon overwrites all.
  float* t    = o_recon;
  float* z    = o_recon + (size_t)N_ROWS * DIM;
  uint4* recs = (uint4*)o_recon;

  // decoder fusion (2%-threshold outputs)
  rowdot_bias_kernel<<<IN_DIM, 256, 0, stream>>>(W_out, b_dec, b_out, b_dc);
  gemm128<false><<<dim3(DIM / 128, IN_DIM / 128), 256, 0, stream>>>(
      W_out, W_dec, nullptr, W_dc, IN_DIM, DIM, DIM);

  // ---- np-f32 emulated encoder (bit-exact chains) ----
  emul_gemm_kernel<<<dim3(DIM / 128, N_ROWS / 128), 256, 0, stream>>>(
      roi, W_in, b_in, t, DIM, IN_DIM, IN_DIM, IN_DIM, PANEL_MASK_K2048_C32);
  emul_gemm_kernel<<<dim3(DIM / 128, N_ROWS / 128), 256, 0, stream>>>(
      t, W_enc, b_enc, z, DIM, DIM, DIM, DIM, PANEL_MASK_K1024_C32);

  // ---- np pairwise row sums of squares ----
  sumsq1024_kernel<<<N_ROWS / 4, 256, 0, stream>>>(z, z2);
  sumsq1024_kernel<<<CBK / 4, 256, 0, stream>>>(cb, c2);

  // ---- certified MFMA screen (t region now dead -> records) ----
  mfma_screen_kernel<<<dim3(CBK / 128, N_ROWS / 128), 256, 0, stream>>>(
      z, cb, z2, c2, recs);
  // ---- exact rescore of certified candidates ----
  collect_rescore_kernel<<<N_ROWS, 256, 0, stream>>>(
      recs, z, cb, z2, c2, ids, o_ids);

  // ---- outputs ----
  gather_zq_kernel<<<N_ROWS, 256, 0, stream>>>(cb, ids, o_zq);
  sqdiff_partial_kernel<<<(N_ROWS * DIM) / 2048, 256, 0, stream>>>(o_zq, z, ep);

  // recon via bf16 MFMA (overwrites records/z region AFTER ep consumed z)
  mfma_recon_kernel<<<dim3(IN_DIM / 128, N_ROWS / 128), 256, 0, stream>>>(
      o_zq, W_dc, b_dc, o_recon);

  sqdiff_partial_kernel<<<(N_ROWS * IN_DIM) / 2048, 256, 0, stream>>>(
      o_recon, roi, rp);
  final_losses_kernel<<<1, 256, 0, stream>>>(rp, ep, o_scal);
}

// Round 14
// 1485.930 us; speedup vs baseline: 3.4160x; 1.0343x over previous
//
#include <hip/hip_runtime.h>
#include <float.h>

// ---------------------------------------------------------------------------
// VQ-VAE quantizer forward — round 14: round-13 pipeline (PASSED, 1537 us)
// with the MFMA screen de-VALU-ified:
//  * Z's bf16x2 split precomputed once (zsplit_kernel, packed u32) into the
//    dead t-region; screen unpacks with bit-ops (2/elem vs 8-op FP split).
//  * CB split inline via truncation (mask+sub+mask); error still << DELTA.
//  * LDS rows widened to 128B (hi|lo halves) with XOR (r&7)<<4 -> 2-way reads.
// ids semantics unchanged: certified screen (DELTA=1.2e-3) + exact
// sequential-k chain rescore (panel joins k=384,704) = np.argmin first-index.
// ---------------------------------------------------------------------------

#define N_ROWS 8192
#define IN_DIM 2048
#define DIM 1024
#define CBK 8192

#define PANEL_MASK_K1024_C32 0x0000000000401000ULL  // joins k=384,704
#define PANEL_MASK_K2048_C32 0x0101001001001000ULL  // k=384,768,1152,1536,1792

#define SCREEN_DELTA 1.2e-3f

typedef __attribute__((ext_vector_type(8))) short short8;
typedef __attribute__((ext_vector_type(8))) unsigned short ushort8;
typedef __attribute__((ext_vector_type(4))) float f32x4;

__device__ __forceinline__ float sqf(float v) { return __builtin_fmaf(v, v, 0.0f); }

__device__ __forceinline__ unsigned short f2bf(float f) {  // RNE f32->bf16
  unsigned int u = __float_as_uint(f);
  u += 0x7fffu + ((u >> 16) & 1u);
  return (unsigned short)(u >> 16);
}

__device__ __forceinline__ int swz128(int c) {
  return (c & 3) | (((c >> 3) & 7) << 2) | (((c >> 2) & 1) << 5) | ((c >> 6) << 6);
}

__device__ __forceinline__ float block_reduce_sum(float v) {
  __shared__ float sh[4];
  #pragma unroll
  for (int off = 32; off > 0; off >>= 1) v += __shfl_down(v, off, 64);
  const int lane = threadIdx.x & 63, w = threadIdx.x >> 6;
  if (lane == 0) sh[w] = v;
  __syncthreads();
  float r = 0.f;
  if (threadIdx.x == 0) r = sh[0] + sh[1] + sh[2] + sh[3];
  return r;  // valid on thread 0 only
}

// exact emulated-f32 distance: sequential-k chain, panel joins at 384/704.
__device__ __forceinline__ float chain_d(const float* __restrict__ zsh,
                                         const float* __restrict__ cbr,
                                         float z2r, float c2e) {
  float part = 0.f;
  for (int k = 0; k < 384; ++k) part = __builtin_fmaf(zsh[k], cbr[k], part);
  float total = part;
  part = 0.f;
  for (int k = 384; k < 704; ++k) part = __builtin_fmaf(zsh[k], cbr[k], part);
  total = total + part;
  part = 0.f;
  for (int k = 704; k < 1024; ++k) part = __builtin_fmaf(zsh[k], cbr[k], part);
  total = total + part;
  return __builtin_fmaf(-2.0f, total, z2r) + c2e;
}

// ---------------------------------------------------------------------------
// fp32 128x128x16 tiled GEMM (W_dc fusion only). Double-buffered. (r10 PASSED)
// ---------------------------------------------------------------------------
template <bool BT>
__global__ __launch_bounds__(256) void gemm128(
    const float* __restrict__ A, const float* __restrict__ B,
    const float* __restrict__ bias, float* __restrict__ C,
    int M, int N, int K) {
  __shared__ float As[2][16][132];
  __shared__ float Bs[2][16][132];
  const int tid = threadIdx.x;
  const int tx = tid & 15, ty = tid >> 4;
  const int bm = blockIdx.y, bn = blockIdx.x;

  const int mload = tid & 127, kh = tid >> 7;
  const size_t arow = (size_t)(bm * 128 + mload) * (size_t)K;
  const size_t brow = BT ? (size_t)(bn * 128 + mload) * (size_t)K : 0;
  const int swn = swz128(mload);
  const int c4 = (tid & 31) << 2;
  const int kr = tid >> 5;
  const int swc = swz128(c4);

  float acc[8][8];
  #pragma unroll
  for (int r = 0; r < 8; ++r)
    #pragma unroll
    for (int c = 0; c < 8; ++c) acc[r][c] = 0.f;

  const int boff = ((tx & 7) << 2) | ((tx >> 3) << 6);

  float4 av0, av1, bv0, bv1;
  av0 = *(const float4*)&A[arow + kh * 8];
  av1 = *(const float4*)&A[arow + kh * 8 + 4];
  if (BT) {
    bv0 = *(const float4*)&B[brow + kh * 8];
    bv1 = *(const float4*)&B[brow + kh * 8 + 4];
  } else {
    bv0 = *(const float4*)&B[(size_t)kr * N + bn * 128 + c4];
    bv1 = *(const float4*)&B[(size_t)(kr + 8) * N + bn * 128 + c4];
  }
  As[0][kh * 8 + 0][mload] = av0.x; As[0][kh * 8 + 1][mload] = av0.y;
  As[0][kh * 8 + 2][mload] = av0.z; As[0][kh * 8 + 3][mload] = av0.w;
  As[0][kh * 8 + 4][mload] = av1.x; As[0][kh * 8 + 5][mload] = av1.y;
  As[0][kh * 8 + 6][mload] = av1.z; As[0][kh * 8 + 7][mload] = av1.w;
  if (BT) {
    Bs[0][kh * 8 + 0][swn] = bv0.x; Bs[0][kh * 8 + 1][swn] = bv0.y;
    Bs[0][kh * 8 + 2][swn] = bv0.z; Bs[0][kh * 8 + 3][swn] = bv0.w;
    Bs[0][kh * 8 + 4][swn] = bv1.x; Bs[0][kh * 8 + 5][swn] = bv1.y;
    Bs[0][kh * 8 + 6][swn] = bv1.z; Bs[0][kh * 8 + 7][swn] = bv1.w;
  } else {
    *(float4*)&Bs[0][kr][swc] = bv0;
    *(float4*)&Bs[0][kr + 8][swc] = bv1;
  }
  const int nk = K >> 4;
  if (nk > 1) {
    av0 = *(const float4*)&A[arow + 16 + kh * 8];
    av1 = *(const float4*)&A[arow + 16 + kh * 8 + 4];
    if (BT) {
      bv0 = *(const float4*)&B[brow + 16 + kh * 8];
      bv1 = *(const float4*)&B[brow + 16 + kh * 8 + 4];
    } else {
      bv0 = *(const float4*)&B[(size_t)(16 + kr) * N + bn * 128 + c4];
      bv1 = *(const float4*)&B[(size_t)(16 + kr + 8) * N + bn * 128 + c4];
    }
  }
  __syncthreads();

  for (int ki = 0; ki < nk; ++ki) {
    const int p = ki & 1;
    if (ki + 1 < nk) {
      As[p ^ 1][kh * 8 + 0][mload] = av0.x; As[p ^ 1][kh * 8 + 1][mload] = av0.y;
      As[p ^ 1][kh * 8 + 2][mload] = av0.z; As[p ^ 1][kh * 8 + 3][mload] = av0.w;
      As[p ^ 1][kh * 8 + 4][mload] = av1.x; As[p ^ 1][kh * 8 + 5][mload] = av1.y;
      As[p ^ 1][kh * 8 + 6][mload] = av1.z; As[p ^ 1][kh * 8 + 7][mload] = av1.w;
      if (BT) {
        Bs[p ^ 1][kh * 8 + 0][swn] = bv0.x; Bs[p ^ 1][kh * 8 + 1][swn] = bv0.y;
        Bs[p ^ 1][kh * 8 + 2][swn] = bv0.z; Bs[p ^ 1][kh * 8 + 3][swn] = bv0.w;
        Bs[p ^ 1][kh * 8 + 4][swn] = bv1.x; Bs[p ^ 1][kh * 8 + 5][swn] = bv1.y;
        Bs[p ^ 1][kh * 8 + 6][swn] = bv1.z; Bs[p ^ 1][kh * 8 + 7][swn] = bv1.w;
      } else {
        *(float4*)&Bs[p ^ 1][kr][swc] = bv0;
        *(float4*)&Bs[p ^ 1][kr + 8][swc] = bv1;
      }
      if (ki + 2 < nk) {
        const int k2 = (ki + 2) << 4;
        av0 = *(const float4*)&A[arow + k2 + kh * 8];
        av1 = *(const float4*)&A[arow + k2 + kh * 8 + 4];
        if (BT) {
          bv0 = *(const float4*)&B[brow + k2 + kh * 8];
          bv1 = *(const float4*)&B[brow + k2 + kh * 8 + 4];
        } else {
          bv0 = *(const float4*)&B[(size_t)(k2 + kr) * N + bn * 128 + c4];
          bv1 = *(const float4*)&B[(size_t)(k2 + kr + 8) * N + bn * 128 + c4];
        }
      }
    }
    #pragma unroll
    for (int kk = 0; kk < 16; ++kk) {
      const float4 a0 = *(const float4*)&As[p][kk][ty * 8];
      const float4 a1 = *(const float4*)&As[p][kk][ty * 8 + 4];
      const float4 b0 = *(const float4*)&Bs[p][kk][boff];
      const float4 b1 = *(const float4*)&Bs[p][kk][boff + 32];
      const float ar[8] = {a0.x, a0.y, a0.z, a0.w, a1.x, a1.y, a1.z, a1.w};
      const float br[8] = {b0.x, b0.y, b0.z, b0.w, b1.x, b1.y, b1.z, b1.w};
      #pragma unroll
      for (int r = 0; r < 8; ++r)
        #pragma unroll
        for (int c = 0; c < 8; ++c) acc[r][c] = fmaf(ar[r], br[c], acc[r][c]);
    }
    __syncthreads();
  }

  const int gcol = bn * 128 + tx * 8;
  float bb[8] = {0, 0, 0, 0, 0, 0, 0, 0};
  if (bias) {
    const float4 v0 = *(const float4*)&bias[gcol];
    const float4 v1 = *(const float4*)&bias[gcol + 4];
    bb[0] = v0.x; bb[1] = v0.y; bb[2] = v0.z; bb[3] = v0.w;
    bb[4] = v1.x; bb[5] = v1.y; bb[6] = v1.z; bb[7] = v1.w;
  }
  #pragma unroll
  for (int r = 0; r < 8; ++r) {
    float* cp = &C[(size_t)(bm * 128 + ty * 8 + r) * N + gcol];
    float4 o0, o1;
    o0.x = acc[r][0] + bb[0]; o0.y = acc[r][1] + bb[1];
    o0.z = acc[r][2] + bb[2]; o0.w = acc[r][3] + bb[3];
    o1.x = acc[r][4] + bb[4]; o1.y = acc[r][5] + bb[5];
    o1.z = acc[r][6] + bb[6]; o1.w = acc[r][7] + bb[7];
    *(float4*)cp = o0;
    *(float4*)(cp + 4) = o1;
  }
}

// ---------------------------------------------------------------------------
// OpenBLAS-emulating GEMM (bit-exact chains), 128x128 / 8x8, dbuf (r11 PASSED)
// ---------------------------------------------------------------------------
__global__ __launch_bounds__(256) void emul_gemm_kernel(
    const float* __restrict__ A, const float* __restrict__ B,
    const float* __restrict__ bias, float* __restrict__ C,
    int N, int K, int lda, int ldb, unsigned long long panel_mask) {
  __shared__ float As_[2][32][128];
  __shared__ float Bs_[2][32][128];
  const int tid = threadIdx.x;
  const int tx = tid & 15, ty = tid >> 4;
  const int row0 = blockIdx.y * 128, col0 = blockIdx.x * 128;
  const int sr = tid & 127, sh = tid >> 7;
  const int scol = (((sr >> 2) & 1) << 6) + ((sr >> 3) << 2) + (sr & 3);

  float part[8][8], total[8][8];
  #pragma unroll
  for (int r = 0; r < 8; ++r)
    #pragma unroll
    for (int e = 0; e < 8; ++e) { part[r][e] = 0.f; total[r][e] = 0.f; }

  float4 av[4], bv[4];
  #pragma unroll
  for (int q = 0; q < 4; ++q) {
    av[q] = *(const float4*)&A[(size_t)(row0 + sr) * lda + sh * 16 + q * 4];
    bv[q] = *(const float4*)&B[(size_t)(col0 + sr) * ldb + sh * 16 + q * 4];
  }
  #pragma unroll
  for (int q = 0; q < 4; ++q) {
    As_[0][sh * 16 + q * 4 + 0][sr] = av[q].x;
    As_[0][sh * 16 + q * 4 + 1][sr] = av[q].y;
    As_[0][sh * 16 + q * 4 + 2][sr] = av[q].z;
    As_[0][sh * 16 + q * 4 + 3][sr] = av[q].w;
    Bs_[0][sh * 16 + q * 4 + 0][scol] = bv[q].x;
    Bs_[0][sh * 16 + q * 4 + 1][scol] = bv[q].y;
    Bs_[0][sh * 16 + q * 4 + 2][scol] = bv[q].z;
    Bs_[0][sh * 16 + q * 4 + 3][scol] = bv[q].w;
  }
  const int nch = K >> 5;
  if (nch > 1) {
    #pragma unroll
    for (int q = 0; q < 4; ++q) {
      av[q] = *(const float4*)&A[(size_t)(row0 + sr) * lda + 32 + sh * 16 + q * 4];
      bv[q] = *(const float4*)&B[(size_t)(col0 + sr) * ldb + 32 + sh * 16 + q * 4];
    }
  }
  __syncthreads();

  for (int ci = 0; ci < nch; ++ci) {
    const int p = ci & 1;
    if (ci + 1 < nch) {
      #pragma unroll
      for (int q = 0; q < 4; ++q) {
        As_[p ^ 1][sh * 16 + q * 4 + 0][sr] = av[q].x;
        As_[p ^ 1][sh * 16 + q * 4 + 1][sr] = av[q].y;
        As_[p ^ 1][sh * 16 + q * 4 + 2][sr] = av[q].z;
        As_[p ^ 1][sh * 16 + q * 4 + 3][sr] = av[q].w;
        Bs_[p ^ 1][sh * 16 + q * 4 + 0][scol] = bv[q].x;
        Bs_[p ^ 1][sh * 16 + q * 4 + 1][scol] = bv[q].y;
        Bs_[p ^ 1][sh * 16 + q * 4 + 2][scol] = bv[q].z;
        Bs_[p ^ 1][sh * 16 + q * 4 + 3][scol] = bv[q].w;
      }
      if (ci + 2 < nch) {
        const int k2 = (ci + 2) << 5;
        #pragma unroll
        for (int q = 0; q < 4; ++q) {
          av[q] = *(const float4*)&A[(size_t)(row0 + sr) * lda + k2 + sh * 16 + q * 4];
          bv[q] = *(const float4*)&B[(size_t)(col0 + sr) * ldb + k2 + sh * 16 + q * 4];
        }
      }
    }
    if (ci && ((panel_mask >> ci) & 1ULL)) {
      #pragma unroll
      for (int r = 0; r < 8; ++r)
        #pragma unroll
        for (int e = 0; e < 8; ++e) { total[r][e] = total[r][e] + part[r][e]; part[r][e] = 0.f; }
    }
    #pragma unroll 4
    for (int kk = 0; kk < 32; ++kk) {
      const float4 za = *(const float4*)&As_[p][kk][ty * 8];
      const float4 zb = *(const float4*)&As_[p][kk][ty * 8 + 4];
      const float4 ca = *(const float4*)&Bs_[p][kk][tx * 4];
      const float4 cb4 = *(const float4*)&Bs_[p][kk][64 + tx * 4];
      const float zr[8] = {za.x, za.y, za.z, za.w, zb.x, zb.y, zb.z, zb.w};
      const float cr[8] = {ca.x, ca.y, ca.z, ca.w, cb4.x, cb4.y, cb4.z, cb4.w};
      #pragma unroll
      for (int r = 0; r < 8; ++r)
        #pragma unroll
        for (int e = 0; e < 8; ++e)
          part[r][e] = __builtin_fmaf(zr[r], cr[e], part[r][e]);
    }
    __syncthreads();
  }
  #pragma unroll
  for (int r = 0; r < 8; ++r)
    #pragma unroll
    for (int e = 0; e < 8; ++e) total[r][e] = total[r][e] + part[r][e];

  const float4 ba = *(const float4*)&bias[col0 + tx * 8];
  const float4 bb = *(const float4*)&bias[col0 + tx * 8 + 4];
  const float br8[8] = {ba.x, ba.y, ba.z, ba.w, bb.x, bb.y, bb.z, bb.w};
  #pragma unroll
  for (int r = 0; r < 8; ++r) {
    float* cp = &C[(size_t)(row0 + ty * 8 + r) * N + col0 + tx * 8];
    float4 o0, o1;
    o0.x = total[r][0] + br8[0]; o0.y = total[r][1] + br8[1];
    o0.z = total[r][2] + br8[2]; o0.w = total[r][3] + br8[3];
    o1.x = total[r][4] + br8[4]; o1.y = total[r][5] + br8[5];
    o1.z = total[r][6] + br8[6]; o1.w = total[r][7] + br8[7];
    *(float4*)cp = o0;
    *(float4*)(cp + 4) = o1;
  }
}

// ---------------------------------------------------------------------------
// Z bf16x2 truncation split, packed hi | lo<<16 per element.
// hi = trunc_bf16(x); rem = x - hi (exact); lo = trunc_bf16(rem).
// ---------------------------------------------------------------------------
__global__ __launch_bounds__(256) void zsplit_kernel(
    const float* __restrict__ Z, unsigned* __restrict__ ZP) {
  const size_t base = (size_t)blockIdx.x * 1024 + threadIdx.x * 4;
  const float4 v = *(const float4*)&Z[base];
  const float xf[4] = {v.x, v.y, v.z, v.w};
  uint4 o;
  unsigned ov[4];
  #pragma unroll
  for (int i = 0; i < 4; ++i) {
    const unsigned u = __float_as_uint(xf[i]);
    const unsigned hb = u & 0xFFFF0000u;
    const float rem = xf[i] - __uint_as_float(hb);
    ov[i] = (u >> 16) | (__float_as_uint(rem) & 0xFFFF0000u);
  }
  o.x = ov[0]; o.y = ov[1]; o.z = ov[2]; o.w = ov[3];
  *(uint4*)&ZP[base] = o;
}

// ---------------------------------------------------------------------------
// bf16x2 MFMA distance screen v2. Block = 128 rows x 128 entries, 4 waves,
// K-stage 32. LDS rows 128B: hi k0..31 in bytes 0..63, lo in 64..127,
// XOR swizzle (r&7)<<4 -> 2-way frag reads. Z pre-split (packed u32);
// CB truncation-split inline. Emits {min d~, cnt, <=12 idx} per (row,chunk).
// ---------------------------------------------------------------------------
__global__ __launch_bounds__(256) void mfma_screen_kernel(
    const unsigned* __restrict__ ZP, const float* __restrict__ CB,
    const float* __restrict__ Z2, const float* __restrict__ C2,
    uint4* __restrict__ recs) {
  __shared__ unsigned short Zs[128 * 64];  // 16 KB, 128B per row
  __shared__ unsigned short Cs[128 * 64];  // 16 KB
  __shared__ int rowminI[128];
  __shared__ int cnt[128];
  __shared__ unsigned short cand[128][12];
  const int tid = threadIdx.x;
  const int wid = tid >> 6, lane = tid & 63;
  const int e0 = blockIdx.x * 128, row0 = blockIdx.y * 128;
  const int wr = (wid >> 1) * 64, wc = (wid & 1) * 64;

  if (tid < 128) { rowminI[tid] = 0x7F800000; cnt[tid] = 0; }

  f32x4 acc[4][4];
  #pragma unroll
  for (int m = 0; m < 4; ++m)
    #pragma unroll
    for (int n = 0; n < 4; ++n)
      #pragma unroll
      for (int j = 0; j < 4; ++j) acc[m][n][j] = 0.f;

  const int stg_r = tid >> 3, stg_kg = (tid & 7) * 4;  // 4 elems per thread-pass

  for (int k0 = 0; k0 < 1024; k0 += 32) {
    __syncthreads();
    #pragma unroll
    for (int s = 0; s < 4; ++s) {
      const int r = stg_r + s * 32;  // 0..127 across 4 passes
      const int swz = (r & 7) << 4;
      const int bhi = (r * 128 + stg_kg * 2) ^ swz;
      const int blo = (r * 128 + 64 + stg_kg * 2) ^ swz;
      // Z: load packed, unpack with bit ops
      const uint4 p = *(const uint4*)&ZP[(size_t)(row0 + r) * 1024 + k0 + stg_kg];
      uint2 zh, zl;
      zh.x = (p.x & 0xFFFFu) | (p.y << 16);
      zh.y = (p.z & 0xFFFFu) | (p.w << 16);
      zl.x = (p.x >> 16) | (p.y & 0xFFFF0000u);
      zl.y = (p.z >> 16) | (p.w & 0xFFFF0000u);
      *(uint2*)((char*)Zs + bhi) = zh;
      *(uint2*)((char*)Zs + blo) = zl;
      // CB: truncation split inline
      const float4 cv = *(const float4*)&CB[(size_t)(e0 + r) * 1024 + k0 + stg_kg];
      const float cf[4] = {cv.x, cv.y, cv.z, cv.w};
      unsigned ch[4], cl[4];
      #pragma unroll
      for (int i = 0; i < 4; ++i) {
        const unsigned u = __float_as_uint(cf[i]);
        ch[i] = u & 0xFFFF0000u;
        const float rem = cf[i] - __uint_as_float(ch[i]);
        cl[i] = __float_as_uint(rem) & 0xFFFF0000u;
      }
      uint2 cph, cpl;
      cph.x = (ch[0] >> 16) | ch[1];
      cph.y = (ch[2] >> 16) | ch[3];
      cpl.x = (cl[0] >> 16) | cl[1];
      cpl.y = (cl[2] >> 16) | cl[3];
      *(uint2*)((char*)Cs + bhi) = cph;
      *(uint2*)((char*)Cs + blo) = cpl;
    }
    __syncthreads();
    const int kb2 = 16 * (lane >> 4);  // byte offset of k-slice within hi area
    short8 ah[4], al[4], bh[4], bl[4];
    #pragma unroll
    for (int m = 0; m < 4; ++m) {
      const int r = wr + m * 16 + (lane & 15);
      const int swz = (r & 7) << 4;
      ah[m] = *(const short8*)((const char*)Zs + ((r * 128 + kb2) ^ swz));
      al[m] = *(const short8*)((const char*)Zs + ((r * 128 + 64 + kb2) ^ swz));
    }
    #pragma unroll
    for (int n = 0; n < 4; ++n) {
      const int r = wc + n * 16 + (lane & 15);
      const int swz = (r & 7) << 4;
      bh[n] = *(const short8*)((const char*)Cs + ((r * 128 + kb2) ^ swz));
      bl[n] = *(const short8*)((const char*)Cs + ((r * 128 + 64 + kb2) ^ swz));
    }
    #pragma unroll
    for (int m = 0; m < 4; ++m)
      #pragma unroll
      for (int n = 0; n < 4; ++n) {
        acc[m][n] = __builtin_amdgcn_mfma_f32_16x16x32_bf16(ah[m], bh[n], acc[m][n], 0, 0, 0);
        acc[m][n] = __builtin_amdgcn_mfma_f32_16x16x32_bf16(ah[m], bl[n], acc[m][n], 0, 0, 0);
        acc[m][n] = __builtin_amdgcn_mfma_f32_16x16x32_bf16(al[m], bh[n], acc[m][n], 0, 0, 0);
      }
  }

  // epilogue: d~ values + per-row min + candidate extraction
  float dv[4][4][4];
  #pragma unroll
  for (int m = 0; m < 4; ++m)
    #pragma unroll
    for (int j = 0; j < 4; ++j) {
      const int rg = row0 + wr + m * 16 + (lane >> 4) * 4 + j;
      const float z2r = Z2[rg];
      float lm = FLT_MAX;
      #pragma unroll
      for (int n = 0; n < 4; ++n) {
        const float d = __builtin_fmaf(-2.0f, acc[m][n][j], z2r) +
                        C2[e0 + wc + n * 16 + (lane & 15)];
        dv[m][n][j] = d;
        lm = fminf(lm, d);
      }
      atomicMin(&rowminI[wr + m * 16 + (lane >> 4) * 4 + j], __float_as_int(lm));
    }
  __syncthreads();
  #pragma unroll
  for (int m = 0; m < 4; ++m)
    #pragma unroll
    for (int j = 0; j < 4; ++j) {
      const int rl = wr + m * 16 + (lane >> 4) * 4 + j;
      const float thr = __int_as_float(rowminI[rl]) + SCREEN_DELTA;
      #pragma unroll
      for (int n = 0; n < 4; ++n) {
        if (dv[m][n][j] <= thr) {
          const int pos = atomicAdd(&cnt[rl], 1);
          if (pos < 12)
            cand[rl][pos] = (unsigned short)(e0 + wc + n * 16 + (lane & 15));
        }
      }
    }
  __syncthreads();
  if (tid < 128) {
    uint4 a, b;
    a.x = (unsigned)rowminI[tid];
    a.y = (unsigned)cnt[tid];
    a.z = (unsigned)cand[tid][0] | ((unsigned)cand[tid][1] << 16);
    a.w = (unsigned)cand[tid][2] | ((unsigned)cand[tid][3] << 16);
    b.x = (unsigned)cand[tid][4] | ((unsigned)cand[tid][5] << 16);
    b.y = (unsigned)cand[tid][6] | ((unsigned)cand[tid][7] << 16);
    b.z = (unsigned)cand[tid][8] | ((unsigned)cand[tid][9] << 16);
    b.w = (unsigned)cand[tid][10] | ((unsigned)cand[tid][11] << 16);
    const size_t base = ((size_t)(row0 + tid) * 64 + blockIdx.x) * 2;
    recs[base] = a;
    recs[base + 1] = b;
  }
}

// ---------------------------------------------------------------------------
// Collect + exact rescore (r13 PASSED, unchanged).
// ---------------------------------------------------------------------------
__global__ __launch_bounds__(256) void collect_rescore_kernel(
    const uint4* __restrict__ recs, const float* __restrict__ Z,
    const float* __restrict__ CB, const float* __restrict__ Z2,
    const float* __restrict__ C2, int* __restrict__ ids,
    float* __restrict__ o_ids) {
  __shared__ float zsh[1024];
  __shared__ float gmin_sh;
  __shared__ int lcnt, ovf;
  __shared__ unsigned short list[64];
  __shared__ unsigned long long kred[4];
  const int row = blockIdx.x, tid = threadIdx.x;
  if (tid == 0) { lcnt = 0; ovf = 0; }
  uint4 r0 = make_uint4(0, 0, 0, 0), r1 = make_uint4(0, 0, 0, 0);
  float mymin = FLT_MAX;
  if (tid < 64) {
    const size_t base = ((size_t)row * 64 + tid) * 2;
    r0 = recs[base];
    r1 = recs[base + 1];
    mymin = __uint_as_float(r0.x);
  }
  for (int i = tid; i < 1024; i += 256) zsh[i] = Z[(size_t)row * 1024 + i];
  if (tid < 64) {
    float m = mymin;
    #pragma unroll
    for (int off = 32; off > 0; off >>= 1) m = fminf(m, __shfl_down(m, off, 64));
    if (tid == 0) gmin_sh = m;
  }
  __syncthreads();
  const float thr = gmin_sh + SCREEN_DELTA;
  if (tid < 64 && mymin <= thr) {
    const int c = (int)r0.y;
    if (c > 12) {
      atomicOr(&ovf, 1);
    } else {
      unsigned short idxs[12];
      idxs[0] = r0.z & 0xFFFF; idxs[1] = r0.z >> 16;
      idxs[2] = r0.w & 0xFFFF; idxs[3] = r0.w >> 16;
      idxs[4] = r1.x & 0xFFFF; idxs[5] = r1.x >> 16;
      idxs[6] = r1.y & 0xFFFF; idxs[7] = r1.y >> 16;
      idxs[8] = r1.z & 0xFFFF; idxs[9] = r1.z >> 16;
      idxs[10] = r1.w & 0xFFFF; idxs[11] = r1.w >> 16;
      for (int i = 0; i < c; ++i) {
        const int pos = atomicAdd(&lcnt, 1);
        if (pos < 64) list[pos] = idxs[i];
        else atomicOr(&ovf, 1);
      }
    }
  }
  __syncthreads();
  const float z2r = Z2[row];
  unsigned long long key = ~0ULL;
  if (ovf) {  // rare: exact full-row scan
    for (int e = tid; e < CBK; e += 256) {
      const float d = chain_d(zsh, &CB[(size_t)e * 1024], z2r, C2[e]);
      const unsigned long long k =
          ((unsigned long long)__float_as_uint(d) << 32) | (unsigned)e;
      key = (k < key) ? k : key;
    }
  } else {
    const int n = lcnt < 64 ? lcnt : 64;
    if (tid < n) {
      const int e = list[tid];
      const float d = chain_d(zsh, &CB[(size_t)e * 1024], z2r, C2[e]);
      key = ((unsigned long long)__float_as_uint(d) << 32) | (unsigned)e;
    }
  }
  #pragma unroll
  for (int off = 32; off > 0; off >>= 1) {
    const unsigned long long o = __shfl_down(key, off, 64);
    key = (o < key) ? o : key;
  }
  if ((tid & 63) == 0) kred[tid >> 6] = key;
  __syncthreads();
  if (tid == 0) {
    unsigned long long k = kred[0];
    k = (kred[1] < k) ? kred[1] : k;
    k = (kred[2] < k) ? kred[2] : k;
    k = (kred[3] < k) ? kred[3] : k;
    const int e = (int)(k & 0xFFFFFFFFu);
    ids[row] = e;
    o_ids[row] = (float)e;
  }
}

// ---------------------------------------------------------------------------
// bf16 MFMA recon (r11 PASSED, unchanged).
// ---------------------------------------------------------------------------
__global__ __launch_bounds__(256) void mfma_recon_kernel(
    const float* __restrict__ A, const float* __restrict__ B,
    const float* __restrict__ bias, float* __restrict__ C) {
  __shared__ unsigned short Abf[128 * 64];
  __shared__ unsigned short Bbf[128 * 64];
  const int tid = threadIdx.x;
  const int wid = tid >> 6, lane = tid & 63;
  const int row0 = blockIdx.y * 128, col0 = blockIdx.x * 128;
  const int wr = (wid >> 1) * 64, wc = (wid & 1) * 64;

  f32x4 acc[4][4];
  #pragma unroll
  for (int m = 0; m < 4; ++m)
    #pragma unroll
    for (int n = 0; n < 4; ++n)
      #pragma unroll
      for (int j = 0; j < 4; ++j) acc[m][n][j] = 0.f;

  for (int k0 = 0; k0 < 1024; k0 += 64) {
    __syncthreads();
    #pragma unroll
    for (int q = 0; q < 4; ++q) {
      const int g = tid + q * 256;
      const int r = g >> 3;
      const int kg = (g & 7) * 8;
      const float4 a0 = *(const float4*)&A[(size_t)(row0 + r) * 1024 + k0 + kg];
      const float4 a1 = *(const float4*)&A[(size_t)(row0 + r) * 1024 + k0 + kg + 4];
      const float4 b0 = *(const float4*)&B[(size_t)(col0 + r) * 1024 + k0 + kg];
      const float4 b1 = *(const float4*)&B[(size_t)(col0 + r) * 1024 + k0 + kg + 4];
      ushort8 pa, pb;
      pa[0] = f2bf(a0.x); pa[1] = f2bf(a0.y); pa[2] = f2bf(a0.z); pa[3] = f2bf(a0.w);
      pa[4] = f2bf(a1.x); pa[5] = f2bf(a1.y); pa[6] = f2bf(a1.z); pa[7] = f2bf(a1.w);
      pb[0] = f2bf(b0.x); pb[1] = f2bf(b0.y); pb[2] = f2bf(b0.z); pb[3] = f2bf(b0.w);
      pb[4] = f2bf(b1.x); pb[5] = f2bf(b1.y); pb[6] = f2bf(b1.z); pb[7] = f2bf(b1.w);
      const int byte = (r * 128 + kg * 2) ^ ((r & 7) << 4);
      *(ushort8*)((char*)Abf + byte) = pa;
      *(ushort8*)((char*)Bbf + byte) = pb;
    }
    __syncthreads();
    #pragma unroll
    for (int kh = 0; kh < 2; ++kh) {
      const int kb = kh * 32 + 8 * (lane >> 4);
      short8 afr[4], bfr[4];
      #pragma unroll
      for (int m = 0; m < 4; ++m) {
        const int r = wr + m * 16 + (lane & 15);
        const int byte = (r * 128 + kb * 2) ^ ((r & 7) << 4);
        afr[m] = *(const short8*)((const char*)Abf + byte);
      }
      #pragma unroll
      for (int n = 0; n < 4; ++n) {
        const int r = wc + n * 16 + (lane & 15);
        const int byte = (r * 128 + kb * 2) ^ ((r & 7) << 4);
        bfr[n] = *(const short8*)((const char*)Bbf + byte);
      }
      #pragma unroll
      for (int m = 0; m < 4; ++m)
        #pragma unroll
        for (int n = 0; n < 4; ++n)
          acc[m][n] = __builtin_amdgcn_mfma_f32_16x16x32_bf16(
              afr[m], bfr[n], acc[m][n], 0, 0, 0);
    }
  }

  #pragma unroll
  for (int m = 0; m < 4; ++m)
    #pragma unroll
    for (int n = 0; n < 4; ++n) {
      const int col = col0 + wc + n * 16 + (lane & 15);
      const float bc = bias[col];
      #pragma unroll
      for (int j = 0; j < 4; ++j) {
        const int row = row0 + wr + m * 16 + (lane >> 4) * 4 + j;
        C[(size_t)row * 2048 + col] = acc[m][n][j] + bc;
      }
    }
}

// ---------------------------------------------------------------------------
// numpy pairwise_sum emulation of sum(x*x) over rows of 1024 (unchanged).
// ---------------------------------------------------------------------------
__global__ __launch_bounds__(256) void sumsq1024_kernel(
    const float* __restrict__ X, float* __restrict__ out) {
  __shared__ float rows[4][1024];
  __shared__ float leaves[4][8];
  const int tid = threadIdx.x;
  const int row0 = blockIdx.x * 4;
  for (int i = tid; i < 4096; i += 256)
    rows[i >> 10][i & 1023] = X[(size_t)row0 * 1024 + i];
  __syncthreads();
  if (tid < 32) {
    const int r = tid >> 3, lf = tid & 7;
    const float* a = &rows[r][lf * 128];
    float s0 = sqf(a[0]), s1 = sqf(a[1]), s2 = sqf(a[2]), s3 = sqf(a[3]);
    float s4 = sqf(a[4]), s5 = sqf(a[5]), s6 = sqf(a[6]), s7 = sqf(a[7]);
    for (int i = 8; i < 128; i += 8) {
      s0 = s0 + sqf(a[i + 0]); s1 = s1 + sqf(a[i + 1]);
      s2 = s2 + sqf(a[i + 2]); s3 = s3 + sqf(a[i + 3]);
      s4 = s4 + sqf(a[i + 4]); s5 = s5 + sqf(a[i + 5]);
      s6 = s6 + sqf(a[i + 6]); s7 = s7 + sqf(a[i + 7]);
    }
    leaves[r][lf] = ((s0 + s1) + (s2 + s3)) + ((s4 + s5) + (s6 + s7));
  }
  __syncthreads();
  if (tid < 4) {
    const float* L = leaves[tid];
    const float p01 = L[0] + L[1], p23 = L[2] + L[3];
    const float p45 = L[4] + L[5], p67 = L[6] + L[7];
    out[row0 + tid] = ((p01 + p23) + (p45 + p67));
  }
}

__global__ __launch_bounds__(256) void gather_zq_kernel(
    const float* __restrict__ cb, const int* __restrict__ ids,
    float* __restrict__ zq) {
  const int row = blockIdx.x;
  const int id = ids[row];
  const float4 v = *(const float4*)&cb[(size_t)id * DIM + threadIdx.x * 4];
  *(float4*)&zq[(size_t)row * DIM + threadIdx.x * 4] = v;
}

__global__ __launch_bounds__(256) void rowdot_bias_kernel(
    const float* __restrict__ W, const float* __restrict__ v,
    const float* __restrict__ b2, float* __restrict__ out) {
  const int row = blockIdx.x;
  const float4 w4 = *(const float4*)&W[(size_t)row * 1024 + threadIdx.x * 4];
  const float4 v4 = *(const float4*)&v[threadIdx.x * 4];
  const float s = w4.x * v4.x + w4.y * v4.y + w4.z * v4.z + w4.w * v4.w;
  const float r = block_reduce_sum(s);
  if (threadIdx.x == 0) out[row] = r + b2[row];
}

__global__ __launch_bounds__(256) void sqdiff_partial_kernel(
    const float* __restrict__ a, const float* __restrict__ b,
    float* __restrict__ part) {
  const size_t base = (size_t)blockIdx.x * 2048 + (size_t)threadIdx.x * 8;
  const float4 x0 = *(const float4*)&a[base];
  const float4 x1 = *(const float4*)&a[base + 4];
  const float4 y0 = *(const float4*)&b[base];
  const float4 y1 = *(const float4*)&b[base + 4];
  float s = 0.f;
  float d;
  d = x0.x - y0.x; s += d * d; d = x0.y - y0.y; s += d * d;
  d = x0.z - y0.z; s += d * d; d = x0.w - y0.w; s += d * d;
  d = x1.x - y1.x; s += d * d; d = x1.y - y1.y; s += d * d;
  d = x1.z - y1.z; s += d * d; d = x1.w - y1.w; s += d * d;
  const float r = block_reduce_sum(s);
  if (threadIdx.x == 0) part[blockIdx.x] = r;
}

__global__ __launch_bounds__(256) void final_losses_kernel(
    const float* __restrict__ rp, const float* __restrict__ ep,
    float* __restrict__ o) {
  __shared__ double sh[4];
  const int lane = threadIdx.x & 63, w = threadIdx.x >> 6;
  double s = 0.0;
  for (int i = threadIdx.x; i < 8192; i += 256) s += (double)rp[i];
  #pragma unroll
  for (int off = 32; off > 0; off >>= 1) s += __shfl_down(s, off, 64);
  if (lane == 0) sh[w] = s;
  __syncthreads();
  double rl = 0.0;
  if (threadIdx.x == 0) rl = (sh[0] + sh[1] + sh[2] + sh[3]) / ((double)N_ROWS * IN_DIM);
  __syncthreads();
  double s2 = 0.0;
  for (int i = threadIdx.x; i < 4096; i += 256) s2 += (double)ep[i];
  #pragma unroll
  for (int off = 32; off > 0; off >>= 1) s2 += __shfl_down(s2, off, 64);
  if (lane == 0) sh[w] = s2;
  __syncthreads();
  if (threadIdx.x == 0) {
    const double el = (sh[0] + sh[1] + sh[2] + sh[3]) / ((double)N_ROWS * DIM);
    o[0] = (float)(rl + el + 0.25 * el);
    o[1] = (float)rl;
    o[2] = (float)el;
    o[3] = (float)el;
  }
}

extern "C" void kernel_launch(void* const* d_in, const int* in_sizes, int n_in,
                              void* d_out, int out_size, void* d_ws, size_t ws_size,
                              hipStream_t stream) {
  const float* roi   = (const float*)d_in[0];
  const float* W_in  = (const float*)d_in[1];
  const float* b_in  = (const float*)d_in[2];
  const float* W_enc = (const float*)d_in[3];
  const float* b_enc = (const float*)d_in[4];
  const float* cb    = (const float*)d_in[5];
  const float* W_dec = (const float*)d_in[6];
  const float* b_dec = (const float*)d_in[7];
  const float* W_out = (const float*)d_in[8];
  const float* b_out = (const float*)d_in[9];

  float* out = (float*)d_out;
  float* o_ids   = out;
  float* o_zq    = out + 8192;
  float* o_recon = out + 8192 + (size_t)N_ROWS * DIM;
  float* o_scal  = out + 8192 + (size_t)N_ROWS * DIM + (size_t)N_ROWS * IN_DIM;

  // ws layout (float offsets)
  float*  ws    = (float*)d_ws;
  float*  W_dc  = ws;                          // 2,097,152
  float*  z2    = ws + 2097152;                // 8192
  float*  c2    = ws + 2105344;                // 8192
  int*    ids   = (int*)(ws + 2113536);        // 8192
  float*  b_dc  = ws + 2121728;                // 2048
  float*  ep    = ws + 2123776;                // 4096
  float*  rp    = ws + 2127872;                // 8192

  // Scratch reuse:
  //  o_recon (64 MB): t (f32 8192x1024, first half) dead after z-GEMM ->
  //    Zpack (u32 8192x1024 = 32 MB) lives there during screen; z (f32) in
  //    second half, live until ep. recon overwrites all at the end.
  //  o_zq region (32 MB): screen records (8192x64x32B = 16 MB) live there
  //    until collect; gather_zq then overwrites with the real z_q.
  float*    t     = o_recon;
  float*    z     = o_recon + (size_t)N_ROWS * DIM;
  unsigned* zpack = (unsigned*)o_recon;
  uint4*    recs  = (uint4*)o_zq;

  // decoder fusion (2%-threshold outputs)
  rowdot_bias_kernel<<<IN_DIM, 256, 0, stream>>>(W_out, b_dec, b_out, b_dc);
  gemm128<false><<<dim3(DIM / 128, IN_DIM / 128), 256, 0, stream>>>(
      W_out, W_dec, nullptr, W_dc, IN_DIM, DIM, DIM);

  // ---- np-f32 emulated encoder (bit-exact chains) ----
  emul_gemm_kernel<<<dim3(DIM / 128, N_ROWS / 128), 256, 0, stream>>>(
      roi, W_in, b_in, t, DIM, IN_DIM, IN_DIM, IN_DIM, PANEL_MASK_K2048_C32);
  emul_gemm_kernel<<<dim3(DIM / 128, N_ROWS / 128), 256, 0, stream>>>(
      t, W_enc, b_enc, z, DIM, DIM, DIM, DIM, PANEL_MASK_K1024_C32);

  // ---- np pairwise row sums of squares ----
  sumsq1024_kernel<<<N_ROWS / 4, 256, 0, stream>>>(z, z2);
  sumsq1024_kernel<<<CBK / 4, 256, 0, stream>>>(cb, c2);

  // ---- Z bf16x2 split precompute (t region now dead) ----
  zsplit_kernel<<<N_ROWS, 256, 0, stream>>>(z, zpack);

  // ---- certified MFMA screen -> records in o_zq region ----
  mfma_screen_kernel<<<dim3(CBK / 128, N_ROWS / 128), 256, 0, stream>>>(
      zpack, cb, z2, c2, recs);
  // ---- exact rescore of certified candidates ----
  collect_rescore_kernel<<<N_ROWS, 256, 0, stream>>>(
      recs, z, cb, z2, c2, ids, o_ids);

  // ---- outputs ----
  gather_zq_kernel<<<N_ROWS, 256, 0, stream>>>(cb, ids, o_zq);
  sqdiff_partial_kernel<<<(N_ROWS * DIM) / 2048, 256, 0, stream>>>(o_zq, z, ep);

  // recon via bf16 MFMA (overwrites zpack/z region AFTER ep consumed z)
  mfma_recon_kernel<<<dim3(IN_DIM / 128, N_ROWS / 128), 256, 0, stream>>>(
      o_zq, W_dc, b_dc, o_recon);

  sqdiff_partial_kernel<<<(N_ROWS * IN_DIM) / 2048, 256, 0, stream>>>(
      o_recon, roi, rp);
  final_losses_kernel<<<1, 256, 0, stream>>>(rp, ep, o_scal);
}